// Round 6
// baseline (1506.792 us; speedup 1.0000x reference)
//
#include <hip/hip_runtime.h>
#include <hip/hip_bf16.h>

#define BATCH 16384

typedef __attribute__((ext_vector_type(4))) float f32x4;
typedef __attribute__((ext_vector_type(8))) short bf16x8;

__device__ inline float b2f(unsigned short u) {
    union { unsigned u; float f; } c; c.u = ((unsigned)u) << 16; return c.f;
}
__device__ inline unsigned short f2b(float f) {
    __hip_bfloat16 h = __float2bfloat16(f);
    return *(unsigned short*)&h;
}

#define GLL16(g, l)                                                            \
    __builtin_amdgcn_global_load_lds(                                          \
        (const __attribute__((address_space(1))) void*)(g),                    \
        (__attribute__((address_space(3))) void*)(l), 16, 0, 0)

// ---------------- weight prep: f32 (K x N) -> bf16 transposed (N x K), z-paired ----------------
__global__ void k_tcvt2(const float* __restrict__ src0, const float* __restrict__ src1,
                        int K, int N,
                        unsigned short* __restrict__ dst, int off0, int off1, int dst_ld)
{
    __shared__ float t[32][33];
    const float* src = blockIdx.z ? src1 : src0;
    int dst_off = blockIdx.z ? off1 : off0;
    int k0 = blockIdx.y * 32, n0 = blockIdx.x * 32;
    int tx = threadIdx.x, ty = threadIdx.y; // 32 x 8
    #pragma unroll
    for (int s = 0; s < 32; s += 8) {
        int k = k0 + ty + s, n = n0 + tx;
        t[ty + s][tx] = (k < K && n < N) ? src[(size_t)k * N + n] : 0.f;
    }
    __syncthreads();
    #pragma unroll
    for (int s = 0; s < 32; s += 8) {
        int n = n0 + ty + s, k = k0 + tx;
        if (n < N && k < K)
            dst[(size_t)(dst_off + n) * dst_ld + k] = f2b(t[tx][ty + s]);
    }
}

// ---------------- small prep: bias concats + DA0/DB0 bf16 conversion ----------------
__global__ __launch_bounds__(256) void k_smallprep(
    const float* __restrict__ sb0, const float* __restrict__ gb0,
    const float* __restrict__ sb1, const float* __restrict__ gb1,
    const float* __restrict__ Tb0,
    const float* __restrict__ DA0, const float* __restrict__ DB0,
    float* __restrict__ b1cat, float* __restrict__ b2cat, float* __restrict__ tb0c,
    unsigned short* __restrict__ DA0b, unsigned short* __restrict__ DB0b)
{
    int i = blockIdx.x * 256 + threadIdx.x;
    if (i < 1024)            { b1cat[i] = sb0[i]; return; }
    if (i < 2048)            { b1cat[i] = gb0[i - 1024]; return; }
    if (i < 2560)            { b2cat[i - 2048] = sb1[i - 2048]; return; }
    if (i < 3072)            { b2cat[i - 2560 + 512] = gb1[i - 2560]; return; }
    if (i < 3200)            { tb0c[i - 3072] = Tb0[i - 3072]; return; }
    if (i < 3232)            { tb0c[i - 3200 + 128] = 0.f; return; }
    i -= 3232;
    if (i < 65536)           { DA0b[i] = f2b(DA0[i]); return; }
    i -= 65536;
    if (i < 32768)           { DB0b[i] = f2b(DB0[i]); return; }
}

// ---------------- embedding gather -> bf16 x_emb (B, 2048) ----------------
__global__ __launch_bounds__(256) void k_gather(const int* __restrict__ x,
                                                const float* __restrict__ emb,
                                                unsigned short* __restrict__ Xemb)
{
    int i = blockIdx.x * 256 + threadIdx.x;   // group of 4 elements
    int b  = i >> 9;                          // 512 groups per row of 2048
    int j4 = (i & 511) << 2;
    int f  = j4 >> 6;
    int l  = j4 & 63;
    int idx = x[b * 32 + f];
    float4 v = *(const float4*)(emb + (size_t)idx * 64 + l);
    ushort4 o;
    o.x = f2b(v.x); o.y = f2b(v.y); o.z = f2b(v.z); o.w = f2b(v.w);
    *(ushort4*)(Xemb + (size_t)b * 2048 + j4) = o;
}

// ================= 256x256 MFMA GEMM, BK=32 dbuf, 64 KiB LDS -> 2 blocks/CU ==========
// C(MxN) = A(MxK)*Bt(NxK)^T + bias, opt relu. Tile 256x256, 512 thr (8 waves 2Mx4N,
// per-wave 128x64 output). LDS = 2 slots x 32 KB slab (slab = [256 rows][128B]:
// chunks 0-3 = A k0..31, 4-7 = B k0..31; XOR chunk swizzle p = c ^ (row&7),
// both-sides: pre-swizzled global src + swizzled ds_read). 0 bank conflicts (r2-r5).
// Per slab t: ph0 {reads B + A-half0; MFMA16} ph1 {reads A-half1; lgkm0; BAR_mid;
// STAGE(t+2 -> slot t&1)  [safe: all reads of this slot complete at BAR_mid];
// MFMA16; vmcnt(4) [drains stage(t+1), keeps stage(t+2) in flight]; BAR_end}.
// Counted vmcnt, never 0 (T4). 2 blocks/CU give cross-block TLP (m114 mechanism).
template<int RELU, int OUTBF16>
__global__ __launch_bounds__(512, 4) void k_gemm256(
    const unsigned short* __restrict__ A, int lda, long Az,
    const unsigned short* __restrict__ Bt, int K, long Bz,
    const float* __restrict__ bias, int biasz,
    void* __restrict__ C, int ldc, long Cz,
    int N)
{
    extern __shared__ char smem_raw[];
    const int NS = K >> 5;            // 32-wide K slabs
    const int tid  = threadIdx.x;
    const int lane = tid & 63;
    const int w    = tid >> 6;
    const int wr   = w >> 2, wc = w & 3;
    const int frow = lane & 15, kg = lane >> 4;
    const int z = blockIdx.z;
    A    += (size_t)z * Az;
    Bt   += (size_t)z * Bz;
    bias += (size_t)z * biasz;

    // XCD-aware bijective swizzle (nwg divisible by 8 for all our launches)
    const int gx  = gridDim.x;
    const int nwg = gx * gridDim.y;
    const int lin = blockIdx.y * gx + blockIdx.x;
    const int qq  = nwg >> 3;
    const int swz = (lin & 7) * qq + (lin >> 3);
    const int bx = swz % gx, by = swz / gx;
    const int row0 = by * 256, col0 = bx * 256;

    // staging: one slab stage = 32KB = 4 gloads of 8KB (h=0..3) per thread.
    // lane covers row rr = h*64 + w*8 + lane>>3, physical chunk lane&7;
    // logical chunk lch = (lane&7)^(rr&7) = (lane&7)^((lane>>3)&7).
    const int lch = (lane & 7) ^ ((lane >> 3) & 7);
    const unsigned short* gsrc[4];
    #pragma unroll
    for (int h = 0; h < 4; ++h) {
        int rr = h * 64 + w * 8 + (lane >> 3);
        if (lch < 4) gsrc[h] = A  + (size_t)(row0 + rr) * lda + lch * 8;
        else         gsrc[h] = Bt + (size_t)min(col0 + rr, N - 1) * K + (lch - 4) * 8;
    }
    const int dBase = w * 1024;   // wave-uniform LDS offset within an 8KB gload block

    // fragment read offsets (bytes) within a slab; swizzled physical chunks
    const int pA = (kg ^ (frow & 7)) * 16;
    const int pB = ((4 + kg) ^ (frow & 7)) * 16;
    int aOff[8], bOff[4];
    #pragma unroll
    for (int m = 0; m < 8; ++m) aOff[m] = (wr * 128 + m * 16 + frow) * 128 + pA;
    #pragma unroll
    for (int n = 0; n < 4; ++n) bOff[n] = (wc * 64 + n * 16 + frow) * 128 + pB;

#define STAGE(sIdx, slot_) do {                                                  \
        int s_ = min((int)(sIdx), NS - 1) * 32;                                  \
        char* d_ = smem_raw + (slot_) * 32768 + dBase;                           \
        GLL16(gsrc[0] + s_, d_);                                                 \
        GLL16(gsrc[1] + s_, d_ + 8192);                                          \
        GLL16(gsrc[2] + s_, d_ + 16384);                                         \
        GLL16(gsrc[3] + s_, d_ + 24576);                                         \
    } while (0)
#define READS_B(sb_)                                                             \
        _Pragma("unroll")                                                        \
        for (int n = 0; n < 4; ++n)                                              \
            bfr[n] = *(const bf16x8*)(smem_raw + (sb_) + bOff[n]);
#define READS_A(sb_, mh_)                                                        \
        _Pragma("unroll")                                                        \
        for (int mi = 0; mi < 4; ++mi)                                           \
            afr[mi] = *(const bf16x8*)(smem_raw + (sb_) + aOff[(mh_) * 4 + mi]);
#define MFMA16(mh_) do {                                                         \
        __builtin_amdgcn_s_setprio(1);                                           \
        _Pragma("unroll")                                                        \
        for (int mi = 0; mi < 4; ++mi)                                           \
            _Pragma("unroll")                                                    \
            for (int n = 0; n < 4; ++n)                                          \
                acc[(mh_) * 4 + mi][n] = __builtin_amdgcn_mfma_f32_16x16x32_bf16( \
                    bfr[n], afr[mi], acc[(mh_) * 4 + mi][n], 0, 0, 0);           \
        __builtin_amdgcn_s_setprio(0);                                           \
    } while (0)

    f32x4 acc[8][4] = {};
    bf16x8 afr[4], bfr[4];

    // prologue: slab 0 -> slot 0, slab 1 -> slot 1; publish slab 0
    STAGE(0, 0); STAGE(1, 1);
    asm volatile("s_waitcnt vmcnt(4)" ::: "memory");
    __builtin_amdgcn_s_barrier();

    for (int t = 0; t < NS; ++t) {
        const int slot = t & 1;
        const int sb = slot * 32768;
        // ph0: B + A-half0, MFMA (compiler inserts fine-grained lgkmcnt)
        READS_B(sb); READS_A(sb, 0);
        MFMA16(0);
        // ph1: A-half1
        READS_A(sb, 1);
        asm volatile("s_waitcnt lgkmcnt(0)" ::: "memory");  // own reads of slot done
        __builtin_amdgcn_s_barrier();                       // BAR_mid: ALL reads done
        STAGE(t + 2, slot);                                 // overwrite read slot (safe)
        MFMA16(1);
        asm volatile("s_waitcnt vmcnt(4)" ::: "memory");    // slab t+1 landed; t+2 in flight
        __builtin_amdgcn_s_barrier();                       // BAR_end: slab t+1 published
    }
#undef STAGE
#undef READS_B
#undef READS_A
#undef MFMA16

    // epilogue (swapped-operand layout): lane (frow,kg) holds, per (m,n),
    // row = row0+wr*128+m*16+frow, cols = col0+wc*64+n*16+kg*4 .. +3
    #pragma unroll
    for (int m = 0; m < 8; ++m) {
        int row = row0 + wr * 128 + m * 16 + frow;
        #pragma unroll
        for (int n = 0; n < 4; ++n) {
            int col = col0 + wc * 64 + n * 16 + kg * 4;
            float4 bv = *(const float4*)(bias + col);
            float v0 = acc[m][n][0] + bv.x, v1 = acc[m][n][1] + bv.y;
            float v2 = acc[m][n][2] + bv.z, v3 = acc[m][n][3] + bv.w;
            if (RELU) {
                v0 = fmaxf(v0, 0.f); v1 = fmaxf(v1, 0.f);
                v2 = fmaxf(v2, 0.f); v3 = fmaxf(v3, 0.f);
            }
            if (OUTBF16) {
                ushort4 o = { f2b(v0), f2b(v1), f2b(v2), f2b(v3) };
                *(ushort4*)((unsigned short*)C + (size_t)z * Cz + (size_t)row * ldc + col) = o;
            } else {
                float4 o = { v0, v1, v2, v3 };
                *(float4*)((float*)C + (size_t)z * Cz + (size_t)row * ldc + col) = o;
            }
        }
    }
}

// ---------------- 128x128 MFMA GEMM (m97 structure) for small GEMMs ----------------
template<int RELU, int OUTBF16>
__global__ __launch_bounds__(256) void k_gemm(
    const unsigned short* __restrict__ A, int lda,
    const unsigned short* __restrict__ Bt,         // N x K row-major, ldb = K
    const float* __restrict__ bias,
    void* __restrict__ C, int ldc,
    int N, int K)
{
    __shared__ __align__(16) unsigned short As[128 * 32];
    __shared__ __align__(16) unsigned short Bs[128 * 32];
    const int tid  = threadIdx.x;
    const int lane = tid & 63;
    const int w    = tid >> 6;
    const int wr   = w >> 1, wc = w & 1;
    const int row0 = blockIdx.y * 128;
    const int col0 = blockIdx.x * 128;
    const int frow = lane & 15;
    const int kg   = lane >> 4;
    const int sw   = kg ^ ((frow >> 1) & 3);

    const int srow = w * 32 + (lane >> 2);
    const int csw  = (lane & 3) ^ ((lane >> 3) & 3);
    const int br0  = min(col0 + srow, N - 1);
    const int br1  = min(col0 + srow + 16, N - 1);

    const unsigned short* a0 = A  + (size_t)(row0 + srow) * lda      + csw * 8;
    const unsigned short* a1 = A  + (size_t)(row0 + srow + 16) * lda + csw * 8;
    const unsigned short* b0 = Bt + (size_t)br0 * K + csw * 8;
    const unsigned short* b1 = Bt + (size_t)br1 * K + csw * 8;
    unsigned short* lA0 = As + (w * 2 + 0) * 512;
    unsigned short* lA1 = As + (w * 2 + 1) * 512;
    unsigned short* lB0 = Bs + (w * 2 + 0) * 512;
    unsigned short* lB1 = Bs + (w * 2 + 1) * 512;

    f32x4 acc[4][4] = {};

    for (int bk = 0; bk < K; bk += 32) {
        __syncthreads();
        GLL16(a0 + bk, lA0);
        GLL16(a1 + bk, lA1);
        GLL16(b0 + bk, lB0);
        GLL16(b1 + bk, lB1);
        __syncthreads();
        bf16x8 af[4], bfr[4];
        #pragma unroll
        for (int m = 0; m < 4; ++m)
            af[m] = *(const bf16x8*)&As[(wr * 64 + m * 16 + frow) * 32 + sw * 8];
        #pragma unroll
        for (int n = 0; n < 4; ++n)
            bfr[n] = *(const bf16x8*)&Bs[(wc * 64 + n * 16 + frow) * 32 + sw * 8];
        #pragma unroll
        for (int m = 0; m < 4; ++m)
            #pragma unroll
            for (int n = 0; n < 4; ++n)
                acc[m][n] = __builtin_amdgcn_mfma_f32_16x16x32_bf16(bfr[n], af[m], acc[m][n], 0, 0, 0);
    }

    // swapped-operand epilogue: row = row0+wr*64+m*16+frow, cols col0+wc*64+n*16+kg*4..+3
    #pragma unroll
    for (int m = 0; m < 4; ++m) {
        int row = row0 + wr * 64 + m * 16 + frow;
        #pragma unroll
        for (int n = 0; n < 4; ++n) {
            int col = col0 + wc * 64 + n * 16 + kg * 4;
            if (col >= N) continue;
            float4 bv = *(const float4*)(bias + col);
            float v0 = acc[m][n][0] + bv.x, v1 = acc[m][n][1] + bv.y;
            float v2 = acc[m][n][2] + bv.z, v3 = acc[m][n][3] + bv.w;
            if (RELU) {
                v0 = fmaxf(v0, 0.f); v1 = fmaxf(v1, 0.f);
                v2 = fmaxf(v2, 0.f); v3 = fmaxf(v3, 0.f);
            }
            if (OUTBF16) {
                ushort4 o = { f2b(v0), f2b(v1), f2b(v2), f2b(v3) };
                *(ushort4*)((unsigned short*)C + (size_t)row * ldc + col) = o;
            } else {
                float4 o = { v0, v1, v2, v3 };
                *(float4*)((float*)C + (size_t)row * ldc + col) = o;
            }
        }
    }
}

// ---------------- per-sample domain LoRA (bf16 weights) ----------------
__global__ __launch_bounds__(256) void k_dlora(
    const unsigned short* __restrict__ Xdnn, const int* __restrict__ d,
    const unsigned short* __restrict__ DA0b, const unsigned short* __restrict__ DB0b,
    const float* __restrict__ Dlb0,
    const unsigned short* __restrict__ SHARE,
    unsigned short* __restrict__ LORA, unsigned short* __restrict__ DDNN)
{
    int w = threadIdx.x >> 6, lane = threadIdx.x & 63;
    int b = blockIdx.x * 4 + w;
    int dom = d[b];
    uint4 raw = *(const uint4*)(Xdnn + (size_t)b * 512 + lane * 8);
    const unsigned short* pr = (const unsigned short*)&raw;
    float xv[8];
    #pragma unroll
    for (int j = 0; j < 8; ++j) xv[j] = b2f(pr[j]);

    const unsigned short* Ap = DA0b + ((size_t)dom * 512 + lane * 8) * 16;
    float v[16];
    #pragma unroll
    for (int r = 0; r < 16; ++r) v[r] = 0.f;
    #pragma unroll
    for (int j = 0; j < 8; ++j) {
        uint4 a0 = *(const uint4*)(Ap + j * 16);
        uint4 a1 = *(const uint4*)(Ap + j * 16 + 8);
        const unsigned short* ap = (const unsigned short*)&a0;
        const unsigned short* aq = (const unsigned short*)&a1;
        float xj = xv[j];
        #pragma unroll
        for (int r = 0; r < 8; ++r) v[r]     += xj * b2f(ap[r]);
        #pragma unroll
        for (int r = 0; r < 8; ++r) v[r + 8] += xj * b2f(aq[r]);
    }
    #pragma unroll
    for (int s = 1; s < 64; s <<= 1) {
        #pragma unroll
        for (int r = 0; r < 16; ++r) v[r] += __shfl_xor(v[r], s, 64);
    }
    const unsigned short* Bp = DB0b + (size_t)dom * 16 * 256;
    const float* lbp = Dlb0 + (size_t)dom * 256;
    #pragma unroll
    for (int c = 0; c < 4; ++c) {
        int o = lane + c * 64;
        float a = lbp[o];
        #pragma unroll
        for (int r = 0; r < 16; ++r) a += v[r] * b2f(Bp[r * 256 + o]);
        float sh = b2f(SHARE[(size_t)b * 256 + o]);
        LORA[(size_t)b * 256 + o] = f2b(a);
        DDNN[(size_t)b * 256 + o] = f2b(fmaxf(sh + a, 0.f));
    }
}

// ---------------- fused tail ----------------
__global__ __launch_bounds__(256) void k_tail(
    const float* __restrict__ Yd, const float* __restrict__ Ys, const float* __restrict__ Yl,
    const unsigned short* __restrict__ Hyper,
    const float* __restrict__ TB0, const float* __restrict__ Tlb0,
    const float* __restrict__ Tk1, const float* __restrict__ Tb1,
    const float* __restrict__ TA1, const float* __restrict__ TB1, const float* __restrict__ Tlb1,
    const float* __restrict__ h0W, const float* __restrict__ h0b,
    const float* __restrict__ h1W, const float* __restrict__ h1b,
    float* __restrict__ out)
{
    __shared__ float sTB0[2][16][128];
    __shared__ float sTlb0[2][128];
    __shared__ float sTk1[128];
    __shared__ float sWeff[2][128];
    __shared__ float sY[4][3][160];
    const int tid = threadIdx.x;

    for (int i = tid; i < 4096; i += 256) ((float*)sTB0)[i] = TB0[i];
    if (tid < 256) ((float*)sTlb0)[tid] = Tlb0[tid];
    if (tid < 128) sTk1[tid] = Tk1[tid];
    {
        int t = tid >> 7, j = tid & 127;
        float a = 0.f;
        #pragma unroll
        for (int r = 0; r < 16; ++r) a += TA1[((size_t)t * 128 + j) * 16 + r] * TB1[t * 16 + r];
        sWeff[t][j] = a;
    }
    const float* Yp[3] = {Yd, Ys, Yl};
    int b0 = blockIdx.x * 4;
    for (int i = tid; i < 4 * 3 * 160; i += 256) {
        int s = i / 480, rem = i % 480, st = rem / 160, idx = rem % 160;
        sY[s][st][idx] = Yp[st][(size_t)(b0 + s) * 160 + idx];
    }
    __syncthreads();

    int w = tid >> 6, lane = tid & 63;
    int b = b0 + w;
    const float* yd = sY[w][0];
    const float* ys = sY[w][1];
    const float* yl = sY[w][2];
    int j0 = lane, j1 = lane + 64;

    uint4 hraw = *(const uint4*)(Hyper + (size_t)b * 512 + lane * 8);
    const unsigned short* hp = (const unsigned short*)&hraw;
    float hv[8];
    #pragma unroll
    for (int j = 0; j < 8; ++j) hv[j] = b2f(hp[j]);

    float red[14];
    #pragma unroll
    for (int k = 0; k < 14; ++k) red[k] = 0.f;
    #pragma unroll
    for (int j = 0; j < 8; ++j) {
        float4 w0 = *(const float4*)(h0W + (size_t)(lane * 8 + j) * 4);
        float4 w1 = *(const float4*)(h1W + (size_t)(lane * 8 + j) * 4);
        red[0] += hv[j] * w0.x; red[1] += hv[j] * w0.y; red[2] += hv[j] * w0.z; red[3] += hv[j] * w0.w;
        red[4] += hv[j] * w1.x; red[5] += hv[j] * w1.y; red[6] += hv[j] * w1.z; red[7] += hv[j] * w1.w;
    }

    float SLv[2][2], LSv[2][2];
    #pragma unroll
    for (int t = 0; t < 2; ++t) {
        float lb0 = sTlb0[t][j0], lb1 = sTlb0[t][j1];
        float dl0 = lb0, dl1 = lb1, sl0 = lb0, sl1 = lb1, ll0 = lb0, ll1 = lb1;
        #pragma unroll
        for (int r = 0; r < 16; ++r) {
            float w0v = sTB0[t][r][j0], w1v = sTB0[t][r][j1];
            float ud = yd[128 + t * 16 + r];
            float us = ys[128 + t * 16 + r];
            float ul = yl[128 + t * 16 + r];
            dl0 += ud * w0v; dl1 += ud * w1v;
            sl0 += us * w0v; sl1 += us * w1v;
            ll0 += ul * w0v; ll1 += ul * w1v;
        }
        float D0 = yd[j0] + dl0, D1 = yd[j1] + dl1;
        float S0 = ys[j0],       S1 = ys[j1];
        float L0 = ll0,          L1 = ll1;
        float sl_0 = sl0, sl_1 = sl1;
        float ls_0 = yl[j0], ls_1 = yl[j1];
        if (t == 0) {
            D0 = fmaxf(D0, 0.f); D1 = fmaxf(D1, 0.f);
            S0 = fmaxf(S0, 0.f); S1 = fmaxf(S1, 0.f);
            L0 = fmaxf(L0, 0.f); L1 = fmaxf(L1, 0.f);
            sl_0 = fmaxf(sl_0, 0.f); sl_1 = fmaxf(sl_1, 0.f);
            ls_0 = fmaxf(ls_0, 0.f); ls_1 = fmaxf(ls_1, 0.f);
        }
        SLv[t][0] = sl_0; SLv[t][1] = sl_1;
        LSv[t][0] = ls_0; LSv[t][1] = ls_1;
        float we0 = sWeff[t][j0], we1 = sWeff[t][j1];
        float tk0 = sTk1[j0],     tk1v = sTk1[j1];
        red[8 + t * 3 + 0] = D0 * (tk0 + we0) + D1 * (tk1v + we1);
        red[8 + t * 3 + 1] = S0 * tk0 + S1 * tk1v;
        red[8 + t * 3 + 2] = L0 * we0 + L1 * we1;
    }

    #pragma unroll
    for (int s = 1; s < 64; s <<= 1) {
        #pragma unroll
        for (int k = 0; k < 14; ++k) red[k] += __shfl_xor(red[k], s, 64);
    }

    float Tb1v = Tb1[0];
    #pragma unroll
    for (int t = 0; t < 2; ++t) {
        float fd = red[8 + t * 3 + 0] + Tb1v + Tlb1[t];
        float fs = red[8 + t * 3 + 1] + Tb1v;
        float fl = red[8 + t * 3 + 2] + Tlb1[t];
        const float* hb = t ? h1b : h0b;
        float g0 = 1.f / (1.f + expf(-(red[t * 4 + 0] + hb[0])));
        float g1 = 1.f / (1.f + expf(-(red[t * 4 + 1] + hb[1])));
        float g2 = 1.f / (1.f + expf(-(red[t * 4 + 2] + hb[2])));
        float g3 = 1.f / (1.f + expf(-(red[t * 4 + 3] + hb[3])));
        float base = fd - g0 * fs - g1 * fl;
        size_t o = (size_t)t * BATCH * 128 + (size_t)b * 128;
        out[o + j0] = base - g2 * SLv[t][0] - g3 * LSv[t][0];
        out[o + j1] = base - g2 * SLv[t][1] - g3 * LSv[t][1];
    }
}

// ---------------- host ----------------
extern "C" void kernel_launch(void* const* d_in, const int* in_sizes, int n_in,
                              void* d_out, int out_size, void* d_ws, size_t ws_size,
                              hipStream_t stream)
{
    const int*   x    = (const int*)  d_in[0];
    const int*   dix  = (const int*)  d_in[1];
    const float* emb  = (const float*)d_in[2];
    const float* sW0  = (const float*)d_in[3];
    const float* sb0  = (const float*)d_in[4];
    const float* sW1  = (const float*)d_in[5];
    const float* sb1  = (const float*)d_in[6];
    const float* Dk0  = (const float*)d_in[7];
    const float* Db0  = (const float*)d_in[8];
    const float* DA0  = (const float*)d_in[9];
    const float* DB0  = (const float*)d_in[10];
    const float* Dlb0 = (const float*)d_in[11];
    const float* Tk0  = (const float*)d_in[12];
    const float* Tb0  = (const float*)d_in[13];
    const float* Tk1  = (const float*)d_in[14];
    const float* Tb1  = (const float*)d_in[15];
    const float* TA0  = (const float*)d_in[16];
    const float* TB0  = (const float*)d_in[17];
    const float* Tlb0 = (const float*)d_in[18];
    const float* TA1  = (const float*)d_in[19];
    const float* TB1  = (const float*)d_in[20];
    const float* Tlb1 = (const float*)d_in[21];
    const float* gW0  = (const float*)d_in[22];
    const float* gb0  = (const float*)d_in[23];
    const float* gW1  = (const float*)d_in[24];
    const float* gb1  = (const float*)d_in[25];
    const float* h0W  = (const float*)d_in[26];
    const float* h0b  = (const float*)d_in[27];
    const float* h1W  = (const float*)d_in[28];
    const float* h1b  = (const float*)d_in[29];

    hipFuncSetAttribute((const void*)k_gemm256<1, 1>,
                        hipFuncAttributeMaxDynamicSharedMemorySize, 65536);

    char* ws = (char*)d_ws;
    size_t off = 0;
    auto alloc = [&](size_t bytes) -> void* {
        void* p = ws + off;
        off += (bytes + 255) & ~(size_t)255;
        return p;
    };
    unsigned short* W1t   = (unsigned short*)alloc((size_t)2048 * 2048 * 2);
    unsigned short* W2cat = (unsigned short*)alloc((size_t)1024 * 1024 * 2); // rows 0-511 share, 512-1023 gate
    unsigned short* Dk0t  = (unsigned short*)alloc((size_t)256 * 512 * 2);
    unsigned short* Tcat  = (unsigned short*)alloc((size_t)160 * 256 * 2);
    unsigned short* DA0b  = (unsigned short*)alloc((size_t)8 * 512 * 16 * 2);
    unsigned short* DB0b  = (unsigned short*)alloc((size_t)8 * 16 * 256 * 2);
    float*          b1cat = (float*)alloc(2048 * 4);
    float*          b2cat = (float*)alloc(1024 * 4);
    float*          tb0c  = (float*)alloc(160 * 4);
    char* regA = (char*)alloc((size_t)BATCH * 2048 * 2);   // Xemb, later Ys/Yl/Yd
    char* regB = (char*)alloc((size_t)BATCH * 2048 * 2);   // H, later SHARE/LORA/DDNN
    unsigned short* Xdnn  = (unsigned short*)alloc((size_t)BATCH * 512 * 2);
    unsigned short* Hyper = (unsigned short*)alloc((size_t)BATCH * 512 * 2);

    unsigned short* Xemb = (unsigned short*)regA;
    float* Ybase = (float*)regA;
    float* Ys = Ybase;                              // stream order: SHARE, LORA, DDNN
    float* Yl = Ybase + (size_t)BATCH * 160;
    float* Yd = Ybase + (size_t)2 * BATCH * 160;
    unsigned short* Hbuf  = (unsigned short*)regB;
    unsigned short* SHARE = (unsigned short*)regB;
    unsigned short* LORA  = SHARE + (size_t)BATCH * 256;
    unsigned short* DDNN  = LORA  + (size_t)BATCH * 256;

    dim3 tb(32, 8);
    // weight prep (bf16, transposed N x K) — paired launches
    k_tcvt2<<<dim3(32, 64, 2), tb, 0, stream>>>(sW0, gW0, 2048, 1024, W1t, 0, 1024, 2048);
    k_tcvt2<<<dim3(16, 32, 2), tb, 0, stream>>>(sW1, gW1, 1024, 512, W2cat, 0, 512, 1024);
    k_tcvt2<<<dim3(8, 16, 1),  tb, 0, stream>>>(Dk0, Dk0, 512, 256, Dk0t, 0, 0, 512);
    k_tcvt2<<<dim3(4, 8, 1),   tb, 0, stream>>>(Tk0, Tk0, 256, 128, Tcat, 0, 0, 256);
    k_tcvt2<<<dim3(1, 8, 2),   tb, 0, stream>>>(TA0, TA0 + 256 * 16, 256, 16, Tcat, 128, 144, 256);
    k_smallprep<<<397, 256, 0, stream>>>(sb0, gb0, sb1, gb1, Tb0, DA0, DB0,
                                         b1cat, b2cat, tb0c, DA0b, DB0b);

    // gather
    k_gather<<<32768, 256, 0, stream>>>(x, emb, Xemb);
    // GEMM1 (dbuf BK=32, 2 blocks/CU): x_emb @ [sW0|gW0], relu -> H (B,2048) bf16
    k_gemm256<1, 1><<<dim3(8, 64, 1), 512, 65536, stream>>>(
        Xemb, 2048, 0, W1t, 2048, 0, b1cat, 0, Hbuf, 2048, 0, 2048);
    // GEMM2 grouped (z=0: share-MLP, z=1: gate-hypernet): H halves -> Xdnn / Hyper
    k_gemm256<1, 1><<<dim3(2, 64, 2), 512, 65536, stream>>>(
        Hbuf, 2048, 1024, W2cat, 1024, (long)512 * 1024, b2cat, 512,
        Xdnn, 512, (long)BATCH * 512, 512);
    // GEMM3: share = x_dnn @ Dk0 + Db0 (pre-act) bf16
    k_gemm<0, 1><<<dim3(2, 128), 256, 0, stream>>>(Xdnn, 512, Dk0t, Db0, SHARE, 256, 256, 512);
    // domain LoRA + ddnn
    k_dlora<<<BATCH / 4, 256, 0, stream>>>(Xdnn, dix, DA0b, DB0b, Dlb0, SHARE, LORA, DDNN);
    // stage i=0: one fused GEMM over 3 contiguous streams @ [Tk0|TA0[0]|TA0[1]]
    k_gemm<0, 0><<<dim3(2, 384), 256, 0, stream>>>(SHARE, 256, Tcat, tb0c, Ybase, 160, 160, 256);
    // fused tail
    k_tail<<<BATCH / 4, 256, 0, stream>>>(Yd, Ys, Yl, Hyper, TB0, Tlb0, Tk1, Tb1,
                                          TA1, TB1, Tlb1, h0W, h0b, h1W, h1b, (float*)d_out);
}

// Round 7
// 353.976 us; speedup vs baseline: 4.2568x; 4.2568x over previous
//
#include <hip/hip_runtime.h>
#include <hip/hip_bf16.h>

#define BATCH 16384

typedef __attribute__((ext_vector_type(4))) float f32x4;
typedef __attribute__((ext_vector_type(8))) short bf16x8;

__device__ inline float b2f(unsigned short u) {
    union { unsigned u; float f; } c; c.u = ((unsigned)u) << 16; return c.f;
}
__device__ inline unsigned short f2b(float f) {
    __hip_bfloat16 h = __float2bfloat16(f);
    return *(unsigned short*)&h;
}

#define GLL16(g, l)                                                            \
    __builtin_amdgcn_global_load_lds(                                          \
        (const __attribute__((address_space(1))) void*)(g),                    \
        (__attribute__((address_space(3))) void*)(l), 16, 0, 0)

// ---------------- mega-prep: all transposes + biases + bf16 conversions, ONE launch ----------------
// ranges: [0,4096) W1 | [,5120) W2 | [,5248) Dk0 | [,5280) Tk0 | [,5296) TA0 |
//         [,5693) small | [,11943) embB
__global__ __launch_bounds__(256) void k_prep(
    const float* __restrict__ sW0, const float* __restrict__ gW0,
    const float* __restrict__ sW1, const float* __restrict__ gW1,
    const float* __restrict__ Dk0, const float* __restrict__ Tk0,
    const float* __restrict__ TA0,
    const float* __restrict__ sb0, const float* __restrict__ gb0,
    const float* __restrict__ sb1, const float* __restrict__ gb1,
    const float* __restrict__ Tb0, const float* __restrict__ DA0,
    const float* __restrict__ DB0, const float* __restrict__ emb,
    unsigned short* __restrict__ W1t, unsigned short* __restrict__ W2cat,
    unsigned short* __restrict__ Dk0t, unsigned short* __restrict__ Tcat,
    float* __restrict__ b1cat, float* __restrict__ b2cat, float* __restrict__ tb0c,
    unsigned short* __restrict__ DA0b, unsigned short* __restrict__ DB0b,
    unsigned short* __restrict__ embB)
{
    int id = blockIdx.x;
    const int tid = threadIdx.x;
    __shared__ float t[32][33];
    auto tcvt = [&](const float* src, int K, int N, unsigned short* dst,
                    int dst_off, int dst_ld, int bx, int by) {
        int k0 = by * 32, n0 = bx * 32;
        int tx = tid & 31, ty = tid >> 5;   // 32 x 8
        #pragma unroll
        for (int s = 0; s < 32; s += 8) {
            int k = k0 + ty + s, n = n0 + tx;
            t[ty + s][tx] = (k < K && n < N) ? src[(size_t)k * N + n] : 0.f;
        }
        __syncthreads();
        #pragma unroll
        for (int s = 0; s < 32; s += 8) {
            int n = n0 + ty + s, k = k0 + tx;
            if (n < N && k < K)
                dst[(size_t)(dst_off + n) * dst_ld + k] = f2b(t[tx][ty + s]);
        }
    };
    if (id < 4096) { int z = id >> 11, rem = id & 2047;
        tcvt(z ? gW0 : sW0, 2048, 1024, W1t, z * 1024, 2048, rem & 31, rem >> 5); return; }
    id -= 4096;
    if (id < 1024) { int z = id >> 9, rem = id & 511;
        tcvt(z ? gW1 : sW1, 1024, 512, W2cat, z * 512, 1024, rem & 15, rem >> 4); return; }
    id -= 1024;
    if (id < 128) { tcvt(Dk0, 512, 256, Dk0t, 0, 512, id & 7, id >> 3); return; }
    id -= 128;
    if (id < 32)  { tcvt(Tk0, 256, 128, Tcat, 0, 256, id & 3, id >> 2); return; }
    id -= 32;
    if (id < 16)  { int z = id >> 3;
        tcvt(TA0 + z * 256 * 16, 256, 16, Tcat, 128 + z * 16, 256, 0, id & 7); return; }
    id -= 16;
    if (id < 397) {
        int i = id * 256 + tid;
        if (i < 1024)            { b1cat[i] = sb0[i]; return; }
        if (i < 2048)            { b1cat[i] = gb0[i - 1024]; return; }
        if (i < 2560)            { b2cat[i - 2048] = sb1[i - 2048]; return; }
        if (i < 3072)            { b2cat[i - 2560 + 512] = gb1[i - 2560]; return; }
        if (i < 3200)            { tb0c[i - 3072] = Tb0[i - 3072]; return; }
        if (i < 3232)            { tb0c[i - 3200 + 128] = 0.f; return; }
        i -= 3232;
        if (i < 65536)           { DA0b[i] = f2b(DA0[i]); return; }
        i -= 65536;
        if (i < 32768)           { DB0b[i] = f2b(DB0[i]); return; }
        return;
    }
    id -= 397;
    {   // embB: f32 (100000 x 64) -> bf16, 4 elems/thread
        int e = (id * 256 + tid) * 4;
        if (e < 100000 * 64) {
            float4 v = *(const float4*)(emb + e);
            ushort4 o = { f2b(v.x), f2b(v.y), f2b(v.z), f2b(v.w) };
            *(ushort4*)(embB + e) = o;
        }
    }
}

// ================= 256x256 fine-phase MFMA GEMM (round-5 structure + optional fused gather) =====
// C(MxN) = A(MxK)*Bt(NxK)^T + bias, opt relu. Tile 256x256, BK=64 (2 kslices of 32),
// 512 thr (8 waves 2Mx4N). LDS: 2 dbuf slots x 64KB (2 kslices x [256 rows][A|B 128B]),
// XOR chunk swizzle p=c^(row&7) both-sides; 0 bank conflicts (verified r2-r5).
// GATHER=1: A rows are gathered embeddings — x-block (256x32 ints, 32KB) DMA'd to a 3rd
// LDS region in the prologue; per-STAGE each A-lane computes src = embB + x[row,t]*64
// + ks*32 + lch*8 (feature index == K-tile index since tiles are 64 = L wide).
// Index reads are ds_read (lgkm) so the vmcnt(4) audit is unchanged: 4 vm-ops/STAGE,
// queue=8 at each VM4, oldest 4 = the kslice the next phase reads. vmcnt never 0 (T4).
template<int RELU, int OUTBF16, int GATHER>
__global__ __launch_bounds__(512, 2) void k_gemm256(
    const unsigned short* __restrict__ A, int lda, long Az,
    const unsigned short* __restrict__ Bt, int K, long Bz,
    const float* __restrict__ bias, int biasz,
    void* __restrict__ C, int ldc, long Cz,
    int N, const int* __restrict__ xsrc, const unsigned short* __restrict__ embB)
{
    extern __shared__ char smem_raw[];
    const int NT = K >> 6;            // 64-wide K tiles
    const int tid  = threadIdx.x;
    const int lane = tid & 63;
    const int w    = tid >> 6;
    const int wr   = w >> 2, wc = w & 3;
    const int frow = lane & 15, kg = lane >> 4;
    const int z = blockIdx.z;
    A    += (size_t)z * Az;
    Bt   += (size_t)z * Bz;
    bias += (size_t)z * biasz;

    // XCD-aware bijective swizzle (nwg divisible by 8 for all our launches)
    const int gx  = gridDim.x;
    const int nwg = gx * gridDim.y;
    const int lin = blockIdx.y * gx + blockIdx.x;
    const int qq  = nwg >> 3;
    const int swz = (lin & 7) * qq + (lin >> 3);
    const int bx = swz % gx, by = swz / gx;
    const int row0 = by * 256, col0 = bx * 256;

    // staging: one kslice = 32KB = 4 gloads of 8KB (h=0..3) per thread.
    // lane covers row rr = h*64 + w*8 + lane>>3, physical chunk lane&7;
    // logical chunk lch = (lane&7)^(rr&7) = (lane&7)^((lane>>3)&7).
    const int lch = (lane & 7) ^ ((lane >> 3) & 7);
    const int isA = (lch < 4);
    const int eoBase = lch * 8;                    // elem offset within embedding row (A)
    const int* xb = (const int*)(smem_raw + 131072);   // 32KB x-block (GATHER)
    int rrh[4];
    const unsigned short* gsrc[4];
    #pragma unroll
    for (int h = 0; h < 4; ++h) {
        int rr = h * 64 + w * 8 + (lane >> 3);
        rrh[h] = rr;
        if (isA) gsrc[h] = GATHER ? embB : A + (size_t)(row0 + rr) * lda + lch * 8;
        else     gsrc[h] = Bt + (size_t)min(col0 + rr, N - 1) * K + (lch - 4) * 8;
    }
    const int dBase = w * 1024;   // wave-uniform LDS offset within an 8KB gload block

    // fragment read offsets (bytes) within a kslice region; swizzled physical chunks
    const int pA = (kg ^ (frow & 7)) * 16;
    const int pB = ((4 + kg) ^ (frow & 7)) * 16;
    int aOff[8], bOff[4];
    #pragma unroll
    for (int m = 0; m < 8; ++m) aOff[m] = (wr * 128 + m * 16 + frow) * 128 + pA;
    #pragma unroll
    for (int n = 0; n < 4; ++n) bOff[n] = (wc * 64 + n * 16 + frow) * 128 + pB;

#define STAGE(t_, ks_, slot_) do {                                               \
        int tc_ = min((int)(t_), NT - 1);                                        \
        char* d_ = smem_raw + (slot_) * 65536 + (ks_) * 32768 + dBase;           \
        if (GATHER) {                                                            \
            _Pragma("unroll")                                                    \
            for (int h_ = 0; h_ < 4; ++h_) {                                     \
                int ix_ = xb[rrh[h_] * 32 + tc_];                                \
                const unsigned short* sa_ = embB + (size_t)ix_ * 64              \
                                            + (ks_) * 32 + eoBase;               \
                const unsigned short* sb_ = gsrc[h_] + tc_ * 64 + (ks_) * 32;    \
                const unsigned short* s_  = isA ? sa_ : sb_;                     \
                GLL16(s_, d_ + h_ * 8192);                                       \
            }                                                                    \
        } else {                                                                 \
            int o_ = tc_ * 64 + (ks_) * 32;                                      \
            GLL16(gsrc[0] + o_, d_);                                             \
            GLL16(gsrc[1] + o_, d_ + 8192);                                      \
            GLL16(gsrc[2] + o_, d_ + 16384);                                     \
            GLL16(gsrc[3] + o_, d_ + 24576);                                     \
        }                                                                        \
    } while (0)
#define READS_B(sb_, ks_)                                                        \
        _Pragma("unroll")                                                        \
        for (int n = 0; n < 4; ++n)                                              \
            bfr[n] = *(const bf16x8*)(smem_raw + (sb_) + (ks_) * 32768 + bOff[n]);
#define READS_A(sb_, ks_, mh_)                                                   \
        _Pragma("unroll")                                                        \
        for (int mi = 0; mi < 4; ++mi)                                           \
            afr[mi] = *(const bf16x8*)(smem_raw + (sb_) + (ks_) * 32768 + aOff[(mh_) * 4 + mi]);
#define MFMA16(mh_) do {                                                         \
        __builtin_amdgcn_s_setprio(1);                                           \
        _Pragma("unroll")                                                        \
        for (int mi = 0; mi < 4; ++mi)                                           \
            _Pragma("unroll")                                                    \
            for (int n = 0; n < 4; ++n)                                          \
                acc[(mh_) * 4 + mi][n] = __builtin_amdgcn_mfma_f32_16x16x32_bf16( \
                    bfr[n], afr[mi], acc[(mh_) * 4 + mi][n], 0, 0, 0);           \
        __builtin_amdgcn_s_setprio(0);                                           \
    } while (0)
#define LGKM0 asm volatile("s_waitcnt lgkmcnt(0)" ::: "memory")
#define VM4   asm volatile("s_waitcnt vmcnt(4)" ::: "memory")
#define BAR   __builtin_amdgcn_s_barrier()

    f32x4 acc[8][4] = {};
    bf16x8 afr[4], bfr[4];

    // prologue: (GATHER) DMA x-block; then tile 0 both kslices into slot 0.
    if (GATHER) {
        const char* xs = (const char*)(xsrc + row0 * 32);
        #pragma unroll
        for (int r = 0; r < 4; ++r)
            GLL16(xs + r * 8192 + w * 1024 + lane * 16,
                  smem_raw + 131072 + r * 8192 + w * 1024);
        asm volatile("s_waitcnt vmcnt(0)" ::: "memory");   // x-block resident
        __builtin_amdgcn_s_barrier();                      // published to all waves
    }
    STAGE(0, 0, 0); STAGE(0, 1, 0);
    VM4; BAR;

    for (int t = 0; t < NT; ++t) {
        const int slot = t & 1, nslot = slot ^ 1;
        const int sb = slot * 65536;
        // ph0: ks0, mh0
        READS_B(sb, 0); READS_A(sb, 0, 0);
        STAGE(t + 1, 0, nslot);
        BAR; LGKM0; MFMA16(0); BAR;
        // ph1: ks0, mh1
        READS_A(sb, 0, 1);
        VM4;                       // publishes ks1(t)
        BAR; LGKM0; MFMA16(1); BAR;
        // ph2: ks1, mh0
        READS_B(sb, 1); READS_A(sb, 1, 0);
        STAGE(t + 1, 1, nslot);
        BAR; LGKM0; MFMA16(0); BAR;
        // ph3: ks1, mh1
        READS_A(sb, 1, 1);
        VM4;                       // publishes ks0(t+1)
        BAR; LGKM0; MFMA16(1); BAR;
    }
#undef STAGE
#undef READS_B
#undef READS_A
#undef MFMA16
#undef LGKM0
#undef VM4
#undef BAR

    // epilogue (swapped-operand layout): row = row0+wr*128+m*16+frow,
    // cols = col0+wc*64+n*16+kg*4 .. +3
    #pragma unroll
    for (int m = 0; m < 8; ++m) {
        int row = row0 + wr * 128 + m * 16 + frow;
        #pragma unroll
        for (int n = 0; n < 4; ++n) {
            int col = col0 + wc * 64 + n * 16 + kg * 4;
            float4 bv = *(const float4*)(bias + col);
            float v0 = acc[m][n][0] + bv.x, v1 = acc[m][n][1] + bv.y;
            float v2 = acc[m][n][2] + bv.z, v3 = acc[m][n][3] + bv.w;
            if (RELU) {
                v0 = fmaxf(v0, 0.f); v1 = fmaxf(v1, 0.f);
                v2 = fmaxf(v2, 0.f); v3 = fmaxf(v3, 0.f);
            }
            if (OUTBF16) {
                ushort4 o = { f2b(v0), f2b(v1), f2b(v2), f2b(v3) };
                *(ushort4*)((unsigned short*)C + (size_t)z * Cz + (size_t)row * ldc + col) = o;
            } else {
                float4 o = { v0, v1, v2, v3 };
                *(float4*)((float*)C + (size_t)z * Cz + (size_t)row * ldc + col) = o;
            }
        }
    }
}

// ---------------- 128x128 MFMA GEMM (m97 structure) for small GEMMs ----------------
template<int RELU, int OUTBF16>
__global__ __launch_bounds__(256) void k_gemm(
    const unsigned short* __restrict__ A, int lda,
    const unsigned short* __restrict__ Bt,         // N x K row-major, ldb = K
    const float* __restrict__ bias,
    void* __restrict__ C, int ldc,
    int N, int K)
{
    __shared__ __align__(16) unsigned short As[128 * 32];
    __shared__ __align__(16) unsigned short Bs[128 * 32];
    const int tid  = threadIdx.x;
    const int lane = tid & 63;
    const int w    = tid >> 6;
    const int wr   = w >> 1, wc = w & 1;
    const int row0 = blockIdx.y * 128;
    const int col0 = blockIdx.x * 128;
    const int frow = lane & 15;
    const int kg   = lane >> 4;
    const int sw   = kg ^ ((frow >> 1) & 3);

    const int srow = w * 32 + (lane >> 2);
    const int csw  = (lane & 3) ^ ((lane >> 3) & 3);
    const int br0  = min(col0 + srow, N - 1);
    const int br1  = min(col0 + srow + 16, N - 1);

    const unsigned short* a0 = A  + (size_t)(row0 + srow) * lda      + csw * 8;
    const unsigned short* a1 = A  + (size_t)(row0 + srow + 16) * lda + csw * 8;
    const unsigned short* b0 = Bt + (size_t)br0 * K + csw * 8;
    const unsigned short* b1 = Bt + (size_t)br1 * K + csw * 8;
    unsigned short* lA0 = As + (w * 2 + 0) * 512;
    unsigned short* lA1 = As + (w * 2 + 1) * 512;
    unsigned short* lB0 = Bs + (w * 2 + 0) * 512;
    unsigned short* lB1 = Bs + (w * 2 + 1) * 512;

    f32x4 acc[4][4] = {};

    for (int bk = 0; bk < K; bk += 32) {
        __syncthreads();
        GLL16(a0 + bk, lA0);
        GLL16(a1 + bk, lA1);
        GLL16(b0 + bk, lB0);
        GLL16(b1 + bk, lB1);
        __syncthreads();
        bf16x8 af[4], bfr[4];
        #pragma unroll
        for (int m = 0; m < 4; ++m)
            af[m] = *(const bf16x8*)&As[(wr * 64 + m * 16 + frow) * 32 + sw * 8];
        #pragma unroll
        for (int n = 0; n < 4; ++n)
            bfr[n] = *(const bf16x8*)&Bs[(wc * 64 + n * 16 + frow) * 32 + sw * 8];
        #pragma unroll
        for (int m = 0; m < 4; ++m)
            #pragma unroll
            for (int n = 0; n < 4; ++n)
                acc[m][n] = __builtin_amdgcn_mfma_f32_16x16x32_bf16(bfr[n], af[m], acc[m][n], 0, 0, 0);
    }

    // swapped-operand epilogue: row = row0+wr*64+m*16+frow, cols col0+wc*64+n*16+kg*4..+3
    #pragma unroll
    for (int m = 0; m < 4; ++m) {
        int row = row0 + wr * 64 + m * 16 + frow;
        #pragma unroll
        for (int n = 0; n < 4; ++n) {
            int col = col0 + wc * 64 + n * 16 + kg * 4;
            if (col >= N) continue;
            float4 bv = *(const float4*)(bias + col);
            float v0 = acc[m][n][0] + bv.x, v1 = acc[m][n][1] + bv.y;
            float v2 = acc[m][n][2] + bv.z, v3 = acc[m][n][3] + bv.w;
            if (RELU) {
                v0 = fmaxf(v0, 0.f); v1 = fmaxf(v1, 0.f);
                v2 = fmaxf(v2, 0.f); v3 = fmaxf(v3, 0.f);
            }
            if (OUTBF16) {
                ushort4 o = { f2b(v0), f2b(v1), f2b(v2), f2b(v3) };
                *(ushort4*)((unsigned short*)C + (size_t)row * ldc + col) = o;
            } else {
                float4 o = { v0, v1, v2, v3 };
                *(float4*)((float*)C + (size_t)row * ldc + col) = o;
            }
        }
    }
}

// ---------------- per-sample domain LoRA (bf16 weights) ----------------
__global__ __launch_bounds__(256) void k_dlora(
    const unsigned short* __restrict__ Xdnn, const int* __restrict__ d,
    const unsigned short* __restrict__ DA0b, const unsigned short* __restrict__ DB0b,
    const float* __restrict__ Dlb0,
    const unsigned short* __restrict__ SHARE,
    unsigned short* __restrict__ LORA, unsigned short* __restrict__ DDNN)
{
    int w = threadIdx.x >> 6, lane = threadIdx.x & 63;
    int b = blockIdx.x * 4 + w;
    int dom = d[b];
    uint4 raw = *(const uint4*)(Xdnn + (size_t)b * 512 + lane * 8);
    const unsigned short* pr = (const unsigned short*)&raw;
    float xv[8];
    #pragma unroll
    for (int j = 0; j < 8; ++j) xv[j] = b2f(pr[j]);

    const unsigned short* Ap = DA0b + ((size_t)dom * 512 + lane * 8) * 16;
    float v[16];
    #pragma unroll
    for (int r = 0; r < 16; ++r) v[r] = 0.f;
    #pragma unroll
    for (int j = 0; j < 8; ++j) {
        uint4 a0 = *(const uint4*)(Ap + j * 16);
        uint4 a1 = *(const uint4*)(Ap + j * 16 + 8);
        const unsigned short* ap = (const unsigned short*)&a0;
        const unsigned short* aq = (const unsigned short*)&a1;
        float xj = xv[j];
        #pragma unroll
        for (int r = 0; r < 8; ++r) v[r]     += xj * b2f(ap[r]);
        #pragma unroll
        for (int r = 0; r < 8; ++r) v[r + 8] += xj * b2f(aq[r]);
    }
    #pragma unroll
    for (int s = 1; s < 64; s <<= 1) {
        #pragma unroll
        for (int r = 0; r < 16; ++r) v[r] += __shfl_xor(v[r], s, 64);
    }
    const unsigned short* Bp = DB0b + (size_t)dom * 16 * 256;
    const float* lbp = Dlb0 + (size_t)dom * 256;
    #pragma unroll
    for (int c = 0; c < 4; ++c) {
        int o = lane + c * 64;
        float a = lbp[o];
        #pragma unroll
        for (int r = 0; r < 16; ++r) a += v[r] * b2f(Bp[r * 256 + o]);
        float sh = b2f(SHARE[(size_t)b * 256 + o]);
        LORA[(size_t)b * 256 + o] = f2b(a);
        DDNN[(size_t)b * 256 + o] = f2b(fmaxf(sh + a, 0.f));
    }
}

// ---------------- fused tail ----------------
__global__ __launch_bounds__(256) void k_tail(
    const float* __restrict__ Yd, const float* __restrict__ Ys, const float* __restrict__ Yl,
    const unsigned short* __restrict__ Hyper,
    const float* __restrict__ TB0, const float* __restrict__ Tlb0,
    const float* __restrict__ Tk1, const float* __restrict__ Tb1,
    const float* __restrict__ TA1, const float* __restrict__ TB1, const float* __restrict__ Tlb1,
    const float* __restrict__ h0W, const float* __restrict__ h0b,
    const float* __restrict__ h1W, const float* __restrict__ h1b,
    float* __restrict__ out)
{
    __shared__ float sTB0[2][16][128];
    __shared__ float sTlb0[2][128];
    __shared__ float sTk1[128];
    __shared__ float sWeff[2][128];
    __shared__ float sY[4][3][160];
    const int tid = threadIdx.x;

    for (int i = tid; i < 4096; i += 256) ((float*)sTB0)[i] = TB0[i];
    if (tid < 256) ((float*)sTlb0)[tid] = Tlb0[tid];
    if (tid < 128) sTk1[tid] = Tk1[tid];
    {
        int t = tid >> 7, j = tid & 127;
        float a = 0.f;
        #pragma unroll
        for (int r = 0; r < 16; ++r) a += TA1[((size_t)t * 128 + j) * 16 + r] * TB1[t * 16 + r];
        sWeff[t][j] = a;
    }
    const float* Yp[3] = {Yd, Ys, Yl};
    int b0 = blockIdx.x * 4;
    for (int i = tid; i < 4 * 3 * 160; i += 256) {
        int s = i / 480, rem = i % 480, st = rem / 160, idx = rem % 160;
        sY[s][st][idx] = Yp[st][(size_t)(b0 + s) * 160 + idx];
    }
    __syncthreads();

    int w = tid >> 6, lane = tid & 63;
    int b = b0 + w;
    const float* yd = sY[w][0];
    const float* ys = sY[w][1];
    const float* yl = sY[w][2];
    int j0 = lane, j1 = lane + 64;

    uint4 hraw = *(const uint4*)(Hyper + (size_t)b * 512 + lane * 8);
    const unsigned short* hp = (const unsigned short*)&hraw;
    float hv[8];
    #pragma unroll
    for (int j = 0; j < 8; ++j) hv[j] = b2f(hp[j]);

    float red[14];
    #pragma unroll
    for (int k = 0; k < 14; ++k) red[k] = 0.f;
    #pragma unroll
    for (int j = 0; j < 8; ++j) {
        float4 w0 = *(const float4*)(h0W + (size_t)(lane * 8 + j) * 4);
        float4 w1 = *(const float4*)(h1W + (size_t)(lane * 8 + j) * 4);
        red[0] += hv[j] * w0.x; red[1] += hv[j] * w0.y; red[2] += hv[j] * w0.z; red[3] += hv[j] * w0.w;
        red[4] += hv[j] * w1.x; red[5] += hv[j] * w1.y; red[6] += hv[j] * w1.z; red[7] += hv[j] * w1.w;
    }

    float SLv[2][2], LSv[2][2];
    #pragma unroll
    for (int t = 0; t < 2; ++t) {
        float lb0 = sTlb0[t][j0], lb1 = sTlb0[t][j1];
        float dl0 = lb0, dl1 = lb1, sl0 = lb0, sl1 = lb1, ll0 = lb0, ll1 = lb1;
        #pragma unroll
        for (int r = 0; r < 16; ++r) {
            float w0v = sTB0[t][r][j0], w1v = sTB0[t][r][j1];
            float ud = yd[128 + t * 16 + r];
            float us = ys[128 + t * 16 + r];
            float ul = yl[128 + t * 16 + r];
            dl0 += ud * w0v; dl1 += ud * w1v;
            sl0 += us * w0v; sl1 += us * w1v;
            ll0 += ul * w0v; ll1 += ul * w1v;
        }
        float D0 = yd[j0] + dl0, D1 = yd[j1] + dl1;
        float S0 = ys[j0],       S1 = ys[j1];
        float L0 = ll0,          L1 = ll1;
        float sl_0 = sl0, sl_1 = sl1;
        float ls_0 = yl[j0], ls_1 = yl[j1];
        if (t == 0) {
            D0 = fmaxf(D0, 0.f); D1 = fmaxf(D1, 0.f);
            S0 = fmaxf(S0, 0.f); S1 = fmaxf(S1, 0.f);
            L0 = fmaxf(L0, 0.f); L1 = fmaxf(L1, 0.f);
            sl_0 = fmaxf(sl_0, 0.f); sl_1 = fmaxf(sl_1, 0.f);
            ls_0 = fmaxf(ls_0, 0.f); ls_1 = fmaxf(ls_1, 0.f);
        }
        SLv[t][0] = sl_0; SLv[t][1] = sl_1;
        LSv[t][0] = ls_0; LSv[t][1] = ls_1;
        float we0 = sWeff[t][j0], we1 = sWeff[t][j1];
        float tk0 = sTk1[j0],     tk1v = sTk1[j1];
        red[8 + t * 3 + 0] = D0 * (tk0 + we0) + D1 * (tk1v + we1);
        red[8 + t * 3 + 1] = S0 * tk0 + S1 * tk1v;
        red[8 + t * 3 + 2] = L0 * we0 + L1 * we1;
    }

    #pragma unroll
    for (int s = 1; s < 64; s <<= 1) {
        #pragma unroll
        for (int k = 0; k < 14; ++k) red[k] += __shfl_xor(red[k], s, 64);
    }

    float Tb1v = Tb1[0];
    #pragma unroll
    for (int t = 0; t < 2; ++t) {
        float fd = red[8 + t * 3 + 0] + Tb1v + Tlb1[t];
        float fs = red[8 + t * 3 + 1] + Tb1v;
        float fl = red[8 + t * 3 + 2] + Tlb1[t];
        const float* hb = t ? h1b : h0b;
        float g0 = 1.f / (1.f + expf(-(red[t * 4 + 0] + hb[0])));
        float g1 = 1.f / (1.f + expf(-(red[t * 4 + 1] + hb[1])));
        float g2 = 1.f / (1.f + expf(-(red[t * 4 + 2] + hb[2])));
        float g3 = 1.f / (1.f + expf(-(red[t * 4 + 3] + hb[3])));
        float base = fd - g0 * fs - g1 * fl;
        size_t o = (size_t)t * BATCH * 128 + (size_t)b * 128;
        out[o + j0] = base - g2 * SLv[t][0] - g3 * LSv[t][0];
        out[o + j1] = base - g2 * SLv[t][1] - g3 * LSv[t][1];
    }
}

// ---------------- host ----------------
extern "C" void kernel_launch(void* const* d_in, const int* in_sizes, int n_in,
                              void* d_out, int out_size, void* d_ws, size_t ws_size,
                              hipStream_t stream)
{
    const int*   x    = (const int*)  d_in[0];
    const int*   dix  = (const int*)  d_in[1];
    const float* emb  = (const float*)d_in[2];
    const float* sW0  = (const float*)d_in[3];
    const float* sb0  = (const float*)d_in[4];
    const float* sW1  = (const float*)d_in[5];
    const float* sb1  = (const float*)d_in[6];
    const float* Dk0  = (const float*)d_in[7];
    const float* Db0  = (const float*)d_in[8];
    const float* DA0  = (const float*)d_in[9];
    const float* DB0  = (const float*)d_in[10];
    const float* Dlb0 = (const float*)d_in[11];
    const float* Tk0  = (const float*)d_in[12];
    const float* Tb0  = (const float*)d_in[13];
    const float* Tk1  = (const float*)d_in[14];
    const float* Tb1  = (const float*)d_in[15];
    const float* TA0  = (const float*)d_in[16];
    const float* TB0  = (const float*)d_in[17];
    const float* Tlb0 = (const float*)d_in[18];
    const float* TA1  = (const float*)d_in[19];
    const float* TB1  = (const float*)d_in[20];
    const float* Tlb1 = (const float*)d_in[21];
    const float* gW0  = (const float*)d_in[22];
    const float* gb0  = (const float*)d_in[23];
    const float* gW1  = (const float*)d_in[24];
    const float* gb1  = (const float*)d_in[25];
    const float* h0W  = (const float*)d_in[26];
    const float* h0b  = (const float*)d_in[27];
    const float* h1W  = (const float*)d_in[28];
    const float* h1b  = (const float*)d_in[29];

    hipFuncSetAttribute((const void*)k_gemm256<1, 1, 1>,
                        hipFuncAttributeMaxDynamicSharedMemorySize, 163840);
    hipFuncSetAttribute((const void*)k_gemm256<1, 1, 0>,
                        hipFuncAttributeMaxDynamicSharedMemorySize, 131072);

    char* ws = (char*)d_ws;
    size_t off = 0;
    auto alloc = [&](size_t bytes) -> void* {
        void* p = ws + off;
        off += (bytes + 255) & ~(size_t)255;
        return p;
    };
    unsigned short* W1t   = (unsigned short*)alloc((size_t)2048 * 2048 * 2);
    unsigned short* W2cat = (unsigned short*)alloc((size_t)1024 * 1024 * 2);
    unsigned short* Dk0t  = (unsigned short*)alloc((size_t)256 * 512 * 2);
    unsigned short* Tcat  = (unsigned short*)alloc((size_t)160 * 256 * 2);
    unsigned short* DA0b  = (unsigned short*)alloc((size_t)8 * 512 * 16 * 2);
    unsigned short* DB0b  = (unsigned short*)alloc((size_t)8 * 16 * 256 * 2);
    unsigned short* embB  = (unsigned short*)alloc((size_t)100000 * 64 * 2);
    float*          b1cat = (float*)alloc(2048 * 4);
    float*          b2cat = (float*)alloc(1024 * 4);
    float*          tb0c  = (float*)alloc(160 * 4);
    float*          Ybase = (float*)alloc((size_t)3 * BATCH * 160 * 4);   // Ys|Yl|Yd
    char* regB = (char*)alloc((size_t)BATCH * 2048 * 2);   // H, later SHARE/LORA/DDNN
    unsigned short* Xdnn  = (unsigned short*)alloc((size_t)BATCH * 512 * 2);
    unsigned short* Hyper = (unsigned short*)alloc((size_t)BATCH * 512 * 2);

    float* Ys = Ybase;                              // stream order: SHARE, LORA, DDNN
    float* Yl = Ybase + (size_t)BATCH * 160;
    float* Yd = Ybase + (size_t)2 * BATCH * 160;
    unsigned short* Hbuf  = (unsigned short*)regB;
    unsigned short* SHARE = (unsigned short*)regB;
    unsigned short* LORA  = SHARE + (size_t)BATCH * 256;
    unsigned short* DDNN  = LORA  + (size_t)BATCH * 256;

    // ONE prep launch: all transposes + biases + DA0b/DB0b + embB
    k_prep<<<11943, 256, 0, stream>>>(
        sW0, gW0, sW1, gW1, Dk0, Tk0, TA0,
        sb0, gb0, sb1, gb1, Tb0, DA0, DB0, emb,
        W1t, W2cat, Dk0t, Tcat, b1cat, b2cat, tb0c, DA0b, DB0b, embB);

    // GEMM1 (fused gather): emb[x] @ [sW0|gW0], relu -> H (B,2048) bf16
    k_gemm256<1, 1, 1><<<dim3(8, 64, 1), 512, 163840, stream>>>(
        embB, 0, 0, W1t, 2048, 0, b1cat, 0, Hbuf, 2048, 0, 2048, x, embB);
    // GEMM2 grouped (z=0: share-MLP, z=1: gate-hypernet): H halves -> Xdnn / Hyper
    k_gemm256<1, 1, 0><<<dim3(2, 64, 2), 512, 131072, stream>>>(
        Hbuf, 2048, 1024, W2cat, 1024, (long)512 * 1024, b2cat, 512,
        Xdnn, 512, (long)BATCH * 512, 512, nullptr, nullptr);
    // GEMM3: share = x_dnn @ Dk0 + Db0 (pre-act) bf16
    k_gemm<0, 1><<<dim3(2, 128), 256, 0, stream>>>(Xdnn, 512, Dk0t, Db0, SHARE, 256, 256, 512);
    // domain LoRA + ddnn
    k_dlora<<<BATCH / 4, 256, 0, stream>>>(Xdnn, dix, DA0b, DB0b, Dlb0, SHARE, LORA, DDNN);
    // stage i=0: one fused GEMM over 3 contiguous streams @ [Tk0|TA0[0]|TA0[1]]
    k_gemm<0, 0><<<dim3(2, 384), 256, 0, stream>>>(SHARE, 256, Tcat, tb0c, Ybase, 160, 160, 256);
    // fused tail
    k_tail<<<BATCH / 4, 256, 0, stream>>>(Yd, Ys, Yl, Hyper, TB0, Tlb0, Tk1, Tb1,
                                          TA1, TB1, Tlb1, h0W, h0b, h1W, h1b, (float*)d_out);
}

// Round 8
// 350.837 us; speedup vs baseline: 4.2948x; 1.0089x over previous
//
#include <hip/hip_runtime.h>
#include <hip/hip_bf16.h>

#define BATCH 16384

typedef __attribute__((ext_vector_type(4))) float f32x4;
typedef __attribute__((ext_vector_type(8))) short bf16x8;

__device__ inline float b2f(unsigned short u) {
    union { unsigned u; float f; } c; c.u = ((unsigned)u) << 16; return c.f;
}
__device__ inline unsigned short f2b(float f) {
    __hip_bfloat16 h = __float2bfloat16(f);
    return *(unsigned short*)&h;
}

#define GLL16(g, l)                                                            \
    __builtin_amdgcn_global_load_lds(                                          \
        (const __attribute__((address_space(1))) void*)(g),                    \
        (__attribute__((address_space(3))) void*)(l), 16, 0, 0)

// ---------------- mega-prep: all transposes + biases + bf16 conversions, ONE launch ----------------
__global__ __launch_bounds__(256) void k_prep(
    const float* __restrict__ sW0, const float* __restrict__ gW0,
    const float* __restrict__ sW1, const float* __restrict__ gW1,
    const float* __restrict__ Dk0, const float* __restrict__ Tk0,
    const float* __restrict__ TA0,
    const float* __restrict__ sb0, const float* __restrict__ gb0,
    const float* __restrict__ sb1, const float* __restrict__ gb1,
    const float* __restrict__ Tb0, const float* __restrict__ DA0,
    const float* __restrict__ DB0, const float* __restrict__ emb,
    unsigned short* __restrict__ W1t, unsigned short* __restrict__ W2cat,
    unsigned short* __restrict__ Dk0t, unsigned short* __restrict__ Tcat,
    float* __restrict__ b1cat, float* __restrict__ b2cat, float* __restrict__ tb0c,
    unsigned short* __restrict__ DA0b, unsigned short* __restrict__ DB0b,
    unsigned short* __restrict__ embB)
{
    int id = blockIdx.x;
    const int tid = threadIdx.x;
    __shared__ float t[32][33];
    auto tcvt = [&](const float* src, int K, int N, unsigned short* dst,
                    int dst_off, int dst_ld, int bx, int by) {
        int k0 = by * 32, n0 = bx * 32;
        int tx = tid & 31, ty = tid >> 5;   // 32 x 8
        #pragma unroll
        for (int s = 0; s < 32; s += 8) {
            int k = k0 + ty + s, n = n0 + tx;
            t[ty + s][tx] = (k < K && n < N) ? src[(size_t)k * N + n] : 0.f;
        }
        __syncthreads();
        #pragma unroll
        for (int s = 0; s < 32; s += 8) {
            int n = n0 + ty + s, k = k0 + tx;
            if (n < N && k < K)
                dst[(size_t)(dst_off + n) * dst_ld + k] = f2b(t[tx][ty + s]);
        }
    };
    if (id < 4096) { int z = id >> 11, rem = id & 2047;
        tcvt(z ? gW0 : sW0, 2048, 1024, W1t, z * 1024, 2048, rem & 31, rem >> 5); return; }
    id -= 4096;
    if (id < 1024) { int z = id >> 9, rem = id & 511;
        tcvt(z ? gW1 : sW1, 1024, 512, W2cat, z * 512, 1024, rem & 15, rem >> 4); return; }
    id -= 1024;
    if (id < 128) { tcvt(Dk0, 512, 256, Dk0t, 0, 512, id & 7, id >> 3); return; }
    id -= 128;
    if (id < 32)  { tcvt(Tk0, 256, 128, Tcat, 0, 256, id & 3, id >> 2); return; }
    id -= 32;
    if (id < 16)  { int z = id >> 3;
        tcvt(TA0 + z * 256 * 16, 256, 16, Tcat, 128 + z * 16, 256, 0, id & 7); return; }
    id -= 16;
    if (id < 397) {
        int i = id * 256 + tid;
        if (i < 1024)            { b1cat[i] = sb0[i]; return; }
        if (i < 2048)            { b1cat[i] = gb0[i - 1024]; return; }
        if (i < 2560)            { b2cat[i - 2048] = sb1[i - 2048]; return; }
        if (i < 3072)            { b2cat[i - 2560 + 512] = gb1[i - 2560]; return; }
        if (i < 3200)            { tb0c[i - 3072] = Tb0[i - 3072]; return; }
        if (i < 3232)            { tb0c[i - 3200 + 128] = 0.f; return; }
        i -= 3232;
        if (i < 65536)           { DA0b[i] = f2b(DA0[i]); return; }
        i -= 65536;
        if (i < 32768)           { DB0b[i] = f2b(DB0[i]); return; }
        return;
    }
    id -= 397;
    {   // embB: f32 (100000 x 64) -> bf16, 4 elems/thread
        int e = (id * 256 + tid) * 4;
        if (e < 100000 * 64) {
            float4 v = *(const float4*)(emb + e);
            ushort4 o = { f2b(v.x), f2b(v.y), f2b(v.z), f2b(v.w) };
            *(ushort4*)(embB + e) = o;
        }
    }
}

// ================= 256x256 fine-phase MFMA GEMM (+ fused gather, conflict-free idx) =====
// C(MxN) = A(MxK)*Bt(NxK)^T + bias, opt relu. Tile 256x256, BK=64 (2 kslices of 32),
// 512 thr (8 waves 2Mx4N). LDS: 2 dbuf slots x 64KB, XOR chunk swizzle p=c^(row&7)
// both-sides; 0 bank conflicts on fragments (r2-r5).
// GATHER=1: A rows are gathered embeddings. x-block (256x32 ints) is DMA'd linear into
// slot-1 scratch, transposed in LDS to xbT[tc][rr] (stride 256: read bank = rr&31,
// 8 banks x 8-lane broadcast = conflict-free), then consumed via REGISTER-prefetched
// indices: ixc[] (tile t+1) loaded during tile t-1, ixn[] fetched after ph0's STAGE.
// vmcnt audit unchanged: 4 vm-ops/STAGE, queue=8 at each VM4, never 0 (T4).
template<int RELU, int OUTBF16, int GATHER>
__global__ __launch_bounds__(512, 2) void k_gemm256(
    const unsigned short* __restrict__ A, int lda, long Az,
    const unsigned short* __restrict__ Bt, int K, long Bz,
    const float* __restrict__ bias, int biasz,
    void* __restrict__ C, int ldc, long Cz,
    int N, const int* __restrict__ xsrc, const unsigned short* __restrict__ embB)
{
    extern __shared__ char smem_raw[];
    const int NT = K >> 6;            // 64-wide K tiles
    const int tid  = threadIdx.x;
    const int lane = tid & 63;
    const int w    = tid >> 6;
    const int wr   = w >> 2, wc = w & 3;
    const int frow = lane & 15, kg = lane >> 4;
    const int z = blockIdx.z;
    A    += (size_t)z * Az;
    Bt   += (size_t)z * Bz;
    bias += (size_t)z * biasz;

    // XCD-aware bijective swizzle (nwg divisible by 8 for all our launches)
    const int gx  = gridDim.x;
    const int nwg = gx * gridDim.y;
    const int lin = blockIdx.y * gx + blockIdx.x;
    const int qq  = nwg >> 3;
    const int swz = (lin & 7) * qq + (lin >> 3);
    const int bx = swz % gx, by = swz / gx;
    const int row0 = by * 256, col0 = bx * 256;

    // staging: one kslice = 32KB = 4 gloads of 8KB (h=0..3) per thread.
    const int lch = (lane & 7) ^ ((lane >> 3) & 7);
    const int isA = (lch < 4);
    const int eoBase = lch * 8;                    // elem offset within embedding row (A)
    int* xbT = (int*)(smem_raw + 131072);          // 32KB transposed x-block (GATHER)
    int rrh[4];
    const unsigned short* gsrc[4];
    #pragma unroll
    for (int h = 0; h < 4; ++h) {
        int rr = h * 64 + w * 8 + (lane >> 3);
        rrh[h] = rr;
        if (isA) gsrc[h] = GATHER ? embB : A + (size_t)(row0 + rr) * lda + lch * 8;
        else     gsrc[h] = Bt + (size_t)min(col0 + rr, N - 1) * K + (lch - 4) * 8;
    }
    const int dBase = w * 1024;   // wave-uniform LDS offset within an 8KB gload block

    // fragment read offsets (bytes) within a kslice region; swizzled physical chunks
    const int pA = (kg ^ (frow & 7)) * 16;
    const int pB = ((4 + kg) ^ (frow & 7)) * 16;
    int aOff[8], bOff[4];
    #pragma unroll
    for (int m = 0; m < 8; ++m) aOff[m] = (wr * 128 + m * 16 + frow) * 128 + pA;
    #pragma unroll
    for (int n = 0; n < 4; ++n) bOff[n] = (wc * 64 + n * 16 + frow) * 128 + pB;

// STAGE for non-gather path (address from gsrc + linear tile offset)
#define STAGE(t_, ks_, slot_) do {                                              \
        int tc_ = min((int)(t_), NT - 1);                                       \
        int o_ = tc_ * 64 + (ks_) * 32;                                         \
        char* d_ = smem_raw + (slot_) * 65536 + (ks_) * 32768 + dBase;          \
        GLL16(gsrc[0] + o_, d_);                                                \
        GLL16(gsrc[1] + o_, d_ + 8192);                                         \
        GLL16(gsrc[2] + o_, d_ + 16384);                                        \
        GLL16(gsrc[3] + o_, d_ + 24576);                                        \
    } while (0)
// STAGE for gather path: A-lanes use register-prefetched indices ix_[]
#define STAGEX(ix_, tcb_, ks_, slot_) do {                                      \
        char* d_ = smem_raw + (slot_) * 65536 + (ks_) * 32768 + dBase;          \
        _Pragma("unroll")                                                       \
        for (int h_ = 0; h_ < 4; ++h_) {                                        \
            const unsigned short* sa_ = embB + (size_t)(ix_)[h_] * 64           \
                                        + (ks_) * 32 + eoBase;                  \
            const unsigned short* sb2_ = gsrc[h_] + (tcb_) * 64 + (ks_) * 32;   \
            GLL16(isA ? sa_ : sb2_, d_ + h_ * 8192);                            \
        }                                                                       \
    } while (0)
#define READS_B(sb_, ks_)                                                       \
        _Pragma("unroll")                                                       \
        for (int n = 0; n < 4; ++n)                                             \
            bfr[n] = *(const bf16x8*)(smem_raw + (sb_) + (ks_) * 32768 + bOff[n]);
#define READS_A(sb_, ks_, mh_)                                                  \
        _Pragma("unroll")                                                       \
        for (int mi = 0; mi < 4; ++mi)                                          \
            afr[mi] = *(const bf16x8*)(smem_raw + (sb_) + (ks_) * 32768 + aOff[(mh_) * 4 + mi]);
#define MFMA16(mh_) do {                                                        \
        __builtin_amdgcn_s_setprio(1);                                          \
        _Pragma("unroll")                                                       \
        for (int mi = 0; mi < 4; ++mi)                                          \
            _Pragma("unroll")                                                   \
            for (int n = 0; n < 4; ++n)                                         \
                acc[(mh_) * 4 + mi][n] = __builtin_amdgcn_mfma_f32_16x16x32_bf16( \
                    bfr[n], afr[mi], acc[(mh_) * 4 + mi][n], 0, 0, 0);          \
        __builtin_amdgcn_s_setprio(0);                                          \
    } while (0)
#define LGKM0 asm volatile("s_waitcnt lgkmcnt(0)" ::: "memory")
#define VM4   asm volatile("s_waitcnt vmcnt(4)" ::: "memory")
#define BAR   __builtin_amdgcn_s_barrier()

    f32x4 acc[8][4] = {};
    bf16x8 afr[4], bfr[4];
    int ixc[4] = {0, 0, 0, 0};

    if (GATHER) {
        // 1) DMA linear x-block (256x32 ints, 32KB) into slot-1 scratch
        const char* xs = (const char*)(xsrc + row0 * 32);
        #pragma unroll
        for (int r = 0; r < 4; ++r)
            GLL16(xs + r * 8192 + w * 1024 + lane * 16,
                  smem_raw + 65536 + r * 8192 + w * 1024);
        asm volatile("s_waitcnt vmcnt(0)" ::: "memory");
        __builtin_amdgcn_s_barrier();
        // 2) transpose to xbT[tc][rr] (stride 256 ints) for conflict-free reads
        const int* xlin = (const int*)(smem_raw + 65536);
        #pragma unroll
        for (int r = 0; r < 4; ++r) {
            int i = (r * 512 + tid) * 4;              // covers 8192 ints
            int rr_ = i >> 5, tc_ = i & 31;
            int4 vv = *(const int4*)(xlin + i);
            xbT[(tc_ + 0) * 256 + rr_] = vv.x;
            xbT[(tc_ + 1) * 256 + rr_] = vv.y;
            xbT[(tc_ + 2) * 256 + rr_] = vv.z;
            xbT[(tc_ + 3) * 256 + rr_] = vv.w;
        }
        asm volatile("s_waitcnt lgkmcnt(0)" ::: "memory");
        __builtin_amdgcn_s_barrier();
        // 3) indices for tile 0 (used now) and tile 1 (ixc)
        int ix0[4];
        #pragma unroll
        for (int h = 0; h < 4; ++h) ix0[h] = xbT[rrh[h]];
        STAGEX(ix0, 0, 0, 0); STAGEX(ix0, 0, 1, 0);
        int t1 = min(1, NT - 1);
        #pragma unroll
        for (int h = 0; h < 4; ++h) ixc[h] = xbT[t1 * 256 + rrh[h]];
    } else {
        STAGE(0, 0, 0); STAGE(0, 1, 0);
    }
    VM4; BAR;

    for (int t = 0; t < NT; ++t) {
        const int slot = t & 1, nslot = slot ^ 1;
        const int sb = slot * 65536;
        const int tcn = min(t + 1, NT - 1);
        int ixn[4];
        // ph0: ks0, mh0
        READS_B(sb, 0); READS_A(sb, 0, 0);
        if (GATHER) STAGEX(ixc, tcn, 0, nslot); else STAGE(t + 1, 0, nslot);
        if (GATHER) {
            int tc2 = min(t + 2, NT - 1);
            #pragma unroll
            for (int h = 0; h < 4; ++h) ixn[h] = xbT[tc2 * 256 + rrh[h]];
        }
        BAR; LGKM0; MFMA16(0); BAR;
        // ph1: ks0, mh1
        READS_A(sb, 0, 1);
        VM4;                       // publishes ks1(t)
        BAR; LGKM0; MFMA16(1); BAR;
        // ph2: ks1, mh0
        READS_B(sb, 1); READS_A(sb, 1, 0);
        if (GATHER) STAGEX(ixc, tcn, 1, nslot); else STAGE(t + 1, 1, nslot);
        BAR; LGKM0; MFMA16(0); BAR;
        // ph3: ks1, mh1
        READS_A(sb, 1, 1);
        VM4;                       // publishes ks0(t+1)
        BAR; LGKM0; MFMA16(1); BAR;
        if (GATHER) {
            #pragma unroll
            for (int h = 0; h < 4; ++h) ixc[h] = ixn[h];
        }
    }
#undef STAGE
#undef STAGEX
#undef READS_B
#undef READS_A
#undef MFMA16
#undef LGKM0
#undef VM4
#undef BAR

    // epilogue (swapped-operand layout): row = row0+wr*128+m*16+frow,
    // cols = col0+wc*64+n*16+kg*4 .. +3
    #pragma unroll
    for (int m = 0; m < 8; ++m) {
        int row = row0 + wr * 128 + m * 16 + frow;
        #pragma unroll
        for (int n = 0; n < 4; ++n) {
            int col = col0 + wc * 64 + n * 16 + kg * 4;
            float4 bv = *(const float4*)(bias + col);
            float v0 = acc[m][n][0] + bv.x, v1 = acc[m][n][1] + bv.y;
            float v2 = acc[m][n][2] + bv.z, v3 = acc[m][n][3] + bv.w;
            if (RELU) {
                v0 = fmaxf(v0, 0.f); v1 = fmaxf(v1, 0.f);
                v2 = fmaxf(v2, 0.f); v3 = fmaxf(v3, 0.f);
            }
            if (OUTBF16) {
                ushort4 o = { f2b(v0), f2b(v1), f2b(v2), f2b(v3) };
                *(ushort4*)((unsigned short*)C + (size_t)z * Cz + (size_t)row * ldc + col) = o;
            } else {
                float4 o = { v0, v1, v2, v3 };
                *(float4*)((float*)C + (size_t)z * Cz + (size_t)row * ldc + col) = o;
            }
        }
    }
}

// ---------------- 128x128 MFMA GEMM (m97 structure) for small GEMMs ----------------
template<int RELU, int OUTBF16>
__global__ __launch_bounds__(256) void k_gemm(
    const unsigned short* __restrict__ A, int lda,
    const unsigned short* __restrict__ Bt,         // N x K row-major, ldb = K
    const float* __restrict__ bias,
    void* __restrict__ C, int ldc,
    int N, int K)
{
    __shared__ __align__(16) unsigned short As[128 * 32];
    __shared__ __align__(16) unsigned short Bs[128 * 32];
    const int tid  = threadIdx.x;
    const int lane = tid & 63;
    const int w    = tid >> 6;
    const int wr   = w >> 1, wc = w & 1;
    const int row0 = blockIdx.y * 128;
    const int col0 = blockIdx.x * 128;
    const int frow = lane & 15;
    const int kg   = lane >> 4;
    const int sw   = kg ^ ((frow >> 1) & 3);

    const int srow = w * 32 + (lane >> 2);
    const int csw  = (lane & 3) ^ ((lane >> 3) & 3);
    const int br0  = min(col0 + srow, N - 1);
    const int br1  = min(col0 + srow + 16, N - 1);

    const unsigned short* a0 = A  + (size_t)(row0 + srow) * lda      + csw * 8;
    const unsigned short* a1 = A  + (size_t)(row0 + srow + 16) * lda + csw * 8;
    const unsigned short* b0 = Bt + (size_t)br0 * K + csw * 8;
    const unsigned short* b1 = Bt + (size_t)br1 * K + csw * 8;
    unsigned short* lA0 = As + (w * 2 + 0) * 512;
    unsigned short* lA1 = As + (w * 2 + 1) * 512;
    unsigned short* lB0 = Bs + (w * 2 + 0) * 512;
    unsigned short* lB1 = Bs + (w * 2 + 1) * 512;

    f32x4 acc[4][4] = {};

    for (int bk = 0; bk < K; bk += 32) {
        __syncthreads();
        GLL16(a0 + bk, lA0);
        GLL16(a1 + bk, lA1);
        GLL16(b0 + bk, lB0);
        GLL16(b1 + bk, lB1);
        __syncthreads();
        bf16x8 af[4], bfr[4];
        #pragma unroll
        for (int m = 0; m < 4; ++m)
            af[m] = *(const bf16x8*)&As[(wr * 64 + m * 16 + frow) * 32 + sw * 8];
        #pragma unroll
        for (int n = 0; n < 4; ++n)
            bfr[n] = *(const bf16x8*)&Bs[(wc * 64 + n * 16 + frow) * 32 + sw * 8];
        #pragma unroll
        for (int m = 0; m < 4; ++m)
            #pragma unroll
            for (int n = 0; n < 4; ++n)
                acc[m][n] = __builtin_amdgcn_mfma_f32_16x16x32_bf16(bfr[n], af[m], acc[m][n], 0, 0, 0);
    }

    // swapped-operand epilogue: row = row0+wr*64+m*16+frow, cols col0+wc*64+n*16+kg*4..+3
    #pragma unroll
    for (int m = 0; m < 4; ++m) {
        int row = row0 + wr * 64 + m * 16 + frow;
        #pragma unroll
        for (int n = 0; n < 4; ++n) {
            int col = col0 + wc * 64 + n * 16 + kg * 4;
            if (col >= N) continue;
            float4 bv = *(const float4*)(bias + col);
            float v0 = acc[m][n][0] + bv.x, v1 = acc[m][n][1] + bv.y;
            float v2 = acc[m][n][2] + bv.z, v3 = acc[m][n][3] + bv.w;
            if (RELU) {
                v0 = fmaxf(v0, 0.f); v1 = fmaxf(v1, 0.f);
                v2 = fmaxf(v2, 0.f); v3 = fmaxf(v3, 0.f);
            }
            if (OUTBF16) {
                ushort4 o = { f2b(v0), f2b(v1), f2b(v2), f2b(v3) };
                *(ushort4*)((unsigned short*)C + (size_t)row * ldc + col) = o;
            } else {
                float4 o = { v0, v1, v2, v3 };
                *(float4*)((float*)C + (size_t)row * ldc + col) = o;
            }
        }
    }
}

// ---------------- per-sample domain LoRA (bf16 weights) ----------------
__global__ __launch_bounds__(256) void k_dlora(
    const unsigned short* __restrict__ Xdnn, const int* __restrict__ d,
    const unsigned short* __restrict__ DA0b, const unsigned short* __restrict__ DB0b,
    const float* __restrict__ Dlb0,
    const unsigned short* __restrict__ SHARE,
    unsigned short* __restrict__ LORA, unsigned short* __restrict__ DDNN)
{
    int w = threadIdx.x >> 6, lane = threadIdx.x & 63;
    int b = blockIdx.x * 4 + w;
    int dom = d[b];
    uint4 raw = *(const uint4*)(Xdnn + (size_t)b * 512 + lane * 8);
    const unsigned short* pr = (const unsigned short*)&raw;
    float xv[8];
    #pragma unroll
    for (int j = 0; j < 8; ++j) xv[j] = b2f(pr[j]);

    const unsigned short* Ap = DA0b + ((size_t)dom * 512 + lane * 8) * 16;
    float v[16];
    #pragma unroll
    for (int r = 0; r < 16; ++r) v[r] = 0.f;
    #pragma unroll
    for (int j = 0; j < 8; ++j) {
        uint4 a0 = *(const uint4*)(Ap + j * 16);
        uint4 a1 = *(const uint4*)(Ap + j * 16 + 8);
        const unsigned short* ap = (const unsigned short*)&a0;
        const unsigned short* aq = (const unsigned short*)&a1;
        float xj = xv[j];
        #pragma unroll
        for (int r = 0; r < 8; ++r) v[r]     += xj * b2f(ap[r]);
        #pragma unroll
        for (int r = 0; r < 8; ++r) v[r + 8] += xj * b2f(aq[r]);
    }
    #pragma unroll
    for (int s = 1; s < 64; s <<= 1) {
        #pragma unroll
        for (int r = 0; r < 16; ++r) v[r] += __shfl_xor(v[r], s, 64);
    }
    const unsigned short* Bp = DB0b + (size_t)dom * 16 * 256;
    const float* lbp = Dlb0 + (size_t)dom * 256;
    #pragma unroll
    for (int c = 0; c < 4; ++c) {
        int o = lane + c * 64;
        float a = lbp[o];
        #pragma unroll
        for (int r = 0; r < 16; ++r) a += v[r] * b2f(Bp[r * 256 + o]);
        float sh = b2f(SHARE[(size_t)b * 256 + o]);
        LORA[(size_t)b * 256 + o] = f2b(a);
        DDNN[(size_t)b * 256 + o] = f2b(fmaxf(sh + a, 0.f));
    }
}

// ---------------- fused tail ----------------
__global__ __launch_bounds__(256) void k_tail(
    const float* __restrict__ Yd, const float* __restrict__ Ys, const float* __restrict__ Yl,
    const unsigned short* __restrict__ Hyper,
    const float* __restrict__ TB0, const float* __restrict__ Tlb0,
    const float* __restrict__ Tk1, const float* __restrict__ Tb1,
    const float* __restrict__ TA1, const float* __restrict__ TB1, const float* __restrict__ Tlb1,
    const float* __restrict__ h0W, const float* __restrict__ h0b,
    const float* __restrict__ h1W, const float* __restrict__ h1b,
    float* __restrict__ out)
{
    __shared__ float sTB0[2][16][128];
    __shared__ float sTlb0[2][128];
    __shared__ float sTk1[128];
    __shared__ float sWeff[2][128];
    __shared__ float sY[4][3][160];
    const int tid = threadIdx.x;

    for (int i = tid; i < 4096; i += 256) ((float*)sTB0)[i] = TB0[i];
    if (tid < 256) ((float*)sTlb0)[tid] = Tlb0[tid];
    if (tid < 128) sTk1[tid] = Tk1[tid];
    {
        int t = tid >> 7, j = tid & 127;
        float a = 0.f;
        #pragma unroll
        for (int r = 0; r < 16; ++r) a += TA1[((size_t)t * 128 + j) * 16 + r] * TB1[t * 16 + r];
        sWeff[t][j] = a;
    }
    const float* Yp[3] = {Yd, Ys, Yl};
    int b0 = blockIdx.x * 4;
    for (int i = tid; i < 4 * 3 * 160; i += 256) {
        int s = i / 480, rem = i % 480, st = rem / 160, idx = rem % 160;
        sY[s][st][idx] = Yp[st][(size_t)(b0 + s) * 160 + idx];
    }
    __syncthreads();

    int w = tid >> 6, lane = tid & 63;
    int b = b0 + w;
    const float* yd = sY[w][0];
    const float* ys = sY[w][1];
    const float* yl = sY[w][2];
    int j0 = lane, j1 = lane + 64;

    uint4 hraw = *(const uint4*)(Hyper + (size_t)b * 512 + lane * 8);
    const unsigned short* hp = (const unsigned short*)&hraw;
    float hv[8];
    #pragma unroll
    for (int j = 0; j < 8; ++j) hv[j] = b2f(hp[j]);

    float red[14];
    #pragma unroll
    for (int k = 0; k < 14; ++k) red[k] = 0.f;
    #pragma unroll
    for (int j = 0; j < 8; ++j) {
        float4 w0 = *(const float4*)(h0W + (size_t)(lane * 8 + j) * 4);
        float4 w1 = *(const float4*)(h1W + (size_t)(lane * 8 + j) * 4);
        red[0] += hv[j] * w0.x; red[1] += hv[j] * w0.y; red[2] += hv[j] * w0.z; red[3] += hv[j] * w0.w;
        red[4] += hv[j] * w1.x; red[5] += hv[j] * w1.y; red[6] += hv[j] * w1.z; red[7] += hv[j] * w1.w;
    }

    float SLv[2][2], LSv[2][2];
    #pragma unroll
    for (int t = 0; t < 2; ++t) {
        float lb0 = sTlb0[t][j0], lb1 = sTlb0[t][j1];
        float dl0 = lb0, dl1 = lb1, sl0 = lb0, sl1 = lb1, ll0 = lb0, ll1 = lb1;
        #pragma unroll
        for (int r = 0; r < 16; ++r) {
            float w0v = sTB0[t][r][j0], w1v = sTB0[t][r][j1];
            float ud = yd[128 + t * 16 + r];
            float us = ys[128 + t * 16 + r];
            float ul = yl[128 + t * 16 + r];
            dl0 += ud * w0v; dl1 += ud * w1v;
            sl0 += us * w0v; sl1 += us * w1v;
            ll0 += ul * w0v; ll1 += ul * w1v;
        }
        float D0 = yd[j0] + dl0, D1 = yd[j1] + dl1;
        float S0 = ys[j0],       S1 = ys[j1];
        float L0 = ll0,          L1 = ll1;
        float sl_0 = sl0, sl_1 = sl1;
        float ls_0 = yl[j0], ls_1 = yl[j1];
        if (t == 0) {
            D0 = fmaxf(D0, 0.f); D1 = fmaxf(D1, 0.f);
            S0 = fmaxf(S0, 0.f); S1 = fmaxf(S1, 0.f);
            L0 = fmaxf(L0, 0.f); L1 = fmaxf(L1, 0.f);
            sl_0 = fmaxf(sl_0, 0.f); sl_1 = fmaxf(sl_1, 0.f);
            ls_0 = fmaxf(ls_0, 0.f); ls_1 = fmaxf(ls_1, 0.f);
        }
        SLv[t][0] = sl_0; SLv[t][1] = sl_1;
        LSv[t][0] = ls_0; LSv[t][1] = ls_1;
        float we0 = sWeff[t][j0], we1 = sWeff[t][j1];
        float tk0 = sTk1[j0],     tk1v = sTk1[j1];
        red[8 + t * 3 + 0] = D0 * (tk0 + we0) + D1 * (tk1v + we1);
        red[8 + t * 3 + 1] = S0 * tk0 + S1 * tk1v;
        red[8 + t * 3 + 2] = L0 * we0 + L1 * we1;
    }

    #pragma unroll
    for (int s = 1; s < 64; s <<= 1) {
        #pragma unroll
        for (int k = 0; k < 14; ++k) red[k] += __shfl_xor(red[k], s, 64);
    }

    float Tb1v = Tb1[0];
    #pragma unroll
    for (int t = 0; t < 2; ++t) {
        float fd = red[8 + t * 3 + 0] + Tb1v + Tlb1[t];
        float fs = red[8 + t * 3 + 1] + Tb1v;
        float fl = red[8 + t * 3 + 2] + Tlb1[t];
        const float* hb = t ? h1b : h0b;
        float g0 = 1.f / (1.f + expf(-(red[t * 4 + 0] + hb[0])));
        float g1 = 1.f / (1.f + expf(-(red[t * 4 + 1] + hb[1])));
        float g2 = 1.f / (1.f + expf(-(red[t * 4 + 2] + hb[2])));
        float g3 = 1.f / (1.f + expf(-(red[t * 4 + 3] + hb[3])));
        float base = fd - g0 * fs - g1 * fl;
        size_t o = (size_t)t * BATCH * 128 + (size_t)b * 128;
        out[o + j0] = base - g2 * SLv[t][0] - g3 * LSv[t][0];
        out[o + j1] = base - g2 * SLv[t][1] - g3 * LSv[t][1];
    }
}

// ---------------- host ----------------
extern "C" void kernel_launch(void* const* d_in, const int* in_sizes, int n_in,
                              void* d_out, int out_size, void* d_ws, size_t ws_size,
                              hipStream_t stream)
{
    const int*   x    = (const int*)  d_in[0];
    const int*   dix  = (const int*)  d_in[1];
    const float* emb  = (const float*)d_in[2];
    const float* sW0  = (const float*)d_in[3];
    const float* sb0  = (const float*)d_in[4];
    const float* sW1  = (const float*)d_in[5];
    const float* sb1  = (const float*)d_in[6];
    const float* Dk0  = (const float*)d_in[7];
    const float* Db0  = (const float*)d_in[8];
    const float* DA0  = (const float*)d_in[9];
    const float* DB0  = (const float*)d_in[10];
    const float* Dlb0 = (const float*)d_in[11];
    const float* Tk0  = (const float*)d_in[12];
    const float* Tb0  = (const float*)d_in[13];
    const float* Tk1  = (const float*)d_in[14];
    const float* Tb1  = (const float*)d_in[15];
    const float* TA0  = (const float*)d_in[16];
    const float* TB0  = (const float*)d_in[17];
    const float* Tlb0 = (const float*)d_in[18];
    const float* TA1  = (const float*)d_in[19];
    const float* TB1  = (const float*)d_in[20];
    const float* Tlb1 = (const float*)d_in[21];
    const float* gW0  = (const float*)d_in[22];
    const float* gb0  = (const float*)d_in[23];
    const float* gW1  = (const float*)d_in[24];
    const float* gb1  = (const float*)d_in[25];
    const float* h0W  = (const float*)d_in[26];
    const float* h0b  = (const float*)d_in[27];
    const float* h1W  = (const float*)d_in[28];
    const float* h1b  = (const float*)d_in[29];

    hipFuncSetAttribute((const void*)k_gemm256<1, 1, 1>,
                        hipFuncAttributeMaxDynamicSharedMemorySize, 163840);
    hipFuncSetAttribute((const void*)k_gemm256<1, 1, 0>,
                        hipFuncAttributeMaxDynamicSharedMemorySize, 131072);

    char* ws = (char*)d_ws;
    size_t off = 0;
    auto alloc = [&](size_t bytes) -> void* {
        void* p = ws + off;
        off += (bytes + 255) & ~(size_t)255;
        return p;
    };
    unsigned short* W1t   = (unsigned short*)alloc((size_t)2048 * 2048 * 2);
    unsigned short* W2cat = (unsigned short*)alloc((size_t)1024 * 1024 * 2);
    unsigned short* Dk0t  = (unsigned short*)alloc((size_t)256 * 512 * 2);
    unsigned short* Tcat  = (unsigned short*)alloc((size_t)160 * 256 * 2);
    unsigned short* DA0b  = (unsigned short*)alloc((size_t)8 * 512 * 16 * 2);
    unsigned short* DB0b  = (unsigned short*)alloc((size_t)8 * 16 * 256 * 2);
    unsigned short* embB  = (unsigned short*)alloc((size_t)100000 * 64 * 2);
    float*          b1cat = (float*)alloc(2048 * 4);
    float*          b2cat = (float*)alloc(1024 * 4);
    float*          tb0c  = (float*)alloc(160 * 4);
    float*          Ybase = (float*)alloc((size_t)3 * BATCH * 160 * 4);   // Ys|Yl|Yd
    char* regB = (char*)alloc((size_t)BATCH * 2048 * 2);   // H, later SHARE/LORA/DDNN
    unsigned short* Xdnn  = (unsigned short*)alloc((size_t)BATCH * 512 * 2);
    unsigned short* Hyper = (unsigned short*)alloc((size_t)BATCH * 512 * 2);

    float* Ys = Ybase;                              // stream order: SHARE, LORA, DDNN
    float* Yl = Ybase + (size_t)BATCH * 160;
    float* Yd = Ybase + (size_t)2 * BATCH * 160;
    unsigned short* Hbuf  = (unsigned short*)regB;
    unsigned short* SHARE = (unsigned short*)regB;
    unsigned short* LORA  = SHARE + (size_t)BATCH * 256;
    unsigned short* DDNN  = LORA  + (size_t)BATCH * 256;

    // ONE prep launch: all transposes + biases + DA0b/DB0b + embB
    k_prep<<<11943, 256, 0, stream>>>(
        sW0, gW0, sW1, gW1, Dk0, Tk0, TA0,
        sb0, gb0, sb1, gb1, Tb0, DA0, DB0, emb,
        W1t, W2cat, Dk0t, Tcat, b1cat, b2cat, tb0c, DA0b, DB0b, embB);

    // GEMM1 (fused gather, conflict-free idx): emb[x] @ [sW0|gW0], relu -> H (B,2048) bf16
    k_gemm256<1, 1, 1><<<dim3(8, 64, 1), 512, 163840, stream>>>(
        embB, 0, 0, W1t, 2048, 0, b1cat, 0, Hbuf, 2048, 0, 2048, x, embB);
    // GEMM2 grouped (z=0: share-MLP, z=1: gate-hypernet): H halves -> Xdnn / Hyper
    k_gemm256<1, 1, 0><<<dim3(2, 64, 2), 512, 131072, stream>>>(
        Hbuf, 2048, 1024, W2cat, 1024, (long)512 * 1024, b2cat, 512,
        Xdnn, 512, (long)BATCH * 512, 512, nullptr, nullptr);
    // GEMM3: share = x_dnn @ Dk0 + Db0 (pre-act) bf16
    k_gemm<0, 1><<<dim3(2, 128), 256, 0, stream>>>(Xdnn, 512, Dk0t, Db0, SHARE, 256, 256, 512);
    // domain LoRA + ddnn
    k_dlora<<<BATCH / 4, 256, 0, stream>>>(Xdnn, dix, DA0b, DB0b, Dlb0, SHARE, LORA, DDNN);
    // stage i=0: one fused GEMM over 3 contiguous streams @ [Tk0|TA0[0]|TA0[1]]
    k_gemm<0, 0><<<dim3(2, 384), 256, 0, stream>>>(SHARE, 256, Tcat, tb0c, Ybase, 160, 160, 256);
    // fused tail
    k_tail<<<BATCH / 4, 256, 0, stream>>>(Yd, Ys, Yl, Hyper, TB0, Tlb0, Tk1, Tb1,
                                          TA1, TB1, Tlb1, h0W, h0b, h1W, h1b, (float*)d_out);
}

// Round 9
// 344.713 us; speedup vs baseline: 4.3711x; 1.0178x over previous
//
#include <hip/hip_runtime.h>
#include <hip/hip_bf16.h>

#define BATCH 16384

typedef __attribute__((ext_vector_type(4))) float f32x4;
typedef __attribute__((ext_vector_type(8))) short bf16x8;

__device__ inline float b2f(unsigned short u) {
    union { unsigned u; float f; } c; c.u = ((unsigned)u) << 16; return c.f;
}
__device__ inline unsigned short f2b(float f) {
    __hip_bfloat16 h = __float2bfloat16(f);
    return *(unsigned short*)&h;
}

#define GLL16(g, l)                                                            \
    __builtin_amdgcn_global_load_lds(                                          \
        (const __attribute__((address_space(1))) void*)(g),                    \
        (__attribute__((address_space(3))) void*)(l), 16, 0, 0)

// ---------------- mega-prep: all transposes + biases + bf16 conversions, ONE launch ----------------
__global__ __launch_bounds__(256) void k_prep(
    const float* __restrict__ sW0, const float* __restrict__ gW0,
    const float* __restrict__ sW1, const float* __restrict__ gW1,
    const float* __restrict__ Dk0, const float* __restrict__ Tk0,
    const float* __restrict__ TA0,
    const float* __restrict__ sb0, const float* __restrict__ gb0,
    const float* __restrict__ sb1, const float* __restrict__ gb1,
    const float* __restrict__ Tb0, const float* __restrict__ DA0,
    const float* __restrict__ DB0, const float* __restrict__ emb,
    unsigned short* __restrict__ W1t, unsigned short* __restrict__ W2cat,
    unsigned short* __restrict__ Dk0t, unsigned short* __restrict__ Tcat,
    float* __restrict__ b1cat, float* __restrict__ b2cat, float* __restrict__ tb0c,
    unsigned short* __restrict__ DA0b, unsigned short* __restrict__ DB0b,
    unsigned short* __restrict__ embB)
{
    int id = blockIdx.x;
    const int tid = threadIdx.x;
    __shared__ float t[32][33];
    auto tcvt = [&](const float* src, int K, int N, unsigned short* dst,
                    int dst_off, int dst_ld, int bx, int by) {
        int k0 = by * 32, n0 = bx * 32;
        int tx = tid & 31, ty = tid >> 5;   // 32 x 8
        #pragma unroll
        for (int s = 0; s < 32; s += 8) {
            int k = k0 + ty + s, n = n0 + tx;
            t[ty + s][tx] = (k < K && n < N) ? src[(size_t)k * N + n] : 0.f;
        }
        __syncthreads();
        #pragma unroll
        for (int s = 0; s < 32; s += 8) {
            int n = n0 + ty + s, k = k0 + tx;
            if (n < N && k < K)
                dst[(size_t)(dst_off + n) * dst_ld + k] = f2b(t[tx][ty + s]);
        }
    };
    if (id < 4096) { int z = id >> 11, rem = id & 2047;
        tcvt(z ? gW0 : sW0, 2048, 1024, W1t, z * 1024, 2048, rem & 31, rem >> 5); return; }
    id -= 4096;
    if (id < 1024) { int z = id >> 9, rem = id & 511;
        tcvt(z ? gW1 : sW1, 1024, 512, W2cat, z * 512, 1024, rem & 15, rem >> 4); return; }
    id -= 1024;
    if (id < 128) { tcvt(Dk0, 512, 256, Dk0t, 0, 512, id & 7, id >> 3); return; }
    id -= 128;
    if (id < 32)  { tcvt(Tk0, 256, 128, Tcat, 0, 256, id & 3, id >> 2); return; }
    id -= 32;
    if (id < 16)  { int z = id >> 3;
        tcvt(TA0 + z * 256 * 16, 256, 16, Tcat, 128 + z * 16, 256, 0, id & 7); return; }
    id -= 16;
    if (id < 397) {
        int i = id * 256 + tid;
        if (i < 1024)            { b1cat[i] = sb0[i]; return; }
        if (i < 2048)            { b1cat[i] = gb0[i - 1024]; return; }
        if (i < 2560)            { b2cat[i - 2048] = sb1[i - 2048]; return; }
        if (i < 3072)            { b2cat[i - 2560 + 512] = gb1[i - 2560]; return; }
        if (i < 3200)            { tb0c[i - 3072] = Tb0[i - 3072]; return; }
        if (i < 3232)            { tb0c[i - 3200 + 128] = 0.f; return; }
        i -= 3232;
        if (i < 65536)           { DA0b[i] = f2b(DA0[i]); return; }
        i -= 65536;
        if (i < 32768)           { DB0b[i] = f2b(DB0[i]); return; }
        return;
    }
    id -= 397;
    {   // embB: f32 (100000 x 64) -> bf16, 4 elems/thread
        int e = (id * 256 + tid) * 4;
        if (e < 100000 * 64) {
            float4 v = *(const float4*)(emb + e);
            ushort4 o = { f2b(v.x), f2b(v.y), f2b(v.z), f2b(v.w) };
            *(ushort4*)(embB + e) = o;
        }
    }
}

// ================= 256x256 MFMA GEMM — minimal-barrier, compiler-scheduled ====================
// C(MxN) = A(MxK)*Bt(NxK)^T + bias, opt relu. Tile 256x256, BK=64 (2 kslices of 32),
// 512 thr (8 waves 2Mx4N). LDS: 2 dbuf slots x 64KB, XOR chunk swizzle p=c^(row&7)
// both-sides; 0 fragment conflicts (r2-r8).
// Sync: exactly 2 points per BK=64 tile: {vmcnt(4) ; asm s_barrier("memory")}.
// NO lgkmcnt(0) pins — compiler emits fine-grained lgkmcnt interleaved with MFMA (m97).
// Per half-tile: 12 ds_reads + STAGE next kslice (4 gload_lds) + 32 MFMA, all
// compiler-interleaved. FIFO audit (4 loads/stage/thread): steady-state queue at each
// VM4 = 8; oldest 4 = the kslice the following barrier publishes. vmcnt never 0 (T4).
// GATHER=1: A rows gathered from embB via LDS-transposed x-block xbT with involution
// idx = tc*256 + (rr ^ (tc&31)) (write+read; writes <=2 lanes/bank = free, reads bcast);
// indices register-prefetched one tile ahead (ixc/ixn).
template<int RELU, int OUTBF16, int GATHER>
__global__ __launch_bounds__(512, 2) void k_gemm256(
    const unsigned short* __restrict__ A, int lda, long Az,
    const unsigned short* __restrict__ Bt, int K, long Bz,
    const float* __restrict__ bias, int biasz,
    void* __restrict__ C, int ldc, long Cz,
    int N, const int* __restrict__ xsrc, const unsigned short* __restrict__ embB)
{
    extern __shared__ char smem_raw[];
    const int NT = K >> 6;            // 64-wide K tiles
    const int tid  = threadIdx.x;
    const int lane = tid & 63;
    const int w    = tid >> 6;
    const int wr   = w >> 2, wc = w & 3;
    const int frow = lane & 15, kg = lane >> 4;
    const int z = blockIdx.z;
    A    += (size_t)z * Az;
    Bt   += (size_t)z * Bz;
    bias += (size_t)z * biasz;

    // XCD-aware bijective swizzle (nwg divisible by 8 for all our launches)
    const int gx  = gridDim.x;
    const int nwg = gx * gridDim.y;
    const int lin = blockIdx.y * gx + blockIdx.x;
    const int qq  = nwg >> 3;
    const int swz = (lin & 7) * qq + (lin >> 3);
    const int bx = swz % gx, by = swz / gx;
    const int row0 = by * 256, col0 = bx * 256;

    // staging: one kslice = 32KB = 4 gloads of 8KB (h=0..3) per thread.
    const int lch = (lane & 7) ^ ((lane >> 3) & 7);
    const int isA = (lch < 4);
    const int eoBase = lch * 8;                    // elem offset within embedding row (A)
    int* xbT = (int*)(smem_raw + 131072);          // 32KB transposed x-block (GATHER)
    int rrh[4];
    const unsigned short* gsrc[4];
    #pragma unroll
    for (int h = 0; h < 4; ++h) {
        int rr = h * 64 + w * 8 + (lane >> 3);
        rrh[h] = rr;
        if (isA) gsrc[h] = GATHER ? embB : A + (size_t)(row0 + rr) * lda + lch * 8;
        else     gsrc[h] = Bt + (size_t)min(col0 + rr, N - 1) * K + (lch - 4) * 8;
    }
    const int dBase = w * 1024;   // wave-uniform LDS offset within an 8KB gload block

    // fragment read offsets (bytes) within a kslice region; swizzled physical chunks
    const int pA = (kg ^ (frow & 7)) * 16;
    const int pB = ((4 + kg) ^ (frow & 7)) * 16;
    int aOff[8], bOff[4];
    #pragma unroll
    for (int m = 0; m < 8; ++m) aOff[m] = (wr * 128 + m * 16 + frow) * 128 + pA;
    #pragma unroll
    for (int n = 0; n < 4; ++n) bOff[n] = (wc * 64 + n * 16 + frow) * 128 + pB;

#define STAGE(t_, ks_, slot_) do {                                              \
        int tc_ = min((int)(t_), NT - 1);                                       \
        int o_ = tc_ * 64 + (ks_) * 32;                                         \
        char* d_ = smem_raw + (slot_) * 65536 + (ks_) * 32768 + dBase;          \
        GLL16(gsrc[0] + o_, d_);                                                \
        GLL16(gsrc[1] + o_, d_ + 8192);                                         \
        GLL16(gsrc[2] + o_, d_ + 16384);                                        \
        GLL16(gsrc[3] + o_, d_ + 24576);                                        \
    } while (0)
#define STAGEX(ix_, tcb_, ks_, slot_) do {                                      \
        char* d_ = smem_raw + (slot_) * 65536 + (ks_) * 32768 + dBase;          \
        _Pragma("unroll")                                                       \
        for (int h_ = 0; h_ < 4; ++h_) {                                        \
            const unsigned short* sa_ = embB + (size_t)(ix_)[h_] * 64           \
                                        + (ks_) * 32 + eoBase;                  \
            const unsigned short* sb2_ = gsrc[h_] + (tcb_) * 64 + (ks_) * 32;   \
            GLL16(isA ? sa_ : sb2_, d_ + h_ * 8192);                            \
        }                                                                       \
    } while (0)
#define READS(sb_, ks_) do {                                                    \
        _Pragma("unroll")                                                       \
        for (int n = 0; n < 4; ++n)                                             \
            bfr[n] = *(const bf16x8*)(smem_raw + (sb_) + (ks_) * 32768 + bOff[n]); \
        _Pragma("unroll")                                                       \
        for (int mi = 0; mi < 8; ++mi)                                          \
            afr[mi] = *(const bf16x8*)(smem_raw + (sb_) + (ks_) * 32768 + aOff[mi]); \
    } while (0)
#define MFMA32() do {                                                           \
        __builtin_amdgcn_s_setprio(1);                                          \
        _Pragma("unroll")                                                       \
        for (int mi = 0; mi < 8; ++mi)                                          \
            _Pragma("unroll")                                                   \
            for (int n = 0; n < 4; ++n)                                         \
                acc[mi][n] = __builtin_amdgcn_mfma_f32_16x16x32_bf16(           \
                    bfr[n], afr[mi], acc[mi][n], 0, 0, 0);                      \
        __builtin_amdgcn_s_setprio(0);                                          \
    } while (0)
#define VM4   asm volatile("s_waitcnt vmcnt(4)" ::: "memory")
#define BARM  asm volatile("s_barrier" ::: "memory")

    f32x4 acc[8][4] = {};
    bf16x8 afr[8], bfr[4];
    int ixc[4] = {0, 0, 0, 0};

    if (GATHER) {
        // 1) DMA linear x-block (256x32 ints, 32KB) into slot-1 scratch
        const char* xs = (const char*)(xsrc + row0 * 32);
        #pragma unroll
        for (int r = 0; r < 4; ++r)
            GLL16(xs + r * 8192 + w * 1024 + lane * 16,
                  smem_raw + 65536 + r * 8192 + w * 1024);
        asm volatile("s_waitcnt vmcnt(0)" ::: "memory");
        BARM;
        // 2) transpose to xbT with involution idx = tc*256 + (rr ^ (tc&31))
        const int* xlin = (const int*)(smem_raw + 65536);
        #pragma unroll
        for (int r = 0; r < 4; ++r) {
            int i = (r * 512 + tid) * 4;              // covers 8192 ints
            int rr_ = i >> 5, tc_ = i & 31;
            int4 vv = *(const int4*)(xlin + i);
            xbT[(tc_ + 0) * 256 + (rr_ ^ ((tc_ + 0) & 31))] = vv.x;
            xbT[(tc_ + 1) * 256 + (rr_ ^ ((tc_ + 1) & 31))] = vv.y;
            xbT[(tc_ + 2) * 256 + (rr_ ^ ((tc_ + 2) & 31))] = vv.z;
            xbT[(tc_ + 3) * 256 + (rr_ ^ ((tc_ + 3) & 31))] = vv.w;
        }
        asm volatile("s_waitcnt lgkmcnt(0)" ::: "memory");
        BARM;
        // 3) indices for tile 0 (used now) and tile 1 (ixc)
        int ix0[4];
        #pragma unroll
        for (int h = 0; h < 4; ++h) ix0[h] = xbT[rrh[h]];   // tc=0: rr^0
        STAGEX(ix0, 0, 0, 0); STAGEX(ix0, 0, 1, 0);
        int t1 = min(1, NT - 1);
        #pragma unroll
        for (int h = 0; h < 4; ++h) ixc[h] = xbT[t1 * 256 + (rrh[h] ^ (t1 & 31))];
    } else {
        STAGE(0, 0, 0); STAGE(0, 1, 0);
    }
    VM4; BARM;        // publishes tile0 ks0; ks1 in flight

    for (int t = 0; t < NT; ++t) {
        const int slot = t & 1, nslot = slot ^ 1;
        const int sb = slot * 65536;
        const int tcn = min(t + 1, NT - 1);
        int ixn[4];
        // half 0: reads ks0 + stage ks0(t+1) + 32 MFMA, compiler-interleaved
        READS(sb, 0);
        if (GATHER) STAGEX(ixc, tcn, 0, nslot); else STAGE(t + 1, 0, nslot);
        if (GATHER) {
            int tc2 = min(t + 2, NT - 1);
            #pragma unroll
            for (int h = 0; h < 4; ++h) ixn[h] = xbT[tc2 * 256 + (rrh[h] ^ (tc2 & 31))];
        }
        MFMA32();
        VM4; BARM;    // publishes ks1(t)
        // half 1
        READS(sb, 1);
        if (GATHER) STAGEX(ixc, tcn, 1, nslot); else STAGE(t + 1, 1, nslot);
        MFMA32();
        VM4; BARM;    // publishes ks0(t+1)
        if (GATHER) {
            #pragma unroll
            for (int h = 0; h < 4; ++h) ixc[h] = ixn[h];
        }
    }
#undef STAGE
#undef STAGEX
#undef READS
#undef MFMA32
#undef VM4
#undef BARM

    // epilogue (swapped-operand layout): row = row0+wr*128+m*16+frow,
    // cols = col0+wc*64+n*16+kg*4 .. +3
    #pragma unroll
    for (int m = 0; m < 8; ++m) {
        int row = row0 + wr * 128 + m * 16 + frow;
        #pragma unroll
        for (int n = 0; n < 4; ++n) {
            int col = col0 + wc * 64 + n * 16 + kg * 4;
            float4 bv = *(const float4*)(bias + col);
            float v0 = acc[m][n][0] + bv.x, v1 = acc[m][n][1] + bv.y;
            float v2 = acc[m][n][2] + bv.z, v3 = acc[m][n][3] + bv.w;
            if (RELU) {
                v0 = fmaxf(v0, 0.f); v1 = fmaxf(v1, 0.f);
                v2 = fmaxf(v2, 0.f); v3 = fmaxf(v3, 0.f);
            }
            if (OUTBF16) {
                ushort4 o = { f2b(v0), f2b(v1), f2b(v2), f2b(v3) };
                *(ushort4*)((unsigned short*)C + (size_t)z * Cz + (size_t)row * ldc + col) = o;
            } else {
                float4 o = { v0, v1, v2, v3 };
                *(float4*)((float*)C + (size_t)z * Cz + (size_t)row * ldc + col) = o;
            }
        }
    }
}

// ---------------- 128x128 MFMA GEMM (m97 structure) for small GEMMs ----------------
template<int RELU, int OUTBF16>
__global__ __launch_bounds__(256) void k_gemm(
    const unsigned short* __restrict__ A, int lda,
    const unsigned short* __restrict__ Bt,         // N x K row-major, ldb = K
    const float* __restrict__ bias,
    void* __restrict__ C, int ldc,
    int N, int K)
{
    __shared__ __align__(16) unsigned short As[128 * 32];
    __shared__ __align__(16) unsigned short Bs[128 * 32];
    const int tid  = threadIdx.x;
    const int lane = tid & 63;
    const int w    = tid >> 6;
    const int wr   = w >> 1, wc = w & 1;
    const int row0 = blockIdx.y * 128;
    const int col0 = blockIdx.x * 128;
    const int frow = lane & 15;
    const int kg   = lane >> 4;
    const int sw   = kg ^ ((frow >> 1) & 3);

    const int srow = w * 32 + (lane >> 2);
    const int csw  = (lane & 3) ^ ((lane >> 3) & 3);
    const int br0  = min(col0 + srow, N - 1);
    const int br1  = min(col0 + srow + 16, N - 1);

    const unsigned short* a0 = A  + (size_t)(row0 + srow) * lda      + csw * 8;
    const unsigned short* a1 = A  + (size_t)(row0 + srow + 16) * lda + csw * 8;
    const unsigned short* b0 = Bt + (size_t)br0 * K + csw * 8;
    const unsigned short* b1 = Bt + (size_t)br1 * K + csw * 8;
    unsigned short* lA0 = As + (w * 2 + 0) * 512;
    unsigned short* lA1 = As + (w * 2 + 1) * 512;
    unsigned short* lB0 = Bs + (w * 2 + 0) * 512;
    unsigned short* lB1 = Bs + (w * 2 + 1) * 512;

    f32x4 acc[4][4] = {};

    for (int bk = 0; bk < K; bk += 32) {
        __syncthreads();
        GLL16(a0 + bk, lA0);
        GLL16(a1 + bk, lA1);
        GLL16(b0 + bk, lB0);
        GLL16(b1 + bk, lB1);
        __syncthreads();
        bf16x8 af[4], bfr[4];
        #pragma unroll
        for (int m = 0; m < 4; ++m)
            af[m] = *(const bf16x8*)&As[(wr * 64 + m * 16 + frow) * 32 + sw * 8];
        #pragma unroll
        for (int n = 0; n < 4; ++n)
            bfr[n] = *(const bf16x8*)&Bs[(wc * 64 + n * 16 + frow) * 32 + sw * 8];
        #pragma unroll
        for (int m = 0; m < 4; ++m)
            #pragma unroll
            for (int n = 0; n < 4; ++n)
                acc[m][n] = __builtin_amdgcn_mfma_f32_16x16x32_bf16(bfr[n], af[m], acc[m][n], 0, 0, 0);
    }

    // swapped-operand epilogue: row = row0+wr*64+m*16+frow, cols col0+wc*64+n*16+kg*4..+3
    #pragma unroll
    for (int m = 0; m < 4; ++m) {
        int row = row0 + wr * 64 + m * 16 + frow;
        #pragma unroll
        for (int n = 0; n < 4; ++n) {
            int col = col0 + wc * 64 + n * 16 + kg * 4;
            if (col >= N) continue;
            float4 bv = *(const float4*)(bias + col);
            float v0 = acc[m][n][0] + bv.x, v1 = acc[m][n][1] + bv.y;
            float v2 = acc[m][n][2] + bv.z, v3 = acc[m][n][3] + bv.w;
            if (RELU) {
                v0 = fmaxf(v0, 0.f); v1 = fmaxf(v1, 0.f);
                v2 = fmaxf(v2, 0.f); v3 = fmaxf(v3, 0.f);
            }
            if (OUTBF16) {
                ushort4 o = { f2b(v0), f2b(v1), f2b(v2), f2b(v3) };
                *(ushort4*)((unsigned short*)C + (size_t)row * ldc + col) = o;
            } else {
                float4 o = { v0, v1, v2, v3 };
                *(float4*)((float*)C + (size_t)row * ldc + col) = o;
            }
        }
    }
}

// ---------------- per-sample domain LoRA (bf16 weights) ----------------
__global__ __launch_bounds__(256) void k_dlora(
    const unsigned short* __restrict__ Xdnn, const int* __restrict__ d,
    const unsigned short* __restrict__ DA0b, const unsigned short* __restrict__ DB0b,
    const float* __restrict__ Dlb0,
    const unsigned short* __restrict__ SHARE,
    unsigned short* __restrict__ LORA, unsigned short* __restrict__ DDNN)
{
    int w = threadIdx.x >> 6, lane = threadIdx.x & 63;
    int b = blockIdx.x * 4 + w;
    int dom = d[b];
    uint4 raw = *(const uint4*)(Xdnn + (size_t)b * 512 + lane * 8);
    const unsigned short* pr = (const unsigned short*)&raw;
    float xv[8];
    #pragma unroll
    for (int j = 0; j < 8; ++j) xv[j] = b2f(pr[j]);

    const unsigned short* Ap = DA0b + ((size_t)dom * 512 + lane * 8) * 16;
    float v[16];
    #pragma unroll
    for (int r = 0; r < 16; ++r) v[r] = 0.f;
    #pragma unroll
    for (int j = 0; j < 8; ++j) {
        uint4 a0 = *(const uint4*)(Ap + j * 16);
        uint4 a1 = *(const uint4*)(Ap + j * 16 + 8);
        const unsigned short* ap = (const unsigned short*)&a0;
        const unsigned short* aq = (const unsigned short*)&a1;
        float xj = xv[j];
        #pragma unroll
        for (int r = 0; r < 8; ++r) v[r]     += xj * b2f(ap[r]);
        #pragma unroll
        for (int r = 0; r < 8; ++r) v[r + 8] += xj * b2f(aq[r]);
    }
    #pragma unroll
    for (int s = 1; s < 64; s <<= 1) {
        #pragma unroll
        for (int r = 0; r < 16; ++r) v[r] += __shfl_xor(v[r], s, 64);
    }
    const unsigned short* Bp = DB0b + (size_t)dom * 16 * 256;
    const float* lbp = Dlb0 + (size_t)dom * 256;
    #pragma unroll
    for (int c = 0; c < 4; ++c) {
        int o = lane + c * 64;
        float a = lbp[o];
        #pragma unroll
        for (int r = 0; r < 16; ++r) a += v[r] * b2f(Bp[r * 256 + o]);
        float sh = b2f(SHARE[(size_t)b * 256 + o]);
        LORA[(size_t)b * 256 + o] = f2b(a);
        DDNN[(size_t)b * 256 + o] = f2b(fmaxf(sh + a, 0.f));
    }
}

// ---------------- fused tail ----------------
__global__ __launch_bounds__(256) void k_tail(
    const float* __restrict__ Yd, const float* __restrict__ Ys, const float* __restrict__ Yl,
    const unsigned short* __restrict__ Hyper,
    const float* __restrict__ TB0, const float* __restrict__ Tlb0,
    const float* __restrict__ Tk1, const float* __restrict__ Tb1,
    const float* __restrict__ TA1, const float* __restrict__ TB1, const float* __restrict__ Tlb1,
    const float* __restrict__ h0W, const float* __restrict__ h0b,
    const float* __restrict__ h1W, const float* __restrict__ h1b,
    float* __restrict__ out)
{
    __shared__ float sTB0[2][16][128];
    __shared__ float sTlb0[2][128];
    __shared__ float sTk1[128];
    __shared__ float sWeff[2][128];
    __shared__ float sY[4][3][160];
    const int tid = threadIdx.x;

    for (int i = tid; i < 4096; i += 256) ((float*)sTB0)[i] = TB0[i];
    if (tid < 256) ((float*)sTlb0)[tid] = Tlb0[tid];
    if (tid < 128) sTk1[tid] = Tk1[tid];
    {
        int t = tid >> 7, j = tid & 127;
        float a = 0.f;
        #pragma unroll
        for (int r = 0; r < 16; ++r) a += TA1[((size_t)t * 128 + j) * 16 + r] * TB1[t * 16 + r];
        sWeff[t][j] = a;
    }
    const float* Yp[3] = {Yd, Ys, Yl};
    int b0 = blockIdx.x * 4;
    for (int i = tid; i < 4 * 3 * 160; i += 256) {
        int s = i / 480, rem = i % 480, st = rem / 160, idx = rem % 160;
        sY[s][st][idx] = Yp[st][(size_t)(b0 + s) * 160 + idx];
    }
    __syncthreads();

    int w = tid >> 6, lane = tid & 63;
    int b = b0 + w;
    const float* yd = sY[w][0];
    const float* ys = sY[w][1];
    const float* yl = sY[w][2];
    int j0 = lane, j1 = lane + 64;

    uint4 hraw = *(const uint4*)(Hyper + (size_t)b * 512 + lane * 8);
    const unsigned short* hp = (const unsigned short*)&hraw;
    float hv[8];
    #pragma unroll
    for (int j = 0; j < 8; ++j) hv[j] = b2f(hp[j]);

    float red[14];
    #pragma unroll
    for (int k = 0; k < 14; ++k) red[k] = 0.f;
    #pragma unroll
    for (int j = 0; j < 8; ++j) {
        float4 w0 = *(const float4*)(h0W + (size_t)(lane * 8 + j) * 4);
        float4 w1 = *(const float4*)(h1W + (size_t)(lane * 8 + j) * 4);
        red[0] += hv[j] * w0.x; red[1] += hv[j] * w0.y; red[2] += hv[j] * w0.z; red[3] += hv[j] * w0.w;
        red[4] += hv[j] * w1.x; red[5] += hv[j] * w1.y; red[6] += hv[j] * w1.z; red[7] += hv[j] * w1.w;
    }

    float SLv[2][2], LSv[2][2];
    #pragma unroll
    for (int t = 0; t < 2; ++t) {
        float lb0 = sTlb0[t][j0], lb1 = sTlb0[t][j1];
        float dl0 = lb0, dl1 = lb1, sl0 = lb0, sl1 = lb1, ll0 = lb0, ll1 = lb1;
        #pragma unroll
        for (int r = 0; r < 16; ++r) {
            float w0v = sTB0[t][r][j0], w1v = sTB0[t][r][j1];
            float ud = yd[128 + t * 16 + r];
            float us = ys[128 + t * 16 + r];
            float ul = yl[128 + t * 16 + r];
            dl0 += ud * w0v; dl1 += ud * w1v;
            sl0 += us * w0v; sl1 += us * w1v;
            ll0 += ul * w0v; ll1 += ul * w1v;
        }
        float D0 = yd[j0] + dl0, D1 = yd[j1] + dl1;
        float S0 = ys[j0],       S1 = ys[j1];
        float L0 = ll0,          L1 = ll1;
        float sl_0 = sl0, sl_1 = sl1;
        float ls_0 = yl[j0], ls_1 = yl[j1];
        if (t == 0) {
            D0 = fmaxf(D0, 0.f); D1 = fmaxf(D1, 0.f);
            S0 = fmaxf(S0, 0.f); S1 = fmaxf(S1, 0.f);
            L0 = fmaxf(L0, 0.f); L1 = fmaxf(L1, 0.f);
            sl_0 = fmaxf(sl_0, 0.f); sl_1 = fmaxf(sl_1, 0.f);
            ls_0 = fmaxf(ls_0, 0.f); ls_1 = fmaxf(ls_1, 0.f);
        }
        SLv[t][0] = sl_0; SLv[t][1] = sl_1;
        LSv[t][0] = ls_0; LSv[t][1] = ls_1;
        float we0 = sWeff[t][j0], we1 = sWeff[t][j1];
        float tk0 = sTk1[j0],     tk1v = sTk1[j1];
        red[8 + t * 3 + 0] = D0 * (tk0 + we0) + D1 * (tk1v + we1);
        red[8 + t * 3 + 1] = S0 * tk0 + S1 * tk1v;
        red[8 + t * 3 + 2] = L0 * we0 + L1 * we1;
    }

    #pragma unroll
    for (int s = 1; s < 64; s <<= 1) {
        #pragma unroll
        for (int k = 0; k < 14; ++k) red[k] += __shfl_xor(red[k], s, 64);
    }

    float Tb1v = Tb1[0];
    #pragma unroll
    for (int t = 0; t < 2; ++t) {
        float fd = red[8 + t * 3 + 0] + Tb1v + Tlb1[t];
        float fs = red[8 + t * 3 + 1] + Tb1v;
        float fl = red[8 + t * 3 + 2] + Tlb1[t];
        const float* hb = t ? h1b : h0b;
        float g0 = 1.f / (1.f + expf(-(red[t * 4 + 0] + hb[0])));
        float g1 = 1.f / (1.f + expf(-(red[t * 4 + 1] + hb[1])));
        float g2 = 1.f / (1.f + expf(-(red[t * 4 + 2] + hb[2])));
        float g3 = 1.f / (1.f + expf(-(red[t * 4 + 3] + hb[3])));
        float base = fd - g0 * fs - g1 * fl;
        size_t o = (size_t)t * BATCH * 128 + (size_t)b * 128;
        out[o + j0] = base - g2 * SLv[t][0] - g3 * LSv[t][0];
        out[o + j1] = base - g2 * SLv[t][1] - g3 * LSv[t][1];
    }
}

// ---------------- host ----------------
extern "C" void kernel_launch(void* const* d_in, const int* in_sizes, int n_in,
                              void* d_out, int out_size, void* d_ws, size_t ws_size,
                              hipStream_t stream)
{
    const int*   x    = (const int*)  d_in[0];
    const int*   dix  = (const int*)  d_in[1];
    const float* emb  = (const float*)d_in[2];
    const float* sW0  = (const float*)d_in[3];
    const float* sb0  = (const float*)d_in[4];
    const float* sW1  = (const float*)d_in[5];
    const float* sb1  = (const float*)d_in[6];
    const float* Dk0  = (const float*)d_in[7];
    const float* Db0  = (const float*)d_in[8];
    const float* DA0  = (const float*)d_in[9];
    const float* DB0  = (const float*)d_in[10];
    const float* Dlb0 = (const float*)d_in[11];
    const float* Tk0  = (const float*)d_in[12];
    const float* Tb0  = (const float*)d_in[13];
    const float* Tk1  = (const float*)d_in[14];
    const float* Tb1  = (const float*)d_in[15];
    const float* TA0  = (const float*)d_in[16];
    const float* TB0  = (const float*)d_in[17];
    const float* Tlb0 = (const float*)d_in[18];
    const float* TA1  = (const float*)d_in[19];
    const float* TB1  = (const float*)d_in[20];
    const float* Tlb1 = (const float*)d_in[21];
    const float* gW0  = (const float*)d_in[22];
    const float* gb0  = (const float*)d_in[23];
    const float* gW1  = (const float*)d_in[24];
    const float* gb1  = (const float*)d_in[25];
    const float* h0W  = (const float*)d_in[26];
    const float* h0b  = (const float*)d_in[27];
    const float* h1W  = (const float*)d_in[28];
    const float* h1b  = (const float*)d_in[29];

    hipFuncSetAttribute((const void*)k_gemm256<1, 1, 1>,
                        hipFuncAttributeMaxDynamicSharedMemorySize, 163840);
    hipFuncSetAttribute((const void*)k_gemm256<1, 1, 0>,
                        hipFuncAttributeMaxDynamicSharedMemorySize, 131072);

    char* ws = (char*)d_ws;
    size_t off = 0;
    auto alloc = [&](size_t bytes) -> void* {
        void* p = ws + off;
        off += (bytes + 255) & ~(size_t)255;
        return p;
    };
    unsigned short* W1t   = (unsigned short*)alloc((size_t)2048 * 2048 * 2);
    unsigned short* W2cat = (unsigned short*)alloc((size_t)1024 * 1024 * 2);
    unsigned short* Dk0t  = (unsigned short*)alloc((size_t)256 * 512 * 2);
    unsigned short* Tcat  = (unsigned short*)alloc((size_t)160 * 256 * 2);
    unsigned short* DA0b  = (unsigned short*)alloc((size_t)8 * 512 * 16 * 2);
    unsigned short* DB0b  = (unsigned short*)alloc((size_t)8 * 16 * 256 * 2);
    unsigned short* embB  = (unsigned short*)alloc((size_t)100000 * 64 * 2);
    float*          b1cat = (float*)alloc(2048 * 4);
    float*          b2cat = (float*)alloc(1024 * 4);
    float*          tb0c  = (float*)alloc(160 * 4);
    float*          Ybase = (float*)alloc((size_t)3 * BATCH * 160 * 4);   // Ys|Yl|Yd
    char* regB = (char*)alloc((size_t)BATCH * 2048 * 2);   // H, later SHARE/LORA/DDNN
    unsigned short* Xdnn  = (unsigned short*)alloc((size_t)BATCH * 512 * 2);
    unsigned short* Hyper = (unsigned short*)alloc((size_t)BATCH * 512 * 2);

    float* Ys = Ybase;                              // stream order: SHARE, LORA, DDNN
    float* Yl = Ybase + (size_t)BATCH * 160;
    float* Yd = Ybase + (size_t)2 * BATCH * 160;
    unsigned short* Hbuf  = (unsigned short*)regB;
    unsigned short* SHARE = (unsigned short*)regB;
    unsigned short* LORA  = SHARE + (size_t)BATCH * 256;
    unsigned short* DDNN  = LORA  + (size_t)BATCH * 256;

    // ONE prep launch: all transposes + biases + DA0b/DB0b + embB
    k_prep<<<11943, 256, 0, stream>>>(
        sW0, gW0, sW1, gW1, Dk0, Tk0, TA0,
        sb0, gb0, sb1, gb1, Tb0, DA0, DB0, emb,
        W1t, W2cat, Dk0t, Tcat, b1cat, b2cat, tb0c, DA0b, DB0b, embB);

    // GEMM1 (fused gather, minimal barriers): emb[x] @ [sW0|gW0], relu -> H (B,2048) bf16
    k_gemm256<1, 1, 1><<<dim3(8, 64, 1), 512, 163840, stream>>>(
        embB, 0, 0, W1t, 2048, 0, b1cat, 0, Hbuf, 2048, 0, 2048, x, embB);
    // GEMM2 grouped (z=0: share-MLP, z=1: gate-hypernet): H halves -> Xdnn / Hyper
    k_gemm256<1, 1, 0><<<dim3(2, 64, 2), 512, 131072, stream>>>(
        Hbuf, 2048, 1024, W2cat, 1024, (long)512 * 1024, b2cat, 512,
        Xdnn, 512, (long)BATCH * 512, 512, nullptr, nullptr);
    // GEMM3: share = x_dnn @ Dk0 + Db0 (pre-act) bf16
    k_gemm<0, 1><<<dim3(2, 128), 256, 0, stream>>>(Xdnn, 512, Dk0t, Db0, SHARE, 256, 256, 512);
    // domain LoRA + ddnn
    k_dlora<<<BATCH / 4, 256, 0, stream>>>(Xdnn, dix, DA0b, DB0b, Dlb0, SHARE, LORA, DDNN);
    // stage i=0: one fused GEMM over 3 contiguous streams @ [Tk0|TA0[0]|TA0[1]]
    k_gemm<0, 0><<<dim3(2, 384), 256, 0, stream>>>(SHARE, 256, Tcat, tb0c, Ybase, 160, 160, 256);
    // fused tail
    k_tail<<<BATCH / 4, 256, 0, stream>>>(Yd, Ys, Yl, Hyper, TB0, Tlb0, Tk1, Tb1,
                                          TA1, TB1, Tlb1, h0W, h0b, h1W, h1b, (float*)d_out);
}

// Round 10
// 320.502 us; speedup vs baseline: 4.7013x; 1.0755x over previous
//
#include <hip/hip_runtime.h>
#include <hip/hip_bf16.h>

#define BATCH 16384

typedef __attribute__((ext_vector_type(4))) float f32x4;
typedef __attribute__((ext_vector_type(8))) short bf16x8;

__device__ inline float b2f(unsigned short u) {
    union { unsigned u; float f; } c; c.u = ((unsigned)u) << 16; return c.f;
}
__device__ inline unsigned short f2b(float f) {
    __hip_bfloat16 h = __float2bfloat16(f);
    return *(unsigned short*)&h;
}

#define GLL16(g, l)                                                            \
    __builtin_amdgcn_global_load_lds(                                          \
        (const __attribute__((address_space(1))) void*)(g),                    \
        (__attribute__((address_space(3))) void*)(l), 16, 0, 0)

// ---------------- mega-prep: all transposes + biases + bf16 conversions, ONE launch ----------------
// id map: [0,4096) W1 | [,5120) W2 | [,5248) Dk0->D3cat[0:256) | [,5376) DA0t->D3cat[256:384) |
//         [,5408) Tk0 | [,5424) TA0 | [,5567) small | [,11817) embB
__global__ __launch_bounds__(256) void k_prep(
    const float* __restrict__ sW0, const float* __restrict__ gW0,
    const float* __restrict__ sW1, const float* __restrict__ gW1,
    const float* __restrict__ Dk0, const float* __restrict__ Tk0,
    const float* __restrict__ TA0,
    const float* __restrict__ sb0, const float* __restrict__ gb0,
    const float* __restrict__ sb1, const float* __restrict__ gb1,
    const float* __restrict__ Tb0, const float* __restrict__ Db0,
    const float* __restrict__ DA0, const float* __restrict__ DB0,
    const float* __restrict__ emb,
    unsigned short* __restrict__ W1t, unsigned short* __restrict__ W2cat,
    unsigned short* __restrict__ D3cat, unsigned short* __restrict__ Tcat,
    float* __restrict__ b1cat, float* __restrict__ b2cat, float* __restrict__ tb0c,
    float* __restrict__ d3bias, unsigned short* __restrict__ DB0b,
    unsigned short* __restrict__ embB)
{
    int id = blockIdx.x;
    const int tid = threadIdx.x;
    __shared__ float t[32][33];
    auto tcvt = [&](const float* src, int K, int N, unsigned short* dst,
                    int dst_off, int dst_ld, int bx, int by) {
        int k0 = by * 32, n0 = bx * 32;
        int tx = tid & 31, ty = tid >> 5;   // 32 x 8
        #pragma unroll
        for (int s = 0; s < 32; s += 8) {
            int k = k0 + ty + s, n = n0 + tx;
            t[ty + s][tx] = (k < K && n < N) ? src[(size_t)k * N + n] : 0.f;
        }
        __syncthreads();
        #pragma unroll
        for (int s = 0; s < 32; s += 8) {
            int n = n0 + ty + s, k = k0 + tx;
            if (n < N && k < K)
                dst[(size_t)(dst_off + n) * dst_ld + k] = f2b(t[tx][ty + s]);
        }
    };
    if (id < 4096) { int z = id >> 11, rem = id & 2047;
        tcvt(z ? gW0 : sW0, 2048, 1024, W1t, z * 1024, 2048, rem & 31, rem >> 5); return; }
    id -= 4096;
    if (id < 1024) { int z = id >> 9, rem = id & 511;
        tcvt(z ? gW1 : sW1, 1024, 512, W2cat, z * 512, 1024, rem & 15, rem >> 4); return; }
    id -= 1024;
    if (id < 128) { tcvt(Dk0, 512, 256, D3cat, 0, 512, id & 7, id >> 3); return; }
    id -= 128;
    if (id < 128) { int dom = id >> 4, by = id & 15;
        tcvt(DA0 + (size_t)dom * 512 * 16, 512, 16, D3cat, 256 + dom * 16, 512, 0, by); return; }
    id -= 128;
    if (id < 32)  { tcvt(Tk0, 256, 128, Tcat, 0, 256, id & 3, id >> 2); return; }
    id -= 32;
    if (id < 16)  { int z = id >> 3;
        tcvt(TA0 + z * 256 * 16, 256, 16, Tcat, 128 + z * 16, 256, 0, id & 7); return; }
    id -= 16;
    if (id < 143) {
        int i = id * 256 + tid;
        if (i < 1024)            { b1cat[i] = sb0[i]; return; }
        if (i < 2048)            { b1cat[i] = gb0[i - 1024]; return; }
        if (i < 2560)            { b2cat[i - 2048] = sb1[i - 2048]; return; }
        if (i < 3072)            { b2cat[i - 2560 + 512] = gb1[i - 2560]; return; }
        if (i < 3200)            { tb0c[i - 3072] = Tb0[i - 3072]; return; }
        if (i < 3232)            { tb0c[i - 3200 + 128] = 0.f; return; }
        if (i < 3488)            { d3bias[i - 3232] = Db0[i - 3232]; return; }
        if (i < 3616)            { d3bias[i - 3488 + 256] = 0.f; return; }
        i -= 3616;
        if (i < 32768)           { DB0b[i] = f2b(DB0[i]); return; }
        return;
    }
    id -= 143;
    {   // embB: f32 (100000 x 64) -> bf16, 4 elems/thread
        int e = (id * 256 + tid) * 4;
        if (e < 100000 * 64) {
            float4 v = *(const float4*)(emb + e);
            ushort4 o = { f2b(v.x), f2b(v.y), f2b(v.z), f2b(v.w) };
            *(ushort4*)(embB + e) = o;
        }
    }
}

// ================= 256x256 MFMA GEMM — minimal-barrier, compiler-scheduled ====================
// (r9 structure, 157 us verified). GATHER=1: indices fetched as per-thread GLOBAL loads
// from x (L2-hot, 2MB), register-prefetched one tile ahead (ixc/ixn) — no LDS x-block.
// vmcnt audit (gather): prologue ordered {ld f0; ld f1; stage ks0,ks1; VM4} -> steady
// queue entering loop = 4 (ks1). Loop: half0 {reads; stage ks0(t+1)[4]; ld ixn[4]; MFMA;
// VM8 (drains ks1(t))}; half1 {reads; stage ks1(t+1)[4]; MFMA; VM8 (drains ks0(t+1))};
// ixc=ixn copy's compiler-wait drains ixn, keeps ks1(t+1). Counted vmcnt, never 0 (T4).
template<int RELU, int OUTBF16, int GATHER>
__global__ __launch_bounds__(512, 2) void k_gemm256(
    const unsigned short* __restrict__ A, int lda, long Az,
    const unsigned short* __restrict__ Bt, int K, long Bz,
    const float* __restrict__ bias, int biasz,
    void* __restrict__ C, int ldc, long Cz,
    int N, const int* __restrict__ xsrc, const unsigned short* __restrict__ embB)
{
    extern __shared__ char smem_raw[];
    const int NT = K >> 6;            // 64-wide K tiles
    const int tid  = threadIdx.x;
    const int lane = tid & 63;
    const int w    = tid >> 6;
    const int wr   = w >> 2, wc = w & 3;
    const int frow = lane & 15, kg = lane >> 4;
    const int z = blockIdx.z;
    A    += (size_t)z * Az;
    Bt   += (size_t)z * Bz;
    bias += (size_t)z * biasz;

    // XCD-aware bijective swizzle (nwg divisible by 8 for all our launches)
    const int gx  = gridDim.x;
    const int nwg = gx * gridDim.y;
    const int lin = blockIdx.y * gx + blockIdx.x;
    const int qq  = nwg >> 3;
    const int swz = (lin & 7) * qq + (lin >> 3);
    const int bx = swz % gx, by = swz / gx;
    const int row0 = by * 256, col0 = bx * 256;

    // staging: one kslice = 32KB = 4 gloads of 8KB (h=0..3) per thread.
    const int lch = (lane & 7) ^ ((lane >> 3) & 7);
    const int isA = (lch < 4);
    const int eoBase = lch * 8;                    // elem offset within embedding row (A)
    int rrh[4];
    const unsigned short* gsrc[4];
    #pragma unroll
    for (int h = 0; h < 4; ++h) {
        int rr = h * 64 + w * 8 + (lane >> 3);
        rrh[h] = rr;
        if (isA) gsrc[h] = GATHER ? embB : A + (size_t)(row0 + rr) * lda + lch * 8;
        else     gsrc[h] = Bt + (size_t)min(col0 + rr, N - 1) * K + (lch - 4) * 8;
    }
    const int dBase = w * 1024;   // wave-uniform LDS offset within an 8KB gload block

    // fragment read offsets (bytes) within a kslice region; swizzled physical chunks
    const int pA = (kg ^ (frow & 7)) * 16;
    const int pB = ((4 + kg) ^ (frow & 7)) * 16;
    int aOff[8], bOff[4];
    #pragma unroll
    for (int m = 0; m < 8; ++m) aOff[m] = (wr * 128 + m * 16 + frow) * 128 + pA;
    #pragma unroll
    for (int n = 0; n < 4; ++n) bOff[n] = (wc * 64 + n * 16 + frow) * 128 + pB;

#define STAGE(t_, ks_, slot_) do {                                              \
        int tc_ = min((int)(t_), NT - 1);                                       \
        int o_ = tc_ * 64 + (ks_) * 32;                                         \
        char* d_ = smem_raw + (slot_) * 65536 + (ks_) * 32768 + dBase;          \
        GLL16(gsrc[0] + o_, d_);                                                \
        GLL16(gsrc[1] + o_, d_ + 8192);                                         \
        GLL16(gsrc[2] + o_, d_ + 16384);                                        \
        GLL16(gsrc[3] + o_, d_ + 24576);                                        \
    } while (0)
#define STAGEX(ix_, tcb_, ks_, slot_) do {                                      \
        char* d_ = smem_raw + (slot_) * 65536 + (ks_) * 32768 + dBase;          \
        _Pragma("unroll")                                                       \
        for (int h_ = 0; h_ < 4; ++h_) {                                        \
            const unsigned short* sa_ = embB + (size_t)(ix_)[h_] * 64           \
                                        + (ks_) * 32 + eoBase;                  \
            const unsigned short* sb2_ = gsrc[h_] + (tcb_) * 64 + (ks_) * 32;   \
            GLL16(isA ? sa_ : sb2_, d_ + h_ * 8192);                            \
        }                                                                       \
    } while (0)
#define READS(sb_, ks_) do {                                                    \
        _Pragma("unroll")                                                       \
        for (int n = 0; n < 4; ++n)                                             \
            bfr[n] = *(const bf16x8*)(smem_raw + (sb_) + (ks_) * 32768 + bOff[n]); \
        _Pragma("unroll")                                                       \
        for (int mi = 0; mi < 8; ++mi)                                          \
            afr[mi] = *(const bf16x8*)(smem_raw + (sb_) + (ks_) * 32768 + aOff[mi]); \
    } while (0)
#define MFMA32() do {                                                           \
        __builtin_amdgcn_s_setprio(1);                                          \
        _Pragma("unroll")                                                       \
        for (int mi = 0; mi < 8; ++mi)                                          \
            _Pragma("unroll")                                                   \
            for (int n = 0; n < 4; ++n)                                         \
                acc[mi][n] = __builtin_amdgcn_mfma_f32_16x16x32_bf16(           \
                    bfr[n], afr[mi], acc[mi][n], 0, 0, 0);                      \
        __builtin_amdgcn_s_setprio(0);                                          \
    } while (0)
#define VM4   asm volatile("s_waitcnt vmcnt(4)" ::: "memory")
#define VM8   asm volatile("s_waitcnt vmcnt(8)" ::: "memory")
#define BARM  asm volatile("s_barrier" ::: "memory")

    f32x4 acc[8][4] = {};
    bf16x8 afr[8], bfr[4];
    int ixc[4] = {0, 0, 0, 0};

    if (GATHER) {
        int ix0[4];
        #pragma unroll
        for (int h = 0; h < 4; ++h) ix0[h] = xsrc[(row0 + rrh[h]) * 32];
        int t1 = min(1, NT - 1);
        #pragma unroll
        for (int h = 0; h < 4; ++h) ixc[h] = xsrc[(row0 + rrh[h]) * 32 + t1];
        STAGEX(ix0, 0, 0, 0); STAGEX(ix0, 0, 1, 0);
    } else {
        STAGE(0, 0, 0); STAGE(0, 1, 0);
    }
    VM4; BARM;        // publishes tile0 ks0; ks1 (+prologue idx) in flight

    for (int t = 0; t < NT; ++t) {
        const int slot = t & 1, nslot = slot ^ 1;
        const int sb = slot * 65536;
        const int tcn = min(t + 1, NT - 1);
        int ixn[4];
        // half 0: reads ks0 + stage ks0(t+1) + idx prefetch + 32 MFMA
        READS(sb, 0);
        if (GATHER) STAGEX(ixc, tcn, 0, nslot); else STAGE(t + 1, 0, nslot);
        if (GATHER) {
            int tc2 = min(t + 2, NT - 1);
            #pragma unroll
            for (int h = 0; h < 4; ++h) ixn[h] = xsrc[(row0 + rrh[h]) * 32 + tc2];
        }
        MFMA32();
        if (GATHER) VM8; else VM4;
        BARM;         // publishes ks1(t)
        // half 1
        READS(sb, 1);
        if (GATHER) STAGEX(ixc, tcn, 1, nslot); else STAGE(t + 1, 1, nslot);
        MFMA32();
        if (GATHER) VM8; else VM4;
        BARM;         // publishes ks0(t+1)
        if (GATHER) {
            #pragma unroll
            for (int h = 0; h < 4; ++h) ixc[h] = ixn[h];
        }
    }
#undef STAGE
#undef STAGEX
#undef READS
#undef MFMA32
#undef VM4
#undef VM8
#undef BARM

    // epilogue (swapped-operand layout): row = row0+wr*128+m*16+frow,
    // cols = col0+wc*64+n*16+kg*4 .. +3
    #pragma unroll
    for (int m = 0; m < 8; ++m) {
        int row = row0 + wr * 128 + m * 16 + frow;
        #pragma unroll
        for (int n = 0; n < 4; ++n) {
            int col = col0 + wc * 64 + n * 16 + kg * 4;
            float4 bv = *(const float4*)(bias + col);
            float v0 = acc[m][n][0] + bv.x, v1 = acc[m][n][1] + bv.y;
            float v2 = acc[m][n][2] + bv.z, v3 = acc[m][n][3] + bv.w;
            if (RELU) {
                v0 = fmaxf(v0, 0.f); v1 = fmaxf(v1, 0.f);
                v2 = fmaxf(v2, 0.f); v3 = fmaxf(v3, 0.f);
            }
            if (OUTBF16) {
                ushort4 o = { f2b(v0), f2b(v1), f2b(v2), f2b(v3) };
                *(ushort4*)((unsigned short*)C + (size_t)z * Cz + (size_t)row * ldc + col) = o;
            } else {
                float4 o = { v0, v1, v2, v3 };
                *(float4*)((float*)C + (size_t)z * Cz + (size_t)row * ldc + col) = o;
            }
        }
    }
}

// ---------------- 128x128 MFMA GEMM (m97 structure) for small GEMMs ----------------
template<int RELU, int OUTBF16>
__global__ __launch_bounds__(256) void k_gemm(
    const unsigned short* __restrict__ A, int lda,
    const unsigned short* __restrict__ Bt,         // N x K row-major, ldb = K
    const float* __restrict__ bias,
    void* __restrict__ C, int ldc,
    int N, int K)
{
    __shared__ __align__(16) unsigned short As[128 * 32];
    __shared__ __align__(16) unsigned short Bs[128 * 32];
    const int tid  = threadIdx.x;
    const int lane = tid & 63;
    const int w    = tid >> 6;
    const int wr   = w >> 1, wc = w & 1;
    const int row0 = blockIdx.y * 128;
    const int col0 = blockIdx.x * 128;
    const int frow = lane & 15;
    const int kg   = lane >> 4;
    const int sw   = kg ^ ((frow >> 1) & 3);

    const int srow = w * 32 + (lane >> 2);
    const int csw  = (lane & 3) ^ ((lane >> 3) & 3);
    const int br0  = min(col0 + srow, N - 1);
    const int br1  = min(col0 + srow + 16, N - 1);

    const unsigned short* a0 = A  + (size_t)(row0 + srow) * lda      + csw * 8;
    const unsigned short* a1 = A  + (size_t)(row0 + srow + 16) * lda + csw * 8;
    const unsigned short* b0 = Bt + (size_t)br0 * K + csw * 8;
    const unsigned short* b1 = Bt + (size_t)br1 * K + csw * 8;
    unsigned short* lA0 = As + (w * 2 + 0) * 512;
    unsigned short* lA1 = As + (w * 2 + 1) * 512;
    unsigned short* lB0 = Bs + (w * 2 + 0) * 512;
    unsigned short* lB1 = Bs + (w * 2 + 1) * 512;

    f32x4 acc[4][4] = {};

    for (int bk = 0; bk < K; bk += 32) {
        __syncthreads();
        GLL16(a0 + bk, lA0);
        GLL16(a1 + bk, lA1);
        GLL16(b0 + bk, lB0);
        GLL16(b1 + bk, lB1);
        __syncthreads();
        bf16x8 af[4], bfr[4];
        #pragma unroll
        for (int m = 0; m < 4; ++m)
            af[m] = *(const bf16x8*)&As[(wr * 64 + m * 16 + frow) * 32 + sw * 8];
        #pragma unroll
        for (int n = 0; n < 4; ++n)
            bfr[n] = *(const bf16x8*)&Bs[(wc * 64 + n * 16 + frow) * 32 + sw * 8];
        #pragma unroll
        for (int m = 0; m < 4; ++m)
            #pragma unroll
            for (int n = 0; n < 4; ++n)
                acc[m][n] = __builtin_amdgcn_mfma_f32_16x16x32_bf16(bfr[n], af[m], acc[m][n], 0, 0, 0);
    }

    // swapped-operand epilogue: row = row0+wr*64+m*16+frow, cols col0+wc*64+n*16+kg*4..+3
    #pragma unroll
    for (int m = 0; m < 4; ++m) {
        int row = row0 + wr * 64 + m * 16 + frow;
        #pragma unroll
        for (int n = 0; n < 4; ++n) {
            int col = col0 + wc * 64 + n * 16 + kg * 4;
            if (col >= N) continue;
            float4 bv = *(const float4*)(bias + col);
            float v0 = acc[m][n][0] + bv.x, v1 = acc[m][n][1] + bv.y;
            float v2 = acc[m][n][2] + bv.z, v3 = acc[m][n][3] + bv.w;
            if (RELU) {
                v0 = fmaxf(v0, 0.f); v1 = fmaxf(v1, 0.f);
                v2 = fmaxf(v2, 0.f); v3 = fmaxf(v3, 0.f);
            }
            if (OUTBF16) {
                ushort4 o = { f2b(v0), f2b(v1), f2b(v2), f2b(v3) };
                *(ushort4*)((unsigned short*)C + (size_t)row * ldc + col) = o;
            } else {
                float4 o = { v0, v1, v2, v3 };
                *(float4*)((float*)C + (size_t)row * ldc + col) = o;
            }
        }
    }
}

// ---------------- dlora-lite: finish domain LoRA from batched v = x@DA0 (in SHV) ----------------
// SHV (B,384) bf16 = [share 256 | v_all 8x16]. Per sample: lora = v[dom]@DB0b[dom]+Dlb0[dom];
// emit stream copies SHARE / LORA / DDNN=relu(share+lora).
__global__ __launch_bounds__(256) void k_dlora2(
    const unsigned short* __restrict__ SHV, const int* __restrict__ d,
    const unsigned short* __restrict__ DB0b, const float* __restrict__ Dlb0,
    unsigned short* __restrict__ SHARE,
    unsigned short* __restrict__ LORA, unsigned short* __restrict__ DDNN)
{
    int w = threadIdx.x >> 6, lane = threadIdx.x & 63;
    int b = blockIdx.x * 4 + w;
    int dom = d[b];
    const unsigned short* vp = SHV + (size_t)b * 384 + 256 + dom * 16;
    uint4 v0 = *(const uint4*)vp;
    uint4 v1 = *(const uint4*)(vp + 8);
    const unsigned short* pv0 = (const unsigned short*)&v0;
    const unsigned short* pv1 = (const unsigned short*)&v1;
    float v[16];
    #pragma unroll
    for (int r = 0; r < 8; ++r) { v[r] = b2f(pv0[r]); v[r + 8] = b2f(pv1[r]); }
    const unsigned short* Bp = DB0b + (size_t)dom * 16 * 256;
    const float* lbp = Dlb0 + (size_t)dom * 256;
    #pragma unroll
    for (int c = 0; c < 4; ++c) {
        int o = lane + c * 64;
        float a = lbp[o];
        #pragma unroll
        for (int r = 0; r < 16; ++r) a += v[r] * b2f(Bp[r * 256 + o]);
        unsigned short shb = SHV[(size_t)b * 384 + o];
        float sh = b2f(shb);
        SHARE[(size_t)b * 256 + o] = shb;
        LORA[(size_t)b * 256 + o] = f2b(a);
        DDNN[(size_t)b * 256 + o] = f2b(fmaxf(sh + a, 0.f));
    }
}

// ---------------- fused tail (Y now bf16) ----------------
__global__ __launch_bounds__(256) void k_tail(
    const unsigned short* __restrict__ Yd, const unsigned short* __restrict__ Ys,
    const unsigned short* __restrict__ Yl,
    const unsigned short* __restrict__ Hyper,
    const float* __restrict__ TB0, const float* __restrict__ Tlb0,
    const float* __restrict__ Tk1, const float* __restrict__ Tb1,
    const float* __restrict__ TA1, const float* __restrict__ TB1, const float* __restrict__ Tlb1,
    const float* __restrict__ h0W, const float* __restrict__ h0b,
    const float* __restrict__ h1W, const float* __restrict__ h1b,
    float* __restrict__ out)
{
    __shared__ float sTB0[2][16][128];
    __shared__ float sTlb0[2][128];
    __shared__ float sTk1[128];
    __shared__ float sWeff[2][128];
    __shared__ float sY[4][3][160];
    const int tid = threadIdx.x;

    for (int i = tid; i < 4096; i += 256) ((float*)sTB0)[i] = TB0[i];
    if (tid < 256) ((float*)sTlb0)[tid] = Tlb0[tid];
    if (tid < 128) sTk1[tid] = Tk1[tid];
    {
        int t = tid >> 7, j = tid & 127;
        float a = 0.f;
        #pragma unroll
        for (int r = 0; r < 16; ++r) a += TA1[((size_t)t * 128 + j) * 16 + r] * TB1[t * 16 + r];
        sWeff[t][j] = a;
    }
    const unsigned short* Yp[3] = {Yd, Ys, Yl};
    int b0 = blockIdx.x * 4;
    for (int i = tid; i < 4 * 3 * 160; i += 256) {
        int s = i / 480, rem = i % 480, st = rem / 160, idx = rem % 160;
        sY[s][st][idx] = b2f(Yp[st][(size_t)(b0 + s) * 160 + idx]);
    }
    __syncthreads();

    int w = tid >> 6, lane = tid & 63;
    int b = b0 + w;
    const float* yd = sY[w][0];
    const float* ys = sY[w][1];
    const float* yl = sY[w][2];
    int j0 = lane, j1 = lane + 64;

    uint4 hraw = *(const uint4*)(Hyper + (size_t)b * 512 + lane * 8);
    const unsigned short* hp = (const unsigned short*)&hraw;
    float hv[8];
    #pragma unroll
    for (int j = 0; j < 8; ++j) hv[j] = b2f(hp[j]);

    float red[14];
    #pragma unroll
    for (int k = 0; k < 14; ++k) red[k] = 0.f;
    #pragma unroll
    for (int j = 0; j < 8; ++j) {
        float4 w0 = *(const float4*)(h0W + (size_t)(lane * 8 + j) * 4);
        float4 w1 = *(const float4*)(h1W + (size_t)(lane * 8 + j) * 4);
        red[0] += hv[j] * w0.x; red[1] += hv[j] * w0.y; red[2] += hv[j] * w0.z; red[3] += hv[j] * w0.w;
        red[4] += hv[j] * w1.x; red[5] += hv[j] * w1.y; red[6] += hv[j] * w1.z; red[7] += hv[j] * w1.w;
    }

    float SLv[2][2], LSv[2][2];
    #pragma unroll
    for (int t = 0; t < 2; ++t) {
        float lb0 = sTlb0[t][j0], lb1 = sTlb0[t][j1];
        float dl0 = lb0, dl1 = lb1, sl0 = lb0, sl1 = lb1, ll0 = lb0, ll1 = lb1;
        #pragma unroll
        for (int r = 0; r < 16; ++r) {
            float w0v = sTB0[t][r][j0], w1v = sTB0[t][r][j1];
            float ud = yd[128 + t * 16 + r];
            float us = ys[128 + t * 16 + r];
            float ul = yl[128 + t * 16 + r];
            dl0 += ud * w0v; dl1 += ud * w1v;
            sl0 += us * w0v; sl1 += us * w1v;
            ll0 += ul * w0v; ll1 += ul * w1v;
        }
        float D0 = yd[j0] + dl0, D1 = yd[j1] + dl1;
        float S0 = ys[j0],       S1 = ys[j1];
        float L0 = ll0,          L1 = ll1;
        float sl_0 = sl0, sl_1 = sl1;
        float ls_0 = yl[j0], ls_1 = yl[j1];
        if (t == 0) {
            D0 = fmaxf(D0, 0.f); D1 = fmaxf(D1, 0.f);
            S0 = fmaxf(S0, 0.f); S1 = fmaxf(S1, 0.f);
            L0 = fmaxf(L0, 0.f); L1 = fmaxf(L1, 0.f);
            sl_0 = fmaxf(sl_0, 0.f); sl_1 = fmaxf(sl_1, 0.f);
            ls_0 = fmaxf(ls_0, 0.f); ls_1 = fmaxf(ls_1, 0.f);
        }
        SLv[t][0] = sl_0; SLv[t][1] = sl_1;
        LSv[t][0] = ls_0; LSv[t][1] = ls_1;
        float we0 = sWeff[t][j0], we1 = sWeff[t][j1];
        float tk0 = sTk1[j0],     tk1v = sTk1[j1];
        red[8 + t * 3 + 0] = D0 * (tk0 + we0) + D1 * (tk1v + we1);
        red[8 + t * 3 + 1] = S0 * tk0 + S1 * tk1v;
        red[8 + t * 3 + 2] = L0 * we0 + L1 * we1;
    }

    #pragma unroll
    for (int s = 1; s < 64; s <<= 1) {
        #pragma unroll
        for (int k = 0; k < 14; ++k) red[k] += __shfl_xor(red[k], s, 64);
    }

    float Tb1v = Tb1[0];
    #pragma unroll
    for (int t = 0; t < 2; ++t) {
        float fd = red[8 + t * 3 + 0] + Tb1v + Tlb1[t];
        float fs = red[8 + t * 3 + 1] + Tb1v;
        float fl = red[8 + t * 3 + 2] + Tlb1[t];
        const float* hb = t ? h1b : h0b;
        float g0 = 1.f / (1.f + expf(-(red[t * 4 + 0] + hb[0])));
        float g1 = 1.f / (1.f + expf(-(red[t * 4 + 1] + hb[1])));
        float g2 = 1.f / (1.f + expf(-(red[t * 4 + 2] + hb[2])));
        float g3 = 1.f / (1.f + expf(-(red[t * 4 + 3] + hb[3])));
        float base = fd - g0 * fs - g1 * fl;
        size_t o = (size_t)t * BATCH * 128 + (size_t)b * 128;
        out[o + j0] = base - g2 * SLv[t][0] - g3 * LSv[t][0];
        out[o + j1] = base - g2 * SLv[t][1] - g3 * LSv[t][1];
    }
}

// ---------------- host ----------------
extern "C" void kernel_launch(void* const* d_in, const int* in_sizes, int n_in,
                              void* d_out, int out_size, void* d_ws, size_t ws_size,
                              hipStream_t stream)
{
    const int*   x    = (const int*)  d_in[0];
    const int*   dix  = (const int*)  d_in[1];
    const float* emb  = (const float*)d_in[2];
    const float* sW0  = (const float*)d_in[3];
    const float* sb0  = (const float*)d_in[4];
    const float* sW1  = (const float*)d_in[5];
    const float* sb1  = (const float*)d_in[6];
    const float* Dk0  = (const float*)d_in[7];
    const float* Db0  = (const float*)d_in[8];
    const float* DA0  = (const float*)d_in[9];
    const float* DB0  = (const float*)d_in[10];
    const float* Dlb0 = (const float*)d_in[11];
    const float* Tk0  = (const float*)d_in[12];
    const float* Tb0  = (const float*)d_in[13];
    const float* Tk1  = (const float*)d_in[14];
    const float* Tb1  = (const float*)d_in[15];
    const float* TA0  = (const float*)d_in[16];
    const float* TB0  = (const float*)d_in[17];
    const float* Tlb0 = (const float*)d_in[18];
    const float* TA1  = (const float*)d_in[19];
    const float* TB1  = (const float*)d_in[20];
    const float* Tlb1 = (const float*)d_in[21];
    const float* gW0  = (const float*)d_in[22];
    const float* gb0  = (const float*)d_in[23];
    const float* gW1  = (const float*)d_in[24];
    const float* gb1  = (const float*)d_in[25];
    const float* h0W  = (const float*)d_in[26];
    const float* h0b  = (const float*)d_in[27];
    const float* h1W  = (const float*)d_in[28];
    const float* h1b  = (const float*)d_in[29];

    hipFuncSetAttribute((const void*)k_gemm256<1, 1, 1>,
                        hipFuncAttributeMaxDynamicSharedMemorySize, 131072);
    hipFuncSetAttribute((const void*)k_gemm256<1, 1, 0>,
                        hipFuncAttributeMaxDynamicSharedMemorySize, 131072);

    char* ws = (char*)d_ws;
    size_t off = 0;
    auto alloc = [&](size_t bytes) -> void* {
        void* p = ws + off;
        off += (bytes + 255) & ~(size_t)255;
        return p;
    };
    unsigned short* W1t   = (unsigned short*)alloc((size_t)2048 * 2048 * 2);
    unsigned short* W2cat = (unsigned short*)alloc((size_t)1024 * 1024 * 2);
    unsigned short* D3cat = (unsigned short*)alloc((size_t)384 * 512 * 2);
    unsigned short* Tcat  = (unsigned short*)alloc((size_t)160 * 256 * 2);
    unsigned short* DB0b  = (unsigned short*)alloc((size_t)8 * 16 * 256 * 2);
    unsigned short* embB  = (unsigned short*)alloc((size_t)100000 * 64 * 2);
    float*          b1cat = (float*)alloc(2048 * 4);
    float*          b2cat = (float*)alloc(1024 * 4);
    float*          tb0c  = (float*)alloc(160 * 4);
    float*          d3bias= (float*)alloc(384 * 4);
    unsigned short* SHV   = (unsigned short*)alloc((size_t)BATCH * 384 * 2);
    unsigned short* Ybase = (unsigned short*)alloc((size_t)3 * BATCH * 160 * 2); // Ys|Yl|Yd bf16
    char* regB = (char*)alloc((size_t)BATCH * 2048 * 2);   // H, later SHARE/LORA/DDNN
    unsigned short* Xdnn  = (unsigned short*)alloc((size_t)BATCH * 512 * 2);
    unsigned short* Hyper = (unsigned short*)alloc((size_t)BATCH * 512 * 2);

    unsigned short* Ys = Ybase;                     // stream order: SHARE, LORA, DDNN
    unsigned short* Yl = Ybase + (size_t)BATCH * 160;
    unsigned short* Yd = Ybase + (size_t)2 * BATCH * 160;
    unsigned short* Hbuf  = (unsigned short*)regB;
    unsigned short* SHARE = (unsigned short*)regB;
    unsigned short* LORA  = SHARE + (size_t)BATCH * 256;
    unsigned short* DDNN  = LORA  + (size_t)BATCH * 256;

    // ONE prep launch
    k_prep<<<11817, 256, 0, stream>>>(
        sW0, gW0, sW1, gW1, Dk0, Tk0, TA0,
        sb0, gb0, sb1, gb1, Tb0, Db0, DA0, DB0, emb,
        W1t, W2cat, D3cat, Tcat, b1cat, b2cat, tb0c, d3bias, DB0b, embB);

    // GEMM1 (fused gather, reg-prefetched global idx): emb[x] @ [sW0|gW0], relu -> H
    k_gemm256<1, 1, 1><<<dim3(8, 64, 1), 512, 131072, stream>>>(
        embB, 0, 0, W1t, 2048, 0, b1cat, 0, Hbuf, 2048, 0, 2048, x, embB);
    // GEMM2 grouped (z=0: share-MLP, z=1: gate-hypernet): H halves -> Xdnn / Hyper
    k_gemm256<1, 1, 0><<<dim3(2, 64, 2), 512, 131072, stream>>>(
        Hbuf, 2048, 1024, W2cat, 1024, (long)512 * 1024, b2cat, 512,
        Xdnn, 512, (long)BATCH * 512, 512, nullptr, nullptr);
    // GEMM3b: [share | v_all] = Xdnn @ [Dk0 | DA0cat] + [Db0|0]  -> SHV (B,384) bf16
    k_gemm<0, 1><<<dim3(3, 128), 256, 0, stream>>>(Xdnn, 512, D3cat, d3bias, SHV, 384, 384, 512);
    // dlora-lite: finish LoRA + emit SHARE/LORA/DDNN streams
    k_dlora2<<<BATCH / 4, 256, 0, stream>>>(SHV, dix, DB0b, Dlb0, SHARE, LORA, DDNN);
    // stage i=0: one fused GEMM over 3 contiguous streams @ [Tk0|TA0[0]|TA0[1]] -> Y bf16
    k_gemm<0, 1><<<dim3(2, 384), 256, 0, stream>>>(SHARE, 256, Tcat, tb0c, Ybase, 160, 160, 256);
    // fused tail
    k_tail<<<BATCH / 4, 256, 0, stream>>>(Yd, Ys, Yl, Hyper, TB0, Tlb0, Tk1, Tb1,
                                          TA1, TB1, Tlb1, h0W, h0b, h1W, h1b, (float*)d_out);
}

// Round 11
// 314.610 us; speedup vs baseline: 4.7894x; 1.0187x over previous
//
#include <hip/hip_runtime.h>
#include <hip/hip_bf16.h>

#define BATCH 16384

typedef __attribute__((ext_vector_type(4))) float f32x4;
typedef __attribute__((ext_vector_type(8))) short bf16x8;

__device__ inline float b2f(unsigned short u) {
    union { unsigned u; float f; } c; c.u = ((unsigned)u) << 16; return c.f;
}
__device__ inline unsigned short f2b(float f) {
    __hip_bfloat16 h = __float2bfloat16(f);
    return *(unsigned short*)&h;
}

#define GLL16(g, l)                                                            \
    __builtin_amdgcn_global_load_lds(                                          \
        (const __attribute__((address_space(1))) void*)(g),                    \
        (__attribute__((address_space(3))) void*)(l), 16, 0, 0)

// ---------------- mega-prep: all transposes + biases + bf16 conversions, ONE launch ----------------
// id map: [0,4096) W1 | [,5120) W2 | [,5248) Dk0->D3cat[0:256) | [,5376) DA0t->D3cat[256:384) |
//         [,5408) Tk0 | [,5424) TA0 | [,5567) small | [,11817) embB
__global__ __launch_bounds__(256) void k_prep(
    const float* __restrict__ sW0, const float* __restrict__ gW0,
    const float* __restrict__ sW1, const float* __restrict__ gW1,
    const float* __restrict__ Dk0, const float* __restrict__ Tk0,
    const float* __restrict__ TA0,
    const float* __restrict__ sb0, const float* __restrict__ gb0,
    const float* __restrict__ sb1, const float* __restrict__ gb1,
    const float* __restrict__ Tb0, const float* __restrict__ Db0,
    const float* __restrict__ DA0, const float* __restrict__ DB0,
    const float* __restrict__ emb,
    unsigned short* __restrict__ W1t, unsigned short* __restrict__ W2cat,
    unsigned short* __restrict__ D3cat, unsigned short* __restrict__ Tcat,
    float* __restrict__ b1cat, float* __restrict__ b2cat, float* __restrict__ tb0c,
    float* __restrict__ d3bias, unsigned short* __restrict__ DB0b,
    unsigned short* __restrict__ embB)
{
    int id = blockIdx.x;
    const int tid = threadIdx.x;
    __shared__ float t[32][33];
    auto tcvt = [&](const float* src, int K, int N, unsigned short* dst,
                    int dst_off, int dst_ld, int bx, int by) {
        int k0 = by * 32, n0 = bx * 32;
        int tx = tid & 31, ty = tid >> 5;   // 32 x 8
        #pragma unroll
        for (int s = 0; s < 32; s += 8) {
            int k = k0 + ty + s, n = n0 + tx;
            t[ty + s][tx] = (k < K && n < N) ? src[(size_t)k * N + n] : 0.f;
        }
        __syncthreads();
        #pragma unroll
        for (int s = 0; s < 32; s += 8) {
            int n = n0 + ty + s, k = k0 + tx;
            if (n < N && k < K)
                dst[(size_t)(dst_off + n) * dst_ld + k] = f2b(t[tx][ty + s]);
        }
    };
    if (id < 4096) { int z = id >> 11, rem = id & 2047;
        tcvt(z ? gW0 : sW0, 2048, 1024, W1t, z * 1024, 2048, rem & 31, rem >> 5); return; }
    id -= 4096;
    if (id < 1024) { int z = id >> 9, rem = id & 511;
        tcvt(z ? gW1 : sW1, 1024, 512, W2cat, z * 512, 1024, rem & 15, rem >> 4); return; }
    id -= 1024;
    if (id < 128) { tcvt(Dk0, 512, 256, D3cat, 0, 512, id & 7, id >> 3); return; }
    id -= 128;
    if (id < 128) { int dom = id >> 4, by = id & 15;
        tcvt(DA0 + (size_t)dom * 512 * 16, 512, 16, D3cat, 256 + dom * 16, 512, 0, by); return; }
    id -= 128;
    if (id < 32)  { tcvt(Tk0, 256, 128, Tcat, 0, 256, id & 3, id >> 2); return; }
    id -= 32;
    if (id < 16)  { int z = id >> 3;
        tcvt(TA0 + z * 256 * 16, 256, 16, Tcat, 128 + z * 16, 256, 0, id & 7); return; }
    id -= 16;
    if (id < 143) {
        int i = id * 256 + tid;
        if (i < 1024)            { b1cat[i] = sb0[i]; return; }
        if (i < 2048)            { b1cat[i] = gb0[i - 1024]; return; }
        if (i < 2560)            { b2cat[i - 2048] = sb1[i - 2048]; return; }
        if (i < 3072)            { b2cat[i - 2560 + 512] = gb1[i - 2560]; return; }
        if (i < 3200)            { tb0c[i - 3072] = Tb0[i - 3072]; return; }
        if (i < 3232)            { tb0c[i - 3200 + 128] = 0.f; return; }
        if (i < 3488)            { d3bias[i - 3232] = Db0[i - 3232]; return; }
        if (i < 3616)            { d3bias[i - 3488 + 256] = 0.f; return; }
        i -= 3616;
        if (i < 32768)           { DB0b[i] = f2b(DB0[i]); return; }
        return;
    }
    id -= 143;
    {   // embB: f32 (100000 x 64) -> bf16, 4 elems/thread
        int e = (id * 256 + tid) * 4;
        if (e < 100000 * 64) {
            float4 v = *(const float4*)(emb + e);
            ushort4 o = { f2b(v.x), f2b(v.y), f2b(v.z), f2b(v.w) };
            *(ushort4*)(embB + e) = o;
        }
    }
}

// ================= 256x256 MFMA GEMM — minimal-barrier, compiler-scheduled (r9, 157.5us) =====
// C(MxN) = A(MxK)*Bt(NxK)^T + bias, opt relu. Tile 256x256, BK=64 (2 kslices of 32),
// 512 thr (8 waves 2Mx4N). LDS: 2 dbuf slots x 64KB, XOR chunk swizzle p=c^(row&7)
// both-sides; 0 fragment conflicts (r2-r9 verified).
// Sync: exactly 2 points per BK=64 tile: {vmcnt(4) ; asm s_barrier("memory")}.
// NO lgkmcnt(0) pins — compiler emits fine-grained lgkmcnt interleaved with MFMA (m97).
// GATHER=1: A rows gathered from embB via LDS-transposed x-block xbT with involution
// idx = tc*256 + (rr ^ (tc&31)) (write+read; writes <=2 lanes/bank = free, reads bcast);
// indices register-prefetched one tile ahead (ixc/ixn) — idx reads are LDS (lgkm
// counter) so the vm queue stays pure stage-loads: queue=8 at each VM4, oldest 4 =
// the kslice the following barrier publishes. vmcnt never 0 in loop (T4).
template<int RELU, int OUTBF16, int GATHER>
__global__ __launch_bounds__(512, 2) void k_gemm256(
    const unsigned short* __restrict__ A, int lda, long Az,
    const unsigned short* __restrict__ Bt, int K, long Bz,
    const float* __restrict__ bias, int biasz,
    void* __restrict__ C, int ldc, long Cz,
    int N, const int* __restrict__ xsrc, const unsigned short* __restrict__ embB)
{
    extern __shared__ char smem_raw[];
    const int NT = K >> 6;            // 64-wide K tiles
    const int tid  = threadIdx.x;
    const int lane = tid & 63;
    const int w    = tid >> 6;
    const int wr   = w >> 2, wc = w & 3;
    const int frow = lane & 15, kg = lane >> 4;
    const int z = blockIdx.z;
    A    += (size_t)z * Az;
    Bt   += (size_t)z * Bz;
    bias += (size_t)z * biasz;

    // XCD-aware bijective swizzle (nwg divisible by 8 for all our launches)
    const int gx  = gridDim.x;
    const int nwg = gx * gridDim.y;
    const int lin = blockIdx.y * gx + blockIdx.x;
    const int qq  = nwg >> 3;
    const int swz = (lin & 7) * qq + (lin >> 3);
    const int bx = swz % gx, by = swz / gx;
    const int row0 = by * 256, col0 = bx * 256;

    // staging: one kslice = 32KB = 4 gloads of 8KB (h=0..3) per thread.
    const int lch = (lane & 7) ^ ((lane >> 3) & 7);
    const int isA = (lch < 4);
    const int eoBase = lch * 8;                    // elem offset within embedding row (A)
    int* xbT = (int*)(smem_raw + 131072);          // 32KB transposed x-block (GATHER)
    int rrh[4];
    const unsigned short* gsrc[4];
    #pragma unroll
    for (int h = 0; h < 4; ++h) {
        int rr = h * 64 + w * 8 + (lane >> 3);
        rrh[h] = rr;
        if (isA) gsrc[h] = GATHER ? embB : A + (size_t)(row0 + rr) * lda + lch * 8;
        else     gsrc[h] = Bt + (size_t)min(col0 + rr, N - 1) * K + (lch - 4) * 8;
    }
    const int dBase = w * 1024;   // wave-uniform LDS offset within an 8KB gload block

    // fragment read offsets (bytes) within a kslice region; swizzled physical chunks
    const int pA = (kg ^ (frow & 7)) * 16;
    const int pB = ((4 + kg) ^ (frow & 7)) * 16;
    int aOff[8], bOff[4];
    #pragma unroll
    for (int m = 0; m < 8; ++m) aOff[m] = (wr * 128 + m * 16 + frow) * 128 + pA;
    #pragma unroll
    for (int n = 0; n < 4; ++n) bOff[n] = (wc * 64 + n * 16 + frow) * 128 + pB;

#define STAGE(t_, ks_, slot_) do {                                              \
        int tc_ = min((int)(t_), NT - 1);                                       \
        int o_ = tc_ * 64 + (ks_) * 32;                                         \
        char* d_ = smem_raw + (slot_) * 65536 + (ks_) * 32768 + dBase;          \
        GLL16(gsrc[0] + o_, d_);                                                \
        GLL16(gsrc[1] + o_, d_ + 8192);                                         \
        GLL16(gsrc[2] + o_, d_ + 16384);                                        \
        GLL16(gsrc[3] + o_, d_ + 24576);                                        \
    } while (0)
#define STAGEX(ix_, tcb_, ks_, slot_) do {                                      \
        char* d_ = smem_raw + (slot_) * 65536 + (ks_) * 32768 + dBase;          \
        _Pragma("unroll")                                                       \
        for (int h_ = 0; h_ < 4; ++h_) {                                        \
            const unsigned short* sa_ = embB + (size_t)(ix_)[h_] * 64           \
                                        + (ks_) * 32 + eoBase;                  \
            const unsigned short* sb2_ = gsrc[h_] + (tcb_) * 64 + (ks_) * 32;   \
            GLL16(isA ? sa_ : sb2_, d_ + h_ * 8192);                            \
        }                                                                       \
    } while (0)
#define READS(sb_, ks_) do {                                                    \
        _Pragma("unroll")                                                       \
        for (int n = 0; n < 4; ++n)                                             \
            bfr[n] = *(const bf16x8*)(smem_raw + (sb_) + (ks_) * 32768 + bOff[n]); \
        _Pragma("unroll")                                                       \
        for (int mi = 0; mi < 8; ++mi)                                          \
            afr[mi] = *(const bf16x8*)(smem_raw + (sb_) + (ks_) * 32768 + aOff[mi]); \
    } while (0)
#define MFMA32() do {                                                           \
        __builtin_amdgcn_s_setprio(1);                                          \
        _Pragma("unroll")                                                       \
        for (int mi = 0; mi < 8; ++mi)                                          \
            _Pragma("unroll")                                                   \
            for (int n = 0; n < 4; ++n)                                         \
                acc[mi][n] = __builtin_amdgcn_mfma_f32_16x16x32_bf16(           \
                    bfr[n], afr[mi], acc[mi][n], 0, 0, 0);                      \
        __builtin_amdgcn_s_setprio(0);                                          \
    } while (0)
#define VM4   asm volatile("s_waitcnt vmcnt(4)" ::: "memory")
#define BARM  asm volatile("s_barrier" ::: "memory")

    f32x4 acc[8][4] = {};
    bf16x8 afr[8], bfr[4];
    int ixc[4] = {0, 0, 0, 0};

    if (GATHER) {
        // 1) DMA linear x-block (256x32 ints, 32KB) into slot-1 scratch
        const char* xs = (const char*)(xsrc + row0 * 32);
        #pragma unroll
        for (int r = 0; r < 4; ++r)
            GLL16(xs + r * 8192 + w * 1024 + lane * 16,
                  smem_raw + 65536 + r * 8192 + w * 1024);
        asm volatile("s_waitcnt vmcnt(0)" ::: "memory");
        BARM;
        // 2) transpose to xbT with involution idx = tc*256 + (rr ^ (tc&31))
        const int* xlin = (const int*)(smem_raw + 65536);
        #pragma unroll
        for (int r = 0; r < 4; ++r) {
            int i = (r * 512 + tid) * 4;              // covers 8192 ints
            int rr_ = i >> 5, tc_ = i & 31;
            int4 vv = *(const int4*)(xlin + i);
            xbT[(tc_ + 0) * 256 + (rr_ ^ ((tc_ + 0) & 31))] = vv.x;
            xbT[(tc_ + 1) * 256 + (rr_ ^ ((tc_ + 1) & 31))] = vv.y;
            xbT[(tc_ + 2) * 256 + (rr_ ^ ((tc_ + 2) & 31))] = vv.z;
            xbT[(tc_ + 3) * 256 + (rr_ ^ ((tc_ + 3) & 31))] = vv.w;
        }
        asm volatile("s_waitcnt lgkmcnt(0)" ::: "memory");
        BARM;
        // 3) indices for tile 0 (used now) and tile 1 (ixc)
        int ix0[4];
        #pragma unroll
        for (int h = 0; h < 4; ++h) ix0[h] = xbT[rrh[h]];   // tc=0: rr^0
        STAGEX(ix0, 0, 0, 0); STAGEX(ix0, 0, 1, 0);
        int t1 = min(1, NT - 1);
        #pragma unroll
        for (int h = 0; h < 4; ++h) ixc[h] = xbT[t1 * 256 + (rrh[h] ^ (t1 & 31))];
    } else {
        STAGE(0, 0, 0); STAGE(0, 1, 0);
    }
    VM4; BARM;        // publishes tile0 ks0; ks1 in flight

    for (int t = 0; t < NT; ++t) {
        const int slot = t & 1, nslot = slot ^ 1;
        const int sb = slot * 65536;
        const int tcn = min(t + 1, NT - 1);
        int ixn[4];
        // half 0: reads ks0 + stage ks0(t+1) + idx prefetch (LDS) + 32 MFMA
        READS(sb, 0);
        if (GATHER) STAGEX(ixc, tcn, 0, nslot); else STAGE(t + 1, 0, nslot);
        if (GATHER) {
            int tc2 = min(t + 2, NT - 1);
            #pragma unroll
            for (int h = 0; h < 4; ++h) ixn[h] = xbT[tc2 * 256 + (rrh[h] ^ (tc2 & 31))];
        }
        MFMA32();
        VM4; BARM;    // publishes ks1(t)
        // half 1
        READS(sb, 1);
        if (GATHER) STAGEX(ixc, tcn, 1, nslot); else STAGE(t + 1, 1, nslot);
        MFMA32();
        VM4; BARM;    // publishes ks0(t+1)
        if (GATHER) {
            #pragma unroll
            for (int h = 0; h < 4; ++h) ixc[h] = ixn[h];
        }
    }
#undef STAGE
#undef STAGEX
#undef READS
#undef MFMA32
#undef VM4
#undef BARM

    // epilogue (swapped-operand layout): row = row0+wr*128+m*16+frow,
    // cols = col0+wc*64+n*16+kg*4 .. +3
    #pragma unroll
    for (int m = 0; m < 8; ++m) {
        int row = row0 + wr * 128 + m * 16 + frow;
        #pragma unroll
        for (int n = 0; n < 4; ++n) {
            int col = col0 + wc * 64 + n * 16 + kg * 4;
            float4 bv = *(const float4*)(bias + col);
            float v0 = acc[m][n][0] + bv.x, v1 = acc[m][n][1] + bv.y;
            float v2 = acc[m][n][2] + bv.z, v3 = acc[m][n][3] + bv.w;
            if (RELU) {
                v0 = fmaxf(v0, 0.f); v1 = fmaxf(v1, 0.f);
                v2 = fmaxf(v2, 0.f); v3 = fmaxf(v3, 0.f);
            }
            if (OUTBF16) {
                ushort4 o = { f2b(v0), f2b(v1), f2b(v2), f2b(v3) };
                *(ushort4*)((unsigned short*)C + (size_t)z * Cz + (size_t)row * ldc + col) = o;
            } else {
                float4 o = { v0, v1, v2, v3 };
                *(float4*)((float*)C + (size_t)z * Cz + (size_t)row * ldc + col) = o;
            }
        }
    }
}

// ---------------- 128x128 MFMA GEMM (m97 structure) for small GEMMs ----------------
template<int RELU, int OUTBF16>
__global__ __launch_bounds__(256) void k_gemm(
    const unsigned short* __restrict__ A, int lda,
    const unsigned short* __restrict__ Bt,         // N x K row-major, ldb = K
    const float* __restrict__ bias,
    void* __restrict__ C, int ldc,
    int N, int K)
{
    __shared__ __align__(16) unsigned short As[128 * 32];
    __shared__ __align__(16) unsigned short Bs[128 * 32];
    const int tid  = threadIdx.x;
    const int lane = tid & 63;
    const int w    = tid >> 6;
    const int wr   = w >> 1, wc = w & 1;
    const int row0 = blockIdx.y * 128;
    const int col0 = blockIdx.x * 128;
    const int frow = lane & 15;
    const int kg   = lane >> 4;
    const int sw   = kg ^ ((frow >> 1) & 3);

    const int srow = w * 32 + (lane >> 2);
    const int csw  = (lane & 3) ^ ((lane >> 3) & 3);
    const int br0  = min(col0 + srow, N - 1);
    const int br1  = min(col0 + srow + 16, N - 1);

    const unsigned short* a0 = A  + (size_t)(row0 + srow) * lda      + csw * 8;
    const unsigned short* a1 = A  + (size_t)(row0 + srow + 16) * lda + csw * 8;
    const unsigned short* b0 = Bt + (size_t)br0 * K + csw * 8;
    const unsigned short* b1 = Bt + (size_t)br1 * K + csw * 8;
    unsigned short* lA0 = As + (w * 2 + 0) * 512;
    unsigned short* lA1 = As + (w * 2 + 1) * 512;
    unsigned short* lB0 = Bs + (w * 2 + 0) * 512;
    unsigned short* lB1 = Bs + (w * 2 + 1) * 512;

    f32x4 acc[4][4] = {};

    for (int bk = 0; bk < K; bk += 32) {
        __syncthreads();
        GLL16(a0 + bk, lA0);
        GLL16(a1 + bk, lA1);
        GLL16(b0 + bk, lB0);
        GLL16(b1 + bk, lB1);
        __syncthreads();
        bf16x8 af[4], bfr[4];
        #pragma unroll
        for (int m = 0; m < 4; ++m)
            af[m] = *(const bf16x8*)&As[(wr * 64 + m * 16 + frow) * 32 + sw * 8];
        #pragma unroll
        for (int n = 0; n < 4; ++n)
            bfr[n] = *(const bf16x8*)&Bs[(wc * 64 + n * 16 + frow) * 32 + sw * 8];
        #pragma unroll
        for (int m = 0; m < 4; ++m)
            #pragma unroll
            for (int n = 0; n < 4; ++n)
                acc[m][n] = __builtin_amdgcn_mfma_f32_16x16x32_bf16(bfr[n], af[m], acc[m][n], 0, 0, 0);
    }

    // swapped-operand epilogue: row = row0+wr*64+m*16+frow, cols col0+wc*64+n*16+kg*4..+3
    #pragma unroll
    for (int m = 0; m < 4; ++m) {
        int row = row0 + wr * 64 + m * 16 + frow;
        #pragma unroll
        for (int n = 0; n < 4; ++n) {
            int col = col0 + wc * 64 + n * 16 + kg * 4;
            if (col >= N) continue;
            float4 bv = *(const float4*)(bias + col);
            float v0 = acc[m][n][0] + bv.x, v1 = acc[m][n][1] + bv.y;
            float v2 = acc[m][n][2] + bv.z, v3 = acc[m][n][3] + bv.w;
            if (RELU) {
                v0 = fmaxf(v0, 0.f); v1 = fmaxf(v1, 0.f);
                v2 = fmaxf(v2, 0.f); v3 = fmaxf(v3, 0.f);
            }
            if (OUTBF16) {
                ushort4 o = { f2b(v0), f2b(v1), f2b(v2), f2b(v3) };
                *(ushort4*)((unsigned short*)C + (size_t)row * ldc + col) = o;
            } else {
                float4 o = { v0, v1, v2, v3 };
                *(float4*)((float*)C + (size_t)row * ldc + col) = o;
            }
        }
    }
}

// ---------------- dlora-lite: finish domain LoRA from batched v = x@DA0 (in SHV) ----------------
__global__ __launch_bounds__(256) void k_dlora2(
    const unsigned short* __restrict__ SHV, const int* __restrict__ d,
    const unsigned short* __restrict__ DB0b, const float* __restrict__ Dlb0,
    unsigned short* __restrict__ SHARE,
    unsigned short* __restrict__ LORA, unsigned short* __restrict__ DDNN)
{
    int w = threadIdx.x >> 6, lane = threadIdx.x & 63;
    int b = blockIdx.x * 4 + w;
    int dom = d[b];
    const unsigned short* vp = SHV + (size_t)b * 384 + 256 + dom * 16;
    uint4 v0 = *(const uint4*)vp;
    uint4 v1 = *(const uint4*)(vp + 8);
    const unsigned short* pv0 = (const unsigned short*)&v0;
    const unsigned short* pv1 = (const unsigned short*)&v1;
    float v[16];
    #pragma unroll
    for (int r = 0; r < 8; ++r) { v[r] = b2f(pv0[r]); v[r + 8] = b2f(pv1[r]); }
    const unsigned short* Bp = DB0b + (size_t)dom * 16 * 256;
    const float* lbp = Dlb0 + (size_t)dom * 256;
    #pragma unroll
    for (int c = 0; c < 4; ++c) {
        int o = lane + c * 64;
        float a = lbp[o];
        #pragma unroll
        for (int r = 0; r < 16; ++r) a += v[r] * b2f(Bp[r * 256 + o]);
        unsigned short shb = SHV[(size_t)b * 384 + o];
        float sh = b2f(shb);
        SHARE[(size_t)b * 256 + o] = shb;
        LORA[(size_t)b * 256 + o] = f2b(a);
        DDNN[(size_t)b * 256 + o] = f2b(fmaxf(sh + a, 0.f));
    }
}

// ---------------- fused tail (Y bf16) ----------------
__global__ __launch_bounds__(256) void k_tail(
    const unsigned short* __restrict__ Yd, const unsigned short* __restrict__ Ys,
    const unsigned short* __restrict__ Yl,
    const unsigned short* __restrict__ Hyper,
    const float* __restrict__ TB0, const float* __restrict__ Tlb0,
    const float* __restrict__ Tk1, const float* __restrict__ Tb1,
    const float* __restrict__ TA1, const float* __restrict__ TB1, const float* __restrict__ Tlb1,
    const float* __restrict__ h0W, const float* __restrict__ h0b,
    const float* __restrict__ h1W, const float* __restrict__ h1b,
    float* __restrict__ out)
{
    __shared__ float sTB0[2][16][128];
    __shared__ float sTlb0[2][128];
    __shared__ float sTk1[128];
    __shared__ float sWeff[2][128];
    __shared__ float sY[4][3][160];
    const int tid = threadIdx.x;

    for (int i = tid; i < 4096; i += 256) ((float*)sTB0)[i] = TB0[i];
    if (tid < 256) ((float*)sTlb0)[tid] = Tlb0[tid];
    if (tid < 128) sTk1[tid] = Tk1[tid];
    {
        int t = tid >> 7, j = tid & 127;
        float a = 0.f;
        #pragma unroll
        for (int r = 0; r < 16; ++r) a += TA1[((size_t)t * 128 + j) * 16 + r] * TB1[t * 16 + r];
        sWeff[t][j] = a;
    }
    const unsigned short* Yp[3] = {Yd, Ys, Yl};
    int b0 = blockIdx.x * 4;
    for (int i = tid; i < 4 * 3 * 160; i += 256) {
        int s = i / 480, rem = i % 480, st = rem / 160, idx = rem % 160;
        sY[s][st][idx] = b2f(Yp[st][(size_t)(b0 + s) * 160 + idx]);
    }
    __syncthreads();

    int w = tid >> 6, lane = tid & 63;
    int b = b0 + w;
    const float* yd = sY[w][0];
    const float* ys = sY[w][1];
    const float* yl = sY[w][2];
    int j0 = lane, j1 = lane + 64;

    uint4 hraw = *(const uint4*)(Hyper + (size_t)b * 512 + lane * 8);
    const unsigned short* hp = (const unsigned short*)&hraw;
    float hv[8];
    #pragma unroll
    for (int j = 0; j < 8; ++j) hv[j] = b2f(hp[j]);

    float red[14];
    #pragma unroll
    for (int k = 0; k < 14; ++k) red[k] = 0.f;
    #pragma unroll
    for (int j = 0; j < 8; ++j) {
        float4 w0 = *(const float4*)(h0W + (size_t)(lane * 8 + j) * 4);
        float4 w1 = *(const float4*)(h1W + (size_t)(lane * 8 + j) * 4);
        red[0] += hv[j] * w0.x; red[1] += hv[j] * w0.y; red[2] += hv[j] * w0.z; red[3] += hv[j] * w0.w;
        red[4] += hv[j] * w1.x; red[5] += hv[j] * w1.y; red[6] += hv[j] * w1.z; red[7] += hv[j] * w1.w;
    }

    float SLv[2][2], LSv[2][2];
    #pragma unroll
    for (int t = 0; t < 2; ++t) {
        float lb0 = sTlb0[t][j0], lb1 = sTlb0[t][j1];
        float dl0 = lb0, dl1 = lb1, sl0 = lb0, sl1 = lb1, ll0 = lb0, ll1 = lb1;
        #pragma unroll
        for (int r = 0; r < 16; ++r) {
            float w0v = sTB0[t][r][j0], w1v = sTB0[t][r][j1];
            float ud = yd[128 + t * 16 + r];
            float us = ys[128 + t * 16 + r];
            float ul = yl[128 + t * 16 + r];
            dl0 += ud * w0v; dl1 += ud * w1v;
            sl0 += us * w0v; sl1 += us * w1v;
            ll0 += ul * w0v; ll1 += ul * w1v;
        }
        float D0 = yd[j0] + dl0, D1 = yd[j1] + dl1;
        float S0 = ys[j0],       S1 = ys[j1];
        float L0 = ll0,          L1 = ll1;
        float sl_0 = sl0, sl_1 = sl1;
        float ls_0 = yl[j0], ls_1 = yl[j1];
        if (t == 0) {
            D0 = fmaxf(D0, 0.f); D1 = fmaxf(D1, 0.f);
            S0 = fmaxf(S0, 0.f); S1 = fmaxf(S1, 0.f);
            L0 = fmaxf(L0, 0.f); L1 = fmaxf(L1, 0.f);
            sl_0 = fmaxf(sl_0, 0.f); sl_1 = fmaxf(sl_1, 0.f);
            ls_0 = fmaxf(ls_0, 0.f); ls_1 = fmaxf(ls_1, 0.f);
        }
        SLv[t][0] = sl_0; SLv[t][1] = sl_1;
        LSv[t][0] = ls_0; LSv[t][1] = ls_1;
        float we0 = sWeff[t][j0], we1 = sWeff[t][j1];
        float tk0 = sTk1[j0],     tk1v = sTk1[j1];
        red[8 + t * 3 + 0] = D0 * (tk0 + we0) + D1 * (tk1v + we1);
        red[8 + t * 3 + 1] = S0 * tk0 + S1 * tk1v;
        red[8 + t * 3 + 2] = L0 * we0 + L1 * we1;
    }

    #pragma unroll
    for (int s = 1; s < 64; s <<= 1) {
        #pragma unroll
        for (int k = 0; k < 14; ++k) red[k] += __shfl_xor(red[k], s, 64);
    }

    float Tb1v = Tb1[0];
    #pragma unroll
    for (int t = 0; t < 2; ++t) {
        float fd = red[8 + t * 3 + 0] + Tb1v + Tlb1[t];
        float fs = red[8 + t * 3 + 1] + Tb1v;
        float fl = red[8 + t * 3 + 2] + Tlb1[t];
        const float* hb = t ? h1b : h0b;
        float g0 = 1.f / (1.f + expf(-(red[t * 4 + 0] + hb[0])));
        float g1 = 1.f / (1.f + expf(-(red[t * 4 + 1] + hb[1])));
        float g2 = 1.f / (1.f + expf(-(red[t * 4 + 2] + hb[2])));
        float g3 = 1.f / (1.f + expf(-(red[t * 4 + 3] + hb[3])));
        float base = fd - g0 * fs - g1 * fl;
        size_t o = (size_t)t * BATCH * 128 + (size_t)b * 128;
        out[o + j0] = base - g2 * SLv[t][0] - g3 * LSv[t][0];
        out[o + j1] = base - g2 * SLv[t][1] - g3 * LSv[t][1];
    }
}

// ---------------- host ----------------
extern "C" void kernel_launch(void* const* d_in, const int* in_sizes, int n_in,
                              void* d_out, int out_size, void* d_ws, size_t ws_size,
                              hipStream_t stream)
{
    const int*   x    = (const int*)  d_in[0];
    const int*   dix  = (const int*)  d_in[1];
    const float* emb  = (const float*)d_in[2];
    const float* sW0  = (const float*)d_in[3];
    const float* sb0  = (const float*)d_in[4];
    const float* sW1  = (const float*)d_in[5];
    const float* sb1  = (const float*)d_in[6];
    const float* Dk0  = (const float*)d_in[7];
    const float* Db0  = (const float*)d_in[8];
    const float* DA0  = (const float*)d_in[9];
    const float* DB0  = (const float*)d_in[10];
    const float* Dlb0 = (const float*)d_in[11];
    const float* Tk0  = (const float*)d_in[12];
    const float* Tb0  = (const float*)d_in[13];
    const float* Tk1  = (const float*)d_in[14];
    const float* Tb1  = (const float*)d_in[15];
    const float* TA0  = (const float*)d_in[16];
    const float* TB0  = (const float*)d_in[17];
    const float* Tlb0 = (const float*)d_in[18];
    const float* TA1  = (const float*)d_in[19];
    const float* TB1  = (const float*)d_in[20];
    const float* Tlb1 = (const float*)d_in[21];
    const float* gW0  = (const float*)d_in[22];
    const float* gb0  = (const float*)d_in[23];
    const float* gW1  = (const float*)d_in[24];
    const float* gb1  = (const float*)d_in[25];
    const float* h0W  = (const float*)d_in[26];
    const float* h0b  = (const float*)d_in[27];
    const float* h1W  = (const float*)d_in[28];
    const float* h1b  = (const float*)d_in[29];

    hipFuncSetAttribute((const void*)k_gemm256<1, 1, 1>,
                        hipFuncAttributeMaxDynamicSharedMemorySize, 163840);
    hipFuncSetAttribute((const void*)k_gemm256<1, 1, 0>,
                        hipFuncAttributeMaxDynamicSharedMemorySize, 131072);

    char* ws = (char*)d_ws;
    size_t off = 0;
    auto alloc = [&](size_t bytes) -> void* {
        void* p = ws + off;
        off += (bytes + 255) & ~(size_t)255;
        return p;
    };
    unsigned short* W1t   = (unsigned short*)alloc((size_t)2048 * 2048 * 2);
    unsigned short* W2cat = (unsigned short*)alloc((size_t)1024 * 1024 * 2);
    unsigned short* D3cat = (unsigned short*)alloc((size_t)384 * 512 * 2);
    unsigned short* Tcat  = (unsigned short*)alloc((size_t)160 * 256 * 2);
    unsigned short* DB0b  = (unsigned short*)alloc((size_t)8 * 16 * 256 * 2);
    unsigned short* embB  = (unsigned short*)alloc((size_t)100000 * 64 * 2);
    float*          b1cat = (float*)alloc(2048 * 4);
    float*          b2cat = (float*)alloc(1024 * 4);
    float*          tb0c  = (float*)alloc(160 * 4);
    float*          d3bias= (float*)alloc(384 * 4);
    unsigned short* SHV   = (unsigned short*)alloc((size_t)BATCH * 384 * 2);
    unsigned short* Ybase = (unsigned short*)alloc((size_t)3 * BATCH * 160 * 2); // Ys|Yl|Yd bf16
    char* regB = (char*)alloc((size_t)BATCH * 2048 * 2);   // H, later SHARE/LORA/DDNN
    unsigned short* Xdnn  = (unsigned short*)alloc((size_t)BATCH * 512 * 2);
    unsigned short* Hyper = (unsigned short*)alloc((size_t)BATCH * 512 * 2);

    unsigned short* Ys = Ybase;                     // stream order: SHARE, LORA, DDNN
    unsigned short* Yl = Ybase + (size_t)BATCH * 160;
    unsigned short* Yd = Ybase + (size_t)2 * BATCH * 160;
    unsigned short* Hbuf  = (unsigned short*)regB;
    unsigned short* SHARE = (unsigned short*)regB;
    unsigned short* LORA  = SHARE + (size_t)BATCH * 256;
    unsigned short* DDNN  = LORA  + (size_t)BATCH * 256;

    // ONE prep launch
    k_prep<<<11817, 256, 0, stream>>>(
        sW0, gW0, sW1, gW1, Dk0, Tk0, TA0,
        sb0, gb0, sb1, gb1, Tb0, Db0, DA0, DB0, emb,
        W1t, W2cat, D3cat, Tcat, b1cat, b2cat, tb0c, d3bias, DB0b, embB);

    // GEMM1 (fused gather, r9 LDS x-block idx path): emb[x] @ [sW0|gW0], relu -> H
    k_gemm256<1, 1, 1><<<dim3(8, 64, 1), 512, 163840, stream>>>(
        embB, 0, 0, W1t, 2048, 0, b1cat, 0, Hbuf, 2048, 0, 2048, x, embB);
    // GEMM2 grouped (z=0: share-MLP, z=1: gate-hypernet): H halves -> Xdnn / Hyper
    k_gemm256<1, 1, 0><<<dim3(2, 64, 2), 512, 131072, stream>>>(
        Hbuf, 2048, 1024, W2cat, 1024, (long)512 * 1024, b2cat, 512,
        Xdnn, 512, (long)BATCH * 512, 512, nullptr, nullptr);
    // GEMM3b: [share | v_all] = Xdnn @ [Dk0 | DA0cat] + [Db0|0]  -> SHV (B,384) bf16
    k_gemm<0, 1><<<dim3(3, 128), 256, 0, stream>>>(Xdnn, 512, D3cat, d3bias, SHV, 384, 384, 512);
    // dlora-lite: finish LoRA + emit SHARE/LORA/DDNN streams
    k_dlora2<<<BATCH / 4, 256, 0, stream>>>(SHV, dix, DB0b, Dlb0, SHARE, LORA, DDNN);
    // stage i=0: one fused GEMM over 3 contiguous streams @ [Tk0|TA0[0]|TA0[1]] -> Y bf16
    k_gemm<0, 1><<<dim3(2, 384), 256, 0, stream>>>(SHARE, 256, Tcat, tb0c, Ybase, 160, 160, 256);
    // fused tail
    k_tail<<<BATCH / 4, 256, 0, stream>>>(Yd, Ys, Yl, Hyper, TB0, Tlb0, Tk1, Tb1,
                                          TA1, TB1, Tlb1, h0W, h0b, h1W, h1b, (float*)d_out);
}